// Round 1
// baseline (1650.923 us; speedup 1.0000x reference)
//
#include <hip/hip_runtime.h>
#include <cstdint>

#define D 128
#define NB 256
#define NPTS 200000
#define KNN 50
#define CAP 8192
#define NSAMP 4096

// ---- workspace byte offsets ----
#define OFF_ACC      0        // 32 floats (zeroed)
#define OFF_SEL      256      // 16 uint  (zeroed)
#define OFF_HIST     512      // 3*2*4096 u32 = 98304 (zeroed)
#define OFF_CNT      102400   // 256 u32 (zeroed)
#define OFF_COMB     131072   // 512*128 f32
#define OFF_D2       393216   // 262144 f32
#define OFF_XNORM    1441792  // 200000 f32
#define OFF_SAMP     2241792  // 256*4096 f32
#define OFF_THR      6436096  // 256 f32
#define OFF_CANDS    6437120  // 256*8192 f32
#define OFF_CANDI    14825728 // 256*8192 i32
#define OFF_PIDX     23214336 // 256*50 i32
#define OFF_PW       23265536 // 256*50 f32

__device__ __forceinline__ unsigned fkey(float f) {
    unsigned u = __float_as_uint(f);
    return u ^ ((unsigned)((int)u >> 31) | 0x80000000u);
}

// ---- Tq = q @ W^T + b (blocks 0..255) ; comb[256..511] = X[idx] (blocks 256..511) ----
__global__ void k_prep(const float* __restrict__ q, const float* __restrict__ X,
                       const float* __restrict__ W, const float* __restrict__ bb,
                       const int* __restrict__ idx, float* __restrict__ comb,
                       float* __restrict__ acc)
{
    __shared__ float row[D];
    __shared__ float red[D];
    const int blk = blockIdx.x, t = threadIdx.x;
    if (blk < NB) {
        row[t] = q[blk * D + t];
        __syncthreads();
        float s = 0.f;
        const float* wr = W + t * D;
        #pragma unroll 4
        for (int k = 0; k < D; k++) s = fmaf(row[k], wr[k], s);
        s += bb[t];
        comb[blk * D + t] = s;
        float dd = s - row[t];
        red[t] = dd * dd;
        __syncthreads();
        for (int off = 64; off > 0; off >>= 1) { if (t < off) red[t] += red[t + off]; __syncthreads(); }
        if (t == 0) atomicAdd(&acc[0], red[0]);
    } else {
        int i = blk - NB;
        comb[(NB + i) * D + t] = X[(long)idx[i] * D + t];
    }
}

// ---- D2[i][j] = ||comb_i - comb_j||^2  (512x512) ----
__global__ void k_d2(const float* __restrict__ comb, float* __restrict__ D2w)
{
    __shared__ float ci[D];
    __shared__ float cj[64][D + 4];
    const int i = blockIdx.x, jb = blockIdx.y, t = threadIdx.x; // 64 threads
    ci[t] = comb[i * D + t];
    ci[t + 64] = comb[i * D + t + 64];
    const float4* src = (const float4*)(comb + (jb * 64) * D);
    #pragma unroll
    for (int m = 0; m < 32; m++) {
        int u = m * 64 + t;
        int r = u >> 5, c = u & 31;
        float4 v = src[u];
        cj[r][c * 4 + 0] = v.x; cj[r][c * 4 + 1] = v.y; cj[r][c * 4 + 2] = v.z; cj[r][c * 4 + 3] = v.w;
    }
    __syncthreads();
    float s = 0.f;
    #pragma unroll 4
    for (int k = 0; k < D; k++) { float d = ci[k] - cj[t][k]; s = fmaf(d, d, s); }
    D2w[i * 512 + jb * 64 + t] = s;
}

// ---- radix-select histograms (pass 0: key>>20 ; pass1: (key>>8)&0xFFF ; pass2: key&0xFF) ----
__global__ void k_hist(const float* __restrict__ D2w, unsigned* __restrict__ hist,
                       const unsigned* __restrict__ sel, int pass)
{
    __shared__ unsigned h[8192];
    const int t = threadIdx.x;
    for (int m = t; m < 8192; m += 256) h[m] = 0;
    __syncthreads();
    unsigned p0 = 0, p1 = 0;
    if (pass) { p0 = sel[0]; p1 = sel[2]; }
    const int e0 = blockIdx.x * 1024;
    for (int m = 0; m < 4; m++) {
        unsigned key = __float_as_uint(D2w[e0 + m * 256 + t]); // all >=0 -> monotone
        if (pass == 0) atomicAdd(&h[key >> 20], 1u);
        else if (pass == 1) {
            if ((key >> 20) == p0) atomicAdd(&h[(key >> 8) & 0xFFFu], 1u);
            if ((key >> 20) == p1) atomicAdd(&h[4096 + ((key >> 8) & 0xFFFu)], 1u);
        } else {
            if ((key >> 8) == p0) atomicAdd(&h[key & 0xFFu], 1u);
            if ((key >> 8) == p1) atomicAdd(&h[4096 + (key & 0xFFu)], 1u);
        }
    }
    __syncthreads();
    unsigned* g = hist + pass * 8192;
    for (int m = t; m < 8192; m += 256) { unsigned vv = h[m]; if (vv) atomicAdd(&g[m], vv); }
}

__global__ void k_scan(const unsigned* __restrict__ hist, unsigned* __restrict__ sel,
                       float* __restrict__ acc, int pass)
{
    __shared__ unsigned part[256];
    __shared__ unsigned res[4];
    const int t = threadIdx.x;
    const int nb = (pass == 2) ? 256 : 4096;
    const int per = nb / 256;
    unsigned rank0 = (pass == 0) ? 131071u : sel[1];
    unsigned rank1 = (pass == 0) ? 131072u : sel[3];
    for (int tg = 0; tg < 2; tg++) {
        const unsigned* h = hist + pass * 8192 + ((pass == 0) ? 0 : tg * 4096);
        unsigned s = 0;
        for (int m = 0; m < per; m++) s += h[t * per + m];
        part[t] = s;
        __syncthreads();
        if (t == 0) {
            unsigned r = (tg == 0) ? rank0 : rank1;
            int c = 0;
            while (part[c] <= r) { r -= part[c]; c++; }
            int bidx = c * per;
            while (h[bidx] <= r) { r -= h[bidx]; bidx++; }
            res[2 * tg] = (unsigned)bidx; res[2 * tg + 1] = r;
        }
        __syncthreads();
    }
    if (t == 0) {
        if (pass == 0) { sel[0] = res[0]; sel[1] = res[1]; sel[2] = res[2]; sel[3] = res[3]; }
        else if (pass == 1) { sel[0] = (sel[0] << 12) | res[0]; sel[1] = res[1];
                              sel[2] = (sel[2] << 12) | res[2]; sel[3] = res[3]; }
        else {
            unsigned k0 = (sel[0] << 8) | res[0];
            unsigned k1 = (sel[2] << 8) | res[2];
            float med = 0.5f * (__uint_as_float(k0) + __uint_as_float(k1));
            float ssq = 0.5f * med;
            if (ssq < 1e-6f) ssq = 1.0f;
            acc[5] = 1.0f / (ssq + 1e-8f);
            acc[6] = med;
        }
    }
}

// ---- MMD quadrant exp sums ----
__global__ void k_mmd(const float* __restrict__ D2w, float* __restrict__ acc)
{
    const int t = threadIdx.x;
    const float g = acc[5];
    float s[3] = {0.f, 0.f, 0.f};
    const int e0 = blockIdx.x * 1024;
    #pragma unroll
    for (int m = 0; m < 4; m++) {
        int e = e0 + m * 256 + t;
        int i = e >> 9, j = e & 511;
        float v = expf(-g * D2w[e]);
        int qd = (i < 256) ? ((j < 256) ? 0 : 2) : ((j < 256) ? 2 : 1);
        s[qd] += v;
    }
    #pragma unroll
    for (int c = 0; c < 3; c++) {
        float x = s[c];
        #pragma unroll
        for (int off = 32; off > 0; off >>= 1) x += __shfl_down(x, off);
        if ((t & 63) == 0 && x != 0.f) atomicAdd(&acc[2 + c], x);
    }
}

// ---- xnorm[j] = ||X_j||^2 ----
__global__ void k_xnorm(const float* __restrict__ X, float* __restrict__ xn)
{
    __shared__ float rsum[32];
    const int t = threadIdx.x;
    const long base4 = (long)blockIdx.x * 1024;
    const float4* src = (const float4*)X;
    for (int m = 0; m < 4; m++) {
        float4 v = src[base4 + m * 256 + t];
        float s = v.x * v.x + v.y * v.y + v.z * v.z + v.w * v.w;
        for (int off = 16; off > 0; off >>= 1) s += __shfl_down(s, off, 32);
        if ((t & 31) == 0) rsum[m * 8 + (t >> 5)] = s;
    }
    __syncthreads();
    if (t < 32) xn[blockIdx.x * 32 + t] = rsum[t];
}

// ---- tiled f32 GEMM: score = xnorm[r] - 2 * dot(Tq_q, X_r) ----
// mode 0: write sample scores (rows < 4096). mode 1: filter-append candidates.
__global__ __launch_bounds__(256, 2) void k_gemm(const float* __restrict__ Tq,
    const float* __restrict__ X, const float* __restrict__ xn,
    const float* __restrict__ thr, float* __restrict__ samp,
    float* __restrict__ cand_s, int* __restrict__ cand_i, unsigned* __restrict__ cnt,
    int row_base, int mode)
{
    __shared__ float Xs[32][132];
    __shared__ float Qs[32][132];
    const int t = threadIdx.x;
    const int qbase = blockIdx.y * 128;
    const int rbase = row_base + blockIdx.x * 128;
    const int tc = t & 15, tr = t >> 4;
    const int r0 = tc * 8, q0 = tr * 8;
    float acc[8][8];
    #pragma unroll
    for (int i = 0; i < 8; i++)
        #pragma unroll
        for (int j = 0; j < 8; j++) acc[i][j] = 0.f;

    for (int kt = 0; kt < D; kt += 32) {
        __syncthreads();
        #pragma unroll
        for (int m = 0; m < 4; m++) {
            int u = m * 256 + t;
            int r = u >> 3, k4 = u & 7;
            int rg = rbase + r; if (rg > NPTS - 1) rg = NPTS - 1;
            const float4 v = *(const float4*)(X + (long)rg * D + kt + k4 * 4);
            Xs[k4 * 4 + 0][r] = v.x; Xs[k4 * 4 + 1][r] = v.y;
            Xs[k4 * 4 + 2][r] = v.z; Xs[k4 * 4 + 3][r] = v.w;
        }
        #pragma unroll
        for (int m = 0; m < 4; m++) {
            int u = m * 256 + t;
            int qq = u >> 3, k4 = u & 7;
            const float4 v = *(const float4*)(Tq + (qbase + qq) * D + kt + k4 * 4);
            Qs[k4 * 4 + 0][qq] = v.x; Qs[k4 * 4 + 1][qq] = v.y;
            Qs[k4 * 4 + 2][qq] = v.z; Qs[k4 * 4 + 3][qq] = v.w;
        }
        __syncthreads();
        #pragma unroll 4
        for (int k = 0; k < 32; k++) {
            float4 xa = *(const float4*)&Xs[k][r0];
            float4 xb = *(const float4*)&Xs[k][r0 + 4];
            float4 qa = *(const float4*)&Qs[k][q0];
            float4 qb = *(const float4*)&Qs[k][q0 + 4];
            float xv[8] = {xa.x, xa.y, xa.z, xa.w, xb.x, xb.y, xb.z, xb.w};
            float qv[8] = {qa.x, qa.y, qa.z, qa.w, qb.x, qb.y, qb.z, qb.w};
            #pragma unroll
            for (int i = 0; i < 8; i++)
                #pragma unroll
                for (int j = 0; j < 8; j++) acc[i][j] = fmaf(qv[i], xv[j], acc[i][j]);
        }
    }

    if (mode == 0) {
        #pragma unroll
        for (int j = 0; j < 8; j++) {
            int rg = rbase + r0 + j;
            float xnv = xn[rg];
            #pragma unroll
            for (int i = 0; i < 8; i++)
                samp[(qbase + q0 + i) * NSAMP + rg] = xnv - 2.f * acc[i][j];
        }
    } else {
        #pragma unroll
        for (int i = 0; i < 8; i++) {
            int qg = qbase + q0 + i;
            float th = thr[qg];
            #pragma unroll
            for (int j = 0; j < 8; j++) {
                int rg = rbase + r0 + j;
                if (rg < NPTS) {
                    float s = xn[rg] - 2.f * acc[i][j];
                    if (s <= th) {
                        unsigned pos = atomicAdd(&cnt[qg], 1u);
                        if (pos < CAP) { cand_s[qg * CAP + pos] = s; cand_i[qg * CAP + pos] = rg; }
                    }
                }
            }
        }
    }
}

// ---- per-query exact 50th-smallest of the 4096 sample scores -> thr; append sample cands ----
__global__ void k_thr(const float* __restrict__ samp, float* __restrict__ thr,
                      float* __restrict__ cand_s, int* __restrict__ cand_i,
                      unsigned* __restrict__ cnt)
{
    __shared__ float ss[NSAMP];
    __shared__ unsigned ks[NSAMP];
    __shared__ unsigned wred[4];
    const int q = blockIdx.x, t = threadIdx.x;
    for (int m = t; m < NSAMP; m += 256) {
        float v = samp[q * NSAMP + m];
        ss[m] = v; ks[m] = fkey(v);
    }
    __syncthreads();
    unsigned v = 0;
    for (int bit = 31; bit >= 0; bit--) {
        unsigned trial = v | (1u << bit);
        unsigned c = 0;
        for (int m = t; m < NSAMP; m += 256) c += (ks[m] < trial) ? 1u : 0u;
        #pragma unroll
        for (int off = 32; off > 0; off >>= 1) c += __shfl_down(c, off);
        if ((t & 63) == 0) wred[t >> 6] = c;
        __syncthreads();
        unsigned total = wred[0] + wred[1] + wred[2] + wred[3];
        __syncthreads();
        if (total <= (unsigned)(KNN - 1)) v = trial;
    }
    if (t == 0) {
        unsigned orig = (v & 0x80000000u) ? (v ^ 0x80000000u) : ~v;
        thr[q] = __uint_as_float(orig);
    }
    for (int m = t; m < NSAMP; m += 256) {
        if (ks[m] <= v) {
            unsigned pos = atomicAdd(&cnt[q], 1u);
            if (pos < CAP) { cand_s[q * CAP + pos] = ss[m]; cand_i[q * CAP + pos] = m; }
        }
    }
}

// ---- exact top-50 from candidates (ties -> smallest index, matching lax.top_k) ----
__global__ void k_select(const float* __restrict__ cand_s, const int* __restrict__ cand_i,
                         const unsigned* __restrict__ cnt, int* __restrict__ post_idx)
{
    __shared__ unsigned ks[CAP];
    __shared__ unsigned wred[4];
    __shared__ unsigned wpos, eqn;
    __shared__ int eq[64];
    const int q = blockIdx.x, t = threadIdx.x;
    unsigned nn = cnt[q];
    const int n = (nn < (unsigned)CAP) ? (int)nn : CAP;
    for (int m = t; m < n; m += 256) ks[m] = fkey(cand_s[q * CAP + m]);
    __syncthreads();
    int kk = KNN - 1; if (kk > n - 1) kk = n - 1;
    unsigned v = 0;
    for (int bit = 31; bit >= 0; bit--) {
        unsigned trial = v | (1u << bit);
        unsigned c = 0;
        for (int m = t; m < n; m += 256) c += (ks[m] < trial) ? 1u : 0u;
        #pragma unroll
        for (int off = 32; off > 0; off >>= 1) c += __shfl_down(c, off);
        if ((t & 63) == 0) wred[t >> 6] = c;
        __syncthreads();
        unsigned total = wred[0] + wred[1] + wred[2] + wred[3];
        __syncthreads();
        if (total <= (unsigned)kk) v = trial;
    }
    if (t == 0) { wpos = 0; eqn = 0; }
    __syncthreads();
    for (int m = t; m < n; m += 256) {
        if (ks[m] < v) {
            unsigned p = atomicAdd(&wpos, 1u);
            post_idx[q * KNN + p] = cand_i[q * CAP + m];
        } else if (ks[m] == v) {
            unsigned p = atomicAdd(&eqn, 1u);
            if (p < 64) eq[p] = cand_i[q * CAP + m];
        }
    }
    __syncthreads();
    if (t == 0) {
        int c1 = (int)wpos;
        int need = KNN - c1;
        int ne = (eqn < 64u) ? (int)eqn : 64;
        for (int a = 0; a < ne; a++)
            for (int b2 = a + 1; b2 < ne; b2++)
                if (eq[b2] < eq[a]) { int tmp = eq[a]; eq[a] = eq[b2]; eq[b2] = tmp; }
        for (int a = 0; a < need && a < ne; a++) post_idx[q * KNN + c1 + a] = eq[a];
    }
}

// ---- exact l2 to selected neighbors + softmax(-l2/tau) ----
__global__ void k_l2sm(const float* __restrict__ comb, const float* __restrict__ X,
                       const int* __restrict__ post_idx, float* __restrict__ post_w)
{
    __shared__ float l2s[KNN];
    __shared__ float qrow[D];
    const int q = blockIdx.x, t = threadIdx.x;
    const int w = t >> 6, l = t & 63;
    if (t < D) qrow[t] = comb[q * D + t];
    __syncthreads();
    for (int nb = w; nb < KNN; nb += 4) {
        long j = post_idx[q * KNN + nb];
        float d0 = qrow[l] - X[j * D + l];
        float d1 = qrow[l + 64] - X[j * D + l + 64];
        float s = d0 * d0 + d1 * d1;
        #pragma unroll
        for (int off = 32; off > 0; off >>= 1) s += __shfl_down(s, off);
        if (l == 0) l2s[nb] = s;
    }
    __syncthreads();
    if (t < 64) {
        float logit = (t < KNN) ? (-l2s[t] * 10.0f) : -3.4e38f; // 1/tau = 10
        float m = logit;
        #pragma unroll
        for (int off = 32; off > 0; off >>= 1) m = fmaxf(m, __shfl_down(m, off));
        m = __shfl(m, 0);
        float e = (t < KNN) ? expf(logit - m) : 0.f;
        float ssum = e;
        #pragma unroll
        for (int off = 32; off > 0; off >>= 1) ssum += __shfl_down(ssum, off);
        ssum = __shfl(ssum, 0);
        if (t < KNN) post_w[q * KNN + t] = e / ssum;
    }
}

// ---- union-KL with exact multiplicity semantics ----
__global__ void k_kl(const int* __restrict__ pri, const float* __restrict__ prw,
                     const int* __restrict__ qix, const int* __restrict__ post_idx,
                     const float* __restrict__ post_w, float* __restrict__ acc)
{
    __shared__ int ci[100];
    __shared__ float pwv[50], qwv[50];
    __shared__ float pterm[100], qterm[100], kterm[100];
    __shared__ float Sp, Sq;
    const int b = blockIdx.x, t = threadIdx.x;
    int qi = qix[b];
    if (t < 50) { ci[t] = pri[qi * 50 + t]; pwv[t] = prw[qi * 50 + t]; }
    else if (t < 100) { int k = t - 50; ci[t] = post_idx[b * 50 + k]; qwv[k] = post_w[b * 50 + k]; }
    __syncthreads();
    float pc = 0.f, qc = 0.f, mult = 0.f;
    if (t < 100) {
        int c = ci[t];
        float pr = 0.f, qr = 0.f;
        for (int k = 0; k < 50; k++) {
            bool m1 = (c == ci[k]); bool m2 = (c == ci[50 + k]);
            mult += (m1 ? 1.f : 0.f) + (m2 ? 1.f : 0.f);
            pr += m1 ? pwv[k] : 0.f;
            qr += m2 ? qwv[k] : 0.f;
        }
        pc = fmaxf(pr, 1e-8f); qc = fmaxf(qr, 1e-8f);
        pterm[t] = pc / mult; qterm[t] = qc / mult;
    }
    __syncthreads();
    if (t == 0) { float a = 0.f, b2 = 0.f; for (int m = 0; m < 100; m++) { a += pterm[m]; b2 += qterm[m]; } Sp = a; Sq = b2; }
    __syncthreads();
    if (t < 100) {
        float p = pc / Sp, qq = qc / Sq;
        kterm[t] = (p * (logf(p) - logf(qq))) / mult;
    }
    __syncthreads();
    if (t == 0) { float s = 0.f; for (int m = 0; m < 100; m++) s += kterm[m]; atomicAdd(&acc[1], s); }
}

// ---- reg + final assembly ----
__global__ void k_final(const float* __restrict__ W, const float* __restrict__ bb,
                        const float* __restrict__ acc, float* __restrict__ out)
{
    __shared__ float red[256];
    const int t = threadIdx.x;
    float s = 0.f;
    for (int m = t; m < D * D; m += 256) { float v = W[m]; s += v * v; }
    if (t < D) { float v = bb[t]; s += v * v; }
    red[t] = s;
    __syncthreads();
    for (int off = 128; off > 0; off >>= 1) { if (t < off) red[t] += red[t + off]; __syncthreads(); }
    if (t == 0) {
        float reg = 0.5f * red[0];
        float kxx = acc[2] / 65536.f, kyy = acc[3] / 65536.f, kxy = acc[4] / 131072.f;
        float ld = fmaxf(kxx + kyy - 2.f * kxy, 0.f);
        float lknn = acc[1] / 256.f;
        float lanc = acc[0] / 256.f;
        float total = ld + lknn + 1e-4f * reg + lanc;
        out[0] = total; out[1] = ld; out[2] = lknn; out[3] = lanc;
    }
}

extern "C" void kernel_launch(void* const* d_in, const int* in_sizes, int n_in,
                              void* d_out, int out_size, void* d_ws, size_t ws_size,
                              hipStream_t stream)
{
    (void)in_sizes; (void)n_in; (void)out_size; (void)ws_size;
    const float* q   = (const float*)d_in[0];
    const float* X   = (const float*)d_in[1];
    const float* W   = (const float*)d_in[2];
    const float* bb  = (const float*)d_in[3];
    const float* prw = (const float*)d_in[4];
    const int*   pri = (const int*)d_in[5];
    const int*   qix = (const int*)d_in[6];
    const int*   idx = (const int*)d_in[7];
    float* out = (float*)d_out;
    char* ws = (char*)d_ws;
    float*    acc  = (float*)(ws + OFF_ACC);
    unsigned* sel  = (unsigned*)(ws + OFF_SEL);
    unsigned* hist = (unsigned*)(ws + OFF_HIST);
    unsigned* cnt  = (unsigned*)(ws + OFF_CNT);
    float*    comb = (float*)(ws + OFF_COMB);
    float*    D2w  = (float*)(ws + OFF_D2);
    float*    xn   = (float*)(ws + OFF_XNORM);
    float*    samp = (float*)(ws + OFF_SAMP);
    float*    thr  = (float*)(ws + OFF_THR);
    float*    cs   = (float*)(ws + OFF_CANDS);
    int*      cix  = (int*)(ws + OFF_CANDI);
    int*      pix  = (int*)(ws + OFF_PIDX);
    float*    pw   = (float*)(ws + OFF_PW);

    hipMemsetAsync(ws, 0, 131072, stream);
    hipLaunchKernelGGL(k_prep,  dim3(512),      dim3(128), 0, stream, q, X, W, bb, idx, comb, acc);
    hipLaunchKernelGGL(k_d2,    dim3(512, 8),   dim3(64),  0, stream, comb, D2w);
    hipLaunchKernelGGL(k_hist,  dim3(256),      dim3(256), 0, stream, D2w, hist, sel, 0);
    hipLaunchKernelGGL(k_scan,  dim3(1),        dim3(256), 0, stream, hist, sel, acc, 0);
    hipLaunchKernelGGL(k_hist,  dim3(256),      dim3(256), 0, stream, D2w, hist, sel, 1);
    hipLaunchKernelGGL(k_scan,  dim3(1),        dim3(256), 0, stream, hist, sel, acc, 1);
    hipLaunchKernelGGL(k_hist,  dim3(256),      dim3(256), 0, stream, D2w, hist, sel, 2);
    hipLaunchKernelGGL(k_scan,  dim3(1),        dim3(256), 0, stream, hist, sel, acc, 2);
    hipLaunchKernelGGL(k_mmd,   dim3(256),      dim3(256), 0, stream, D2w, acc);
    hipLaunchKernelGGL(k_xnorm, dim3(6250),     dim3(256), 0, stream, X, xn);
    hipLaunchKernelGGL(k_gemm,  dim3(32, 2),    dim3(256), 0, stream, comb, X, xn, thr, samp, cs, cix, cnt, 0, 0);
    hipLaunchKernelGGL(k_thr,   dim3(256),      dim3(256), 0, stream, samp, thr, cs, cix, cnt);
    hipLaunchKernelGGL(k_gemm,  dim3(1531, 2),  dim3(256), 0, stream, comb, X, xn, thr, samp, cs, cix, cnt, 4096, 1);
    hipLaunchKernelGGL(k_select,dim3(256),      dim3(256), 0, stream, cs, cix, cnt, pix);
    hipLaunchKernelGGL(k_l2sm,  dim3(256),      dim3(256), 0, stream, comb, X, pix, pw);
    hipLaunchKernelGGL(k_kl,    dim3(256),      dim3(128), 0, stream, pri, prw, qix, pix, pw, acc);
    hipLaunchKernelGGL(k_final, dim3(1),        dim3(256), 0, stream, W, bb, acc, out);
}

// Round 2
// 850.951 us; speedup vs baseline: 1.9401x; 1.9401x over previous
//
#include <hip/hip_runtime.h>
#include <cstdint>

#define D 128
#define NB 256
#define NPTS 200000
#define KNN 50
#define CAP 8192
#define NSAMP 4096
#define SLACK 2.0f

// ---- workspace byte offsets ----
#define OFF_ACC      0        // 32 floats (zeroed)
#define OFF_SEL      256      // 16 uint  (zeroed)
#define OFF_HIST     512      // 3*2*4096 u32 = 98304 (zeroed)
#define OFF_CNT      102400   // 256*16 u32 = 16384 (zeroed; one counter per 64B line)
#define OFF_COMB     131072   // 512*128 f32
#define OFF_D2       393216   // 262144 f32
#define OFF_XNORM    1441792  // 200000 f32
#define OFF_SAMP     2241792  // 256*4096 f32
#define OFF_THR      6436096  // 256 f32
#define OFF_CANDS    6437120  // 256*8192 f32
#define OFF_CANDI    14825728 // 256*8192 i32
#define OFF_PIDX     23214336 // 256*50 i32
#define OFF_PW       23265536 // 256*50 f32
#define OFF_TQBF     23316992 // 256*128 bf16 (ushort)

typedef __attribute__((ext_vector_type(8))) short bf16x8;
typedef __attribute__((ext_vector_type(4))) float f32x4;

__device__ __forceinline__ unsigned fkey(float f) {
    unsigned u = __float_as_uint(f);
    return u ^ ((unsigned)((int)u >> 31) | 0x80000000u);
}

// ---- Tq = q @ W^T + b (blocks 0..255, also bf16 copy) ; comb[256..511] = X[idx] ----
__global__ void k_prep(const float* __restrict__ q, const float* __restrict__ X,
                       const float* __restrict__ W, const float* __restrict__ bb,
                       const int* __restrict__ idx, float* __restrict__ comb,
                       unsigned short* __restrict__ tqbf, float* __restrict__ acc)
{
    __shared__ float row[D];
    __shared__ float red[D];
    const int blk = blockIdx.x, t = threadIdx.x;
    if (blk < NB) {
        row[t] = q[blk * D + t];
        __syncthreads();
        float s = 0.f;
        const float* wr = W + t * D;
        #pragma unroll 4
        for (int k = 0; k < D; k++) s = fmaf(row[k], wr[k], s);
        s += bb[t];
        comb[blk * D + t] = s;
        // bf16 RNE
        unsigned ub = __float_as_uint(s);
        tqbf[blk * D + t] = (unsigned short)((ub + 0x7fffu + ((ub >> 16) & 1u)) >> 16);
        float dd = s - row[t];
        red[t] = dd * dd;
        __syncthreads();
        for (int off = 64; off > 0; off >>= 1) { if (t < off) red[t] += red[t + off]; __syncthreads(); }
        if (t == 0) atomicAdd(&acc[0], red[0]);
    } else {
        int i = blk - NB;
        comb[(NB + i) * D + t] = X[(long)idx[i] * D + t];
    }
}

// ---- D2[i][j] = ||comb_i - comb_j||^2  (512x512) ----
__global__ void k_d2(const float* __restrict__ comb, float* __restrict__ D2w)
{
    __shared__ float ci[D];
    __shared__ float cj[64][D + 4];
    const int i = blockIdx.x, jb = blockIdx.y, t = threadIdx.x; // 64 threads
    ci[t] = comb[i * D + t];
    ci[t + 64] = comb[i * D + t + 64];
    const float4* src = (const float4*)(comb + (jb * 64) * D);
    #pragma unroll
    for (int m = 0; m < 32; m++) {
        int u = m * 64 + t;
        int r = u >> 5, c = u & 31;
        float4 v = src[u];
        cj[r][c * 4 + 0] = v.x; cj[r][c * 4 + 1] = v.y; cj[r][c * 4 + 2] = v.z; cj[r][c * 4 + 3] = v.w;
    }
    __syncthreads();
    float s = 0.f;
    #pragma unroll 4
    for (int k = 0; k < D; k++) { float d = ci[k] - cj[t][k]; s = fmaf(d, d, s); }
    D2w[i * 512 + jb * 64 + t] = s;
}

// ---- radix-select histograms for exact median of D2 ----
__global__ void k_hist(const float* __restrict__ D2w, unsigned* __restrict__ hist,
                       const unsigned* __restrict__ sel, int pass)
{
    __shared__ unsigned h[8192];
    const int t = threadIdx.x;
    for (int m = t; m < 8192; m += 256) h[m] = 0;
    __syncthreads();
    unsigned p0 = 0, p1 = 0;
    if (pass) { p0 = sel[0]; p1 = sel[2]; }
    const int e0 = blockIdx.x * 1024;
    for (int m = 0; m < 4; m++) {
        unsigned key = __float_as_uint(D2w[e0 + m * 256 + t]);
        if (pass == 0) atomicAdd(&h[key >> 20], 1u);
        else if (pass == 1) {
            if ((key >> 20) == p0) atomicAdd(&h[(key >> 8) & 0xFFFu], 1u);
            if ((key >> 20) == p1) atomicAdd(&h[4096 + ((key >> 8) & 0xFFFu)], 1u);
        } else {
            if ((key >> 8) == p0) atomicAdd(&h[key & 0xFFu], 1u);
            if ((key >> 8) == p1) atomicAdd(&h[4096 + (key & 0xFFu)], 1u);
        }
    }
    __syncthreads();
    unsigned* g = hist + pass * 8192;
    for (int m = t; m < 8192; m += 256) { unsigned vv = h[m]; if (vv) atomicAdd(&g[m], vv); }
}

__global__ void k_scan(const unsigned* __restrict__ hist, unsigned* __restrict__ sel,
                       float* __restrict__ acc, int pass)
{
    __shared__ unsigned part[256];
    __shared__ unsigned res[4];
    const int t = threadIdx.x;
    const int nb = (pass == 2) ? 256 : 4096;
    const int per = nb / 256;
    unsigned rank0 = (pass == 0) ? 131071u : sel[1];
    unsigned rank1 = (pass == 0) ? 131072u : sel[3];
    for (int tg = 0; tg < 2; tg++) {
        const unsigned* h = hist + pass * 8192 + ((pass == 0) ? 0 : tg * 4096);
        unsigned s = 0;
        for (int m = 0; m < per; m++) s += h[t * per + m];
        part[t] = s;
        __syncthreads();
        if (t == 0) {
            unsigned r = (tg == 0) ? rank0 : rank1;
            int c = 0;
            while (part[c] <= r) { r -= part[c]; c++; }
            int bidx = c * per;
            while (h[bidx] <= r) { r -= h[bidx]; bidx++; }
            res[2 * tg] = (unsigned)bidx; res[2 * tg + 1] = r;
        }
        __syncthreads();
    }
    if (t == 0) {
        if (pass == 0) { sel[0] = res[0]; sel[1] = res[1]; sel[2] = res[2]; sel[3] = res[3]; }
        else if (pass == 1) { sel[0] = (sel[0] << 12) | res[0]; sel[1] = res[1];
                              sel[2] = (sel[2] << 12) | res[2]; sel[3] = res[3]; }
        else {
            unsigned k0 = (sel[0] << 8) | res[0];
            unsigned k1 = (sel[2] << 8) | res[2];
            float med = 0.5f * (__uint_as_float(k0) + __uint_as_float(k1));
            float ssq = 0.5f * med;
            if (ssq < 1e-6f) ssq = 1.0f;
            acc[5] = 1.0f / (ssq + 1e-8f);
            acc[6] = med;
        }
    }
}

// ---- MMD quadrant exp sums ----
__global__ void k_mmd(const float* __restrict__ D2w, float* __restrict__ acc)
{
    const int t = threadIdx.x;
    const float g = acc[5];
    float s[3] = {0.f, 0.f, 0.f};
    const int e0 = blockIdx.x * 1024;
    #pragma unroll
    for (int m = 0; m < 4; m++) {
        int e = e0 + m * 256 + t;
        int i = e >> 9, j = e & 511;
        float v = expf(-g * D2w[e]);
        int qd = (i < 256) ? ((j < 256) ? 0 : 2) : ((j < 256) ? 2 : 1);
        s[qd] += v;
    }
    #pragma unroll
    for (int c = 0; c < 3; c++) {
        float x = s[c];
        #pragma unroll
        for (int off = 32; off > 0; off >>= 1) x += __shfl_down(x, off);
        if ((t & 63) == 0 && x != 0.f) atomicAdd(&acc[2 + c], x);
    }
}

// ---- xnorm[j] = ||X_j||^2 ----
__global__ void k_xnorm(const float* __restrict__ X, float* __restrict__ xn)
{
    __shared__ float rsum[32];
    const int t = threadIdx.x;
    const long base4 = (long)blockIdx.x * 1024;
    const float4* src = (const float4*)X;
    for (int m = 0; m < 4; m++) {
        float4 v = src[base4 + m * 256 + t];
        float s = v.x * v.x + v.y * v.y + v.z * v.z + v.w * v.w;
        for (int off = 16; off > 0; off >>= 1) s += __shfl_down(s, off, 32);
        if ((t & 31) == 0) rsum[m * 8 + (t >> 5)] = s;
    }
    __syncthreads();
    if (t < 32) xn[blockIdx.x * 32 + t] = rsum[t];
}

// ---- bf16 MFMA score pass: S[q][r] ~= xn[r] - 2*dot(Tq_q, X_r) ----
// mode 0: write sample scores (rows 0..4095) to samp. mode 1: filter-append cand indices.
// Block: 256 thr = 4 waves in 2x2; tile 128q x 128r; per wave 64x64 via 4x4 MFMA 16x16x32.
__global__ __launch_bounds__(256) void k_mf(const unsigned short* __restrict__ tqbf,
    const float* __restrict__ X, const float* __restrict__ xn,
    const float* __restrict__ thr, float* __restrict__ samp,
    int* __restrict__ cand_i, unsigned* __restrict__ cnt, int mode)
{
    const int t = threadIdx.x;
    const int w = t >> 6, lane = t & 63;
    const int qbase = blockIdx.y * 128 + (w >> 1) * 64;
    const int rbase = blockIdx.x * 128 + (w & 1) * 64;
    const int lr = lane & 15, quad = lane >> 4;

    f32x4 acc[4][4];
    #pragma unroll
    for (int i = 0; i < 4; i++)
        #pragma unroll
        for (int j = 0; j < 4; j++) acc[i][j] = (f32x4){0.f, 0.f, 0.f, 0.f};

    #pragma unroll
    for (int ks = 0; ks < 4; ks++) {
        const int koff = ks * 32 + quad * 8;
        bf16x8 a[4], b[4];
        #pragma unroll
        for (int i = 0; i < 4; i++)
            a[i] = *(const bf16x8*)(tqbf + (qbase + i * 16 + lr) * D + koff);
        #pragma unroll
        for (int j = 0; j < 4; j++) {
            int r = rbase + j * 16 + lr; if (r > NPTS - 1) r = NPTS - 1;
            const uint4 u0 = *(const uint4*)(X + (long)r * D + koff);
            const uint4 u1 = *(const uint4*)(X + (long)r * D + koff + 4);
            bf16x8 bv;
            bv[0] = (short)(u0.x >> 16); bv[1] = (short)(u0.y >> 16);
            bv[2] = (short)(u0.z >> 16); bv[3] = (short)(u0.w >> 16);
            bv[4] = (short)(u1.x >> 16); bv[5] = (short)(u1.y >> 16);
            bv[6] = (short)(u1.z >> 16); bv[7] = (short)(u1.w >> 16);
            b[j] = bv;
        }
        #pragma unroll
        for (int i = 0; i < 4; i++)
            #pragma unroll
            for (int j = 0; j < 4; j++)
                acc[i][j] = __builtin_amdgcn_mfma_f32_16x16x32_bf16(a[i], b[j], acc[i][j], 0, 0, 0);
    }

    // C/D layout: col = lane&15 (r), row = quad*4+reg (q)
    if (mode == 0) {
        #pragma unroll
        for (int i = 0; i < 4; i++) {
            #pragma unroll
            for (int reg = 0; reg < 4; reg++) {
                int qq = qbase + i * 16 + quad * 4 + reg;
                #pragma unroll
                for (int j = 0; j < 4; j++) {
                    int r = rbase + j * 16 + lr;
                    samp[qq * NSAMP + r] = xn[r] - 2.f * acc[i][j][reg];
                }
            }
        }
    } else {
        #pragma unroll
        for (int i = 0; i < 4; i++) {
            #pragma unroll
            for (int reg = 0; reg < 4; reg++) {
                int qq = qbase + i * 16 + quad * 4 + reg;
                float th = thr[qq];
                #pragma unroll
                for (int j = 0; j < 4; j++) {
                    int r = rbase + j * 16 + lr;
                    if (r < NPTS) {
                        float s = xn[r] - 2.f * acc[i][j][reg];
                        if (s <= th) {
                            unsigned pos = atomicAdd(&cnt[qq * 16], 1u);
                            if (pos < CAP) cand_i[qq * CAP + pos] = r;
                        }
                    }
                }
            }
        }
    }
}

// ---- per-query exact 50th-smallest of sample bf16-scores -> thr (+slack) ----
__global__ void k_thr(const float* __restrict__ samp, float* __restrict__ thr)
{
    __shared__ unsigned ks[NSAMP];
    __shared__ unsigned wred[4];
    const int q = blockIdx.x, t = threadIdx.x;
    for (int m = t; m < NSAMP; m += 256) ks[m] = fkey(samp[q * NSAMP + m]);
    __syncthreads();
    unsigned v = 0;
    for (int bit = 31; bit >= 0; bit--) {
        unsigned trial = v | (1u << bit);
        unsigned c = 0;
        for (int m = t; m < NSAMP; m += 256) c += (ks[m] < trial) ? 1u : 0u;
        #pragma unroll
        for (int off = 32; off > 0; off >>= 1) c += __shfl_down(c, off);
        if ((t & 63) == 0) wred[t >> 6] = c;
        __syncthreads();
        unsigned total = wred[0] + wred[1] + wred[2] + wred[3];
        __syncthreads();
        if (total <= (unsigned)(KNN - 1)) v = trial;
    }
    if (t == 0) {
        unsigned orig = (v & 0x80000000u) ? (v ^ 0x80000000u) : ~v;
        thr[q] = __uint_as_float(orig) + SLACK;
    }
}

// ---- exact f32 rescore of candidates ----
__global__ void k_rescore(const float* __restrict__ comb, const float* __restrict__ X,
                          const float* __restrict__ xn, const int* __restrict__ cand_i,
                          const unsigned* __restrict__ cnt, float* __restrict__ cand_s)
{
    __shared__ float qrow[D];
    const int q = blockIdx.x, t = threadIdx.x;
    if (t < D) qrow[t] = comb[q * D + t];
    __syncthreads();
    unsigned nn = cnt[q * 16];
    const int n = (nn < (unsigned)CAP) ? (int)nn : CAP;
    const int g = t >> 3, j = t & 7; // 32 groups of 8 lanes
    for (int m = g; m < n; m += 32) {
        int r = cand_i[q * CAP + m];
        const float4* xr = (const float4*)(X + (long)r * D);
        float s = 0.f;
        #pragma unroll
        for (int p = 0; p < 4; p++) {
            float4 xv = xr[j * 4 + p];
            float4 qv = *(const float4*)&qrow[(j * 4 + p) * 4];
            s = fmaf(xv.x, qv.x, fmaf(xv.y, qv.y, fmaf(xv.z, qv.z, fmaf(xv.w, qv.w, s))));
        }
        s += __shfl_down(s, 4); s += __shfl_down(s, 2); s += __shfl_down(s, 1);
        if (j == 0) cand_s[q * CAP + m] = xn[r] - 2.f * s;
    }
}

// ---- exact top-50 from rescored candidates (boundary ties -> smallest index) ----
__global__ void k_select(const float* __restrict__ cand_s, const int* __restrict__ cand_i,
                         const unsigned* __restrict__ cnt, int* __restrict__ post_idx)
{
    __shared__ unsigned ks[CAP];
    __shared__ unsigned wred[4];
    __shared__ unsigned wpos, eqn;
    __shared__ int eq[64];
    const int q = blockIdx.x, t = threadIdx.x;
    unsigned nn = cnt[q * 16];
    const int n = (nn < (unsigned)CAP) ? (int)nn : CAP;
    for (int m = t; m < n; m += 256) ks[m] = fkey(cand_s[q * CAP + m]);
    __syncthreads();
    int kk = KNN - 1; if (kk > n - 1) kk = n - 1;
    unsigned v = 0;
    for (int bit = 31; bit >= 0; bit--) {
        unsigned trial = v | (1u << bit);
        unsigned c = 0;
        for (int m = t; m < n; m += 256) c += (ks[m] < trial) ? 1u : 0u;
        #pragma unroll
        for (int off = 32; off > 0; off >>= 1) c += __shfl_down(c, off);
        if ((t & 63) == 0) wred[t >> 6] = c;
        __syncthreads();
        unsigned total = wred[0] + wred[1] + wred[2] + wred[3];
        __syncthreads();
        if (total <= (unsigned)kk) v = trial;
    }
    if (t == 0) { wpos = 0; eqn = 0; }
    __syncthreads();
    for (int m = t; m < n; m += 256) {
        if (ks[m] < v) {
            unsigned p = atomicAdd(&wpos, 1u);
            post_idx[q * KNN + p] = cand_i[q * CAP + m];
        } else if (ks[m] == v) {
            unsigned p = atomicAdd(&eqn, 1u);
            if (p < 64) eq[p] = cand_i[q * CAP + m];
        }
    }
    __syncthreads();
    if (t == 0) {
        int c1 = (int)wpos;
        int need = KNN - c1;
        int ne = (eqn < 64u) ? (int)eqn : 64;
        for (int a = 0; a < ne; a++)
            for (int b2 = a + 1; b2 < ne; b2++)
                if (eq[b2] < eq[a]) { int tmp = eq[a]; eq[a] = eq[b2]; eq[b2] = tmp; }
        for (int a = 0; a < need && a < ne; a++) post_idx[q * KNN + c1 + a] = eq[a];
    }
}

// ---- exact l2 to selected neighbors + softmax(-l2/tau) ----
__global__ void k_l2sm(const float* __restrict__ comb, const float* __restrict__ X,
                       const int* __restrict__ post_idx, float* __restrict__ post_w)
{
    __shared__ float l2s[KNN];
    __shared__ float qrow[D];
    const int q = blockIdx.x, t = threadIdx.x;
    const int w = t >> 6, l = t & 63;
    if (t < D) qrow[t] = comb[q * D + t];
    __syncthreads();
    for (int nb = w; nb < KNN; nb += 4) {
        long j = post_idx[q * KNN + nb];
        float d0 = qrow[l] - X[j * D + l];
        float d1 = qrow[l + 64] - X[j * D + l + 64];
        float s = d0 * d0 + d1 * d1;
        #pragma unroll
        for (int off = 32; off > 0; off >>= 1) s += __shfl_down(s, off);
        if (l == 0) l2s[nb] = s;
    }
    __syncthreads();
    if (t < 64) {
        float logit = (t < KNN) ? (-l2s[t] * 10.0f) : -3.4e38f; // 1/tau = 10
        float m = logit;
        #pragma unroll
        for (int off = 32; off > 0; off >>= 1) m = fmaxf(m, __shfl_down(m, off));
        m = __shfl(m, 0);
        float e = (t < KNN) ? expf(logit - m) : 0.f;
        float ssum = e;
        #pragma unroll
        for (int off = 32; off > 0; off >>= 1) ssum += __shfl_down(ssum, off);
        ssum = __shfl(ssum, 0);
        if (t < KNN) post_w[q * KNN + t] = e / ssum;
    }
}

// ---- union-KL with exact multiplicity semantics ----
__global__ void k_kl(const int* __restrict__ pri, const float* __restrict__ prw,
                     const int* __restrict__ qix, const int* __restrict__ post_idx,
                     const float* __restrict__ post_w, float* __restrict__ acc)
{
    __shared__ int ci[100];
    __shared__ float pwv[50], qwv[50];
    __shared__ float pterm[100], qterm[100], kterm[100];
    __shared__ float Sp, Sq;
    const int b = blockIdx.x, t = threadIdx.x;
    int qi = qix[b];
    if (t < 50) { ci[t] = pri[qi * 50 + t]; pwv[t] = prw[qi * 50 + t]; }
    else if (t < 100) { int k = t - 50; ci[t] = post_idx[b * 50 + k]; qwv[k] = post_w[b * 50 + k]; }
    __syncthreads();
    float pc = 0.f, qc = 0.f, mult = 0.f;
    if (t < 100) {
        int c = ci[t];
        float pr = 0.f, qr = 0.f;
        for (int k = 0; k < 50; k++) {
            bool m1 = (c == ci[k]); bool m2 = (c == ci[50 + k]);
            mult += (m1 ? 1.f : 0.f) + (m2 ? 1.f : 0.f);
            pr += m1 ? pwv[k] : 0.f;
            qr += m2 ? qwv[k] : 0.f;
        }
        pc = fmaxf(pr, 1e-8f); qc = fmaxf(qr, 1e-8f);
        pterm[t] = pc / mult; qterm[t] = qc / mult;
    }
    __syncthreads();
    if (t == 0) { float a = 0.f, b2 = 0.f; for (int m = 0; m < 100; m++) { a += pterm[m]; b2 += qterm[m]; } Sp = a; Sq = b2; }
    __syncthreads();
    if (t < 100) {
        float p = pc / Sp, qq = qc / Sq;
        kterm[t] = (p * (logf(p) - logf(qq))) / mult;
    }
    __syncthreads();
    if (t == 0) { float s = 0.f; for (int m = 0; m < 100; m++) s += kterm[m]; atomicAdd(&acc[1], s); }
}

// ---- reg + final assembly ----
__global__ void k_final(const float* __restrict__ W, const float* __restrict__ bb,
                        const float* __restrict__ acc, float* __restrict__ out)
{
    __shared__ float red[256];
    const int t = threadIdx.x;
    float s = 0.f;
    for (int m = t; m < D * D; m += 256) { float v = W[m]; s += v * v; }
    if (t < D) { float v = bb[t]; s += v * v; }
    red[t] = s;
    __syncthreads();
    for (int off = 128; off > 0; off >>= 1) { if (t < off) red[t] += red[t + off]; __syncthreads(); }
    if (t == 0) {
        float reg = 0.5f * red[0];
        float kxx = acc[2] / 65536.f, kyy = acc[3] / 65536.f, kxy = acc[4] / 131072.f;
        float ld = fmaxf(kxx + kyy - 2.f * kxy, 0.f);
        float lknn = acc[1] / 256.f;
        float lanc = acc[0] / 256.f;
        float total = ld + lknn + 1e-4f * reg + lanc;
        out[0] = total; out[1] = ld; out[2] = lknn; out[3] = lanc;
    }
}

extern "C" void kernel_launch(void* const* d_in, const int* in_sizes, int n_in,
                              void* d_out, int out_size, void* d_ws, size_t ws_size,
                              hipStream_t stream)
{
    (void)in_sizes; (void)n_in; (void)out_size; (void)ws_size;
    const float* q   = (const float*)d_in[0];
    const float* X   = (const float*)d_in[1];
    const float* W   = (const float*)d_in[2];
    const float* bb  = (const float*)d_in[3];
    const float* prw = (const float*)d_in[4];
    const int*   pri = (const int*)d_in[5];
    const int*   qix = (const int*)d_in[6];
    const int*   idx = (const int*)d_in[7];
    float* out = (float*)d_out;
    char* ws = (char*)d_ws;
    float*    acc  = (float*)(ws + OFF_ACC);
    unsigned* sel  = (unsigned*)(ws + OFF_SEL);
    unsigned* hist = (unsigned*)(ws + OFF_HIST);
    unsigned* cnt  = (unsigned*)(ws + OFF_CNT);
    float*    comb = (float*)(ws + OFF_COMB);
    float*    D2w  = (float*)(ws + OFF_D2);
    float*    xn   = (float*)(ws + OFF_XNORM);
    float*    samp = (float*)(ws + OFF_SAMP);
    float*    thr  = (float*)(ws + OFF_THR);
    float*    cs   = (float*)(ws + OFF_CANDS);
    int*      cix  = (int*)(ws + OFF_CANDI);
    int*      pix  = (int*)(ws + OFF_PIDX);
    float*    pw   = (float*)(ws + OFF_PW);
    unsigned short* tqbf = (unsigned short*)(ws + OFF_TQBF);

    hipMemsetAsync(ws, 0, 131072, stream);
    hipLaunchKernelGGL(k_prep,   dim3(512),      dim3(128), 0, stream, q, X, W, bb, idx, comb, tqbf, acc);
    hipLaunchKernelGGL(k_d2,     dim3(512, 8),   dim3(64),  0, stream, comb, D2w);
    hipLaunchKernelGGL(k_hist,   dim3(256),      dim3(256), 0, stream, D2w, hist, sel, 0);
    hipLaunchKernelGGL(k_scan,   dim3(1),        dim3(256), 0, stream, hist, sel, acc, 0);
    hipLaunchKernelGGL(k_hist,   dim3(256),      dim3(256), 0, stream, D2w, hist, sel, 1);
    hipLaunchKernelGGL(k_scan,   dim3(1),        dim3(256), 0, stream, hist, sel, acc, 1);
    hipLaunchKernelGGL(k_hist,   dim3(256),      dim3(256), 0, stream, D2w, hist, sel, 2);
    hipLaunchKernelGGL(k_scan,   dim3(1),        dim3(256), 0, stream, hist, sel, acc, 2);
    hipLaunchKernelGGL(k_mmd,    dim3(256),      dim3(256), 0, stream, D2w, acc);
    hipLaunchKernelGGL(k_xnorm,  dim3(6250),     dim3(256), 0, stream, X, xn);
    hipLaunchKernelGGL(k_mf,     dim3(32, 2),    dim3(256), 0, stream, tqbf, X, xn, thr, samp, cix, cnt, 0);
    hipLaunchKernelGGL(k_thr,    dim3(256),      dim3(256), 0, stream, samp, thr);
    hipLaunchKernelGGL(k_mf,     dim3(1563, 2),  dim3(256), 0, stream, tqbf, X, xn, thr, samp, cix, cnt, 1);
    hipLaunchKernelGGL(k_rescore,dim3(256),      dim3(256), 0, stream, comb, X, xn, cix, cnt, cs);
    hipLaunchKernelGGL(k_select, dim3(256),      dim3(256), 0, stream, cs, cix, cnt, pix);
    hipLaunchKernelGGL(k_l2sm,   dim3(256),      dim3(256), 0, stream, comb, X, pix, pw);
    hipLaunchKernelGGL(k_kl,     dim3(256),      dim3(128), 0, stream, pri, prw, qix, pix, pw, acc);
    hipLaunchKernelGGL(k_final,  dim3(1),        dim3(256), 0, stream, W, bb, acc, out);
}

// Round 3
// 575.620 us; speedup vs baseline: 2.8681x; 1.4783x over previous
//
#include <hip/hip_runtime.h>
#include <cstdint>

#define D 128
#define NB 256
#define NPTS 200000
#define KNN 50
#define CAP 8192
#define NS_SMALL 4096
#define NS_BIG 8192
#define SLACK 2.0f
#define NRT 12500   // row tiles of 16

// ---- workspace byte offsets (first 23.3 MB identical to known-good round-2 layout) ----
#define OFF_ACC      0        // 32 floats (zeroed)
#define OFF_SEL      256      // 16 uint  (zeroed)
#define OFF_HIST     512      // 3*2*4096 u32 (zeroed)
#define OFF_CNT      102400   // 256*16 u32 (zeroed; one counter per 64B line)
#define OFF_COMB     131072   // 512*128 f32
#define OFF_D2       393216   // 262144 f32
#define OFF_XNORM    1441792  // 200000 f32
#define OFF_SAMP4    2241792  // 256*4096 f32 (fallback)
#define OFF_THR      6436096  // 256 f32
#define OFF_CANDS    6437120  // 256*8192 f32
#define OFF_CANDI    14825728 // 256*8192 i32
#define OFF_PIDX     23214336 // 256*50 i32
#define OFF_PW       23265536 // 256*50 f32
#define OFF_TQBF     23316992 // 256*128 bf16 linear (fallback)
// ---- appended for fast path ----
#define OFF_TQSW     23382528 // 256*128 bf16 swizzled (16 qtiles * 2048 ushorts)
#define OFF_SAMP8    23448064 // 256*8192 f32
#define OFF_XBF      31836672 // 200000*128 bf16 swizzled = 51,200,000 B
#define WS_NEED_BIG  83036672ull

typedef __attribute__((ext_vector_type(8))) short bf16x8;
typedef __attribute__((ext_vector_type(4))) float f32x4;

__device__ __forceinline__ unsigned fkey(float f) {
    unsigned u = __float_as_uint(f);
    return u ^ ((unsigned)((int)u >> 31) | 0x80000000u);
}

// ---- Tq = q @ W^T + b ; writes comb, linear tqbf (RNE) and swizzled tqsw ; X[idx] rows ----
__global__ void k_prep(const float* __restrict__ q, const float* __restrict__ X,
                       const float* __restrict__ W, const float* __restrict__ bb,
                       const int* __restrict__ idx, float* __restrict__ comb,
                       unsigned short* __restrict__ tqbf, unsigned short* __restrict__ tqsw,
                       float* __restrict__ acc)
{
    __shared__ float row[D];
    __shared__ float red[D];
    const int blk = blockIdx.x, t = threadIdx.x;
    if (blk < NB) {
        row[t] = q[blk * D + t];
        __syncthreads();
        float s = 0.f;
        const float* wr = W + t * D;
        #pragma unroll 4
        for (int k = 0; k < D; k++) s = fmaf(row[k], wr[k], s);
        s += bb[t];
        comb[blk * D + t] = s;
        unsigned ub = __float_as_uint(s);
        unsigned short h = (unsigned short)((ub + 0x7fffu + ((ub >> 16) & 1u)) >> 16);
        tqbf[blk * D + t] = h;
        // swizzled: [qtile][ks][quad*16+lr][8]
        {
            int ks = t >> 5, quad = (t & 31) >> 3, j = t & 7;
            int lane = quad * 16 + (blk & 15);
            tqsw[(blk >> 4) * 2048 + ks * 512 + lane * 8 + j] = h;
        }
        float dd = s - row[t];
        red[t] = dd * dd;
        __syncthreads();
        for (int off = 64; off > 0; off >>= 1) { if (t < off) red[t] += red[t + off]; __syncthreads(); }
        if (t == 0) atomicAdd(&acc[0], red[0]);
    } else {
        int i = blk - NB;
        comb[(NB + i) * D + t] = X[(long)idx[i] * D + t];
    }
}

// ---- cast X -> swizzled bf16 fragments + xnorm (fast path) ----
__global__ void k_cast(const float* __restrict__ X, unsigned short* __restrict__ xbf,
                       float* __restrict__ xn)
{
    __shared__ float xr[16];
    const int rt = blockIdx.x, t = threadIdx.x;
    const int lr = t & 15, c = t >> 4;
    if (t < 16) xr[t] = 0.f;
    const float4* src = (const float4*)(X + ((long)(rt * 16 + lr)) * D + c * 8);
    float4 v0 = src[0], v1 = src[1];
    __syncthreads();
    uint4 pk;
    pk.x = (__float_as_uint(v0.x) >> 16) | (__float_as_uint(v0.y) & 0xFFFF0000u);
    pk.y = (__float_as_uint(v0.z) >> 16) | (__float_as_uint(v0.w) & 0xFFFF0000u);
    pk.z = (__float_as_uint(v1.x) >> 16) | (__float_as_uint(v1.y) & 0xFFFF0000u);
    pk.w = (__float_as_uint(v1.z) >> 16) | (__float_as_uint(v1.w) & 0xFFFF0000u);
    *(uint4*)(xbf + (long)rt * 2048 + t * 8) = pk;
    float ssq = v0.x*v0.x + v0.y*v0.y + v0.z*v0.z + v0.w*v0.w
              + v1.x*v1.x + v1.y*v1.y + v1.z*v1.z + v1.w*v1.w;
    atomicAdd(&xr[lr], ssq);
    __syncthreads();
    if (t < 16) xn[rt * 16 + t] = xr[t];
}

// ---- D2[i][j] = ||comb_i - comb_j||^2  (512x512) ----
__global__ void k_d2(const float* __restrict__ comb, float* __restrict__ D2w)
{
    __shared__ float ci[D];
    __shared__ float cj[64][D + 4];
    const int i = blockIdx.x, jb = blockIdx.y, t = threadIdx.x; // 64 threads
    ci[t] = comb[i * D + t];
    ci[t + 64] = comb[i * D + t + 64];
    const float4* src = (const float4*)(comb + (jb * 64) * D);
    #pragma unroll
    for (int m = 0; m < 32; m++) {
        int u = m * 64 + t;
        int r = u >> 5, c = u & 31;
        float4 v = src[u];
        cj[r][c * 4 + 0] = v.x; cj[r][c * 4 + 1] = v.y; cj[r][c * 4 + 2] = v.z; cj[r][c * 4 + 3] = v.w;
    }
    __syncthreads();
    float s = 0.f;
    #pragma unroll 4
    for (int k = 0; k < D; k++) { float d = ci[k] - cj[t][k]; s = fmaf(d, d, s); }
    D2w[i * 512 + jb * 64 + t] = s;
}

// ---- radix-select histograms for exact median of D2 ----
__global__ void k_hist(const float* __restrict__ D2w, unsigned* __restrict__ hist,
                       const unsigned* __restrict__ sel, int pass)
{
    __shared__ unsigned h[8192];
    const int t = threadIdx.x;
    for (int m = t; m < 8192; m += 256) h[m] = 0;
    __syncthreads();
    unsigned p0 = 0, p1 = 0;
    if (pass) { p0 = sel[0]; p1 = sel[2]; }
    const int e0 = blockIdx.x * 1024;
    for (int m = 0; m < 4; m++) {
        unsigned key = __float_as_uint(D2w[e0 + m * 256 + t]);
        if (pass == 0) atomicAdd(&h[key >> 20], 1u);
        else if (pass == 1) {
            if ((key >> 20) == p0) atomicAdd(&h[(key >> 8) & 0xFFFu], 1u);
            if ((key >> 20) == p1) atomicAdd(&h[4096 + ((key >> 8) & 0xFFFu)], 1u);
        } else {
            if ((key >> 8) == p0) atomicAdd(&h[key & 0xFFu], 1u);
            if ((key >> 8) == p1) atomicAdd(&h[4096 + (key & 0xFFu)], 1u);
        }
    }
    __syncthreads();
    unsigned* g = hist + pass * 8192;
    for (int m = t; m < 8192; m += 256) { unsigned vv = h[m]; if (vv) atomicAdd(&g[m], vv); }
}

__global__ void k_scan(const unsigned* __restrict__ hist, unsigned* __restrict__ sel,
                       float* __restrict__ acc, int pass)
{
    __shared__ unsigned part[256];
    __shared__ unsigned res[4];
    const int t = threadIdx.x;
    const int nb = (pass == 2) ? 256 : 4096;
    const int per = nb / 256;
    unsigned rank0 = (pass == 0) ? 131071u : sel[1];
    unsigned rank1 = (pass == 0) ? 131072u : sel[3];
    for (int tg = 0; tg < 2; tg++) {
        const unsigned* h = hist + pass * 8192 + ((pass == 0) ? 0 : tg * 4096);
        unsigned s = 0;
        for (int m = 0; m < per; m++) s += h[t * per + m];
        part[t] = s;
        __syncthreads();
        if (t == 0) {
            unsigned r = (tg == 0) ? rank0 : rank1;
            int c = 0;
            while (part[c] <= r) { r -= part[c]; c++; }
            int bidx = c * per;
            while (h[bidx] <= r) { r -= h[bidx]; bidx++; }
            res[2 * tg] = (unsigned)bidx; res[2 * tg + 1] = r;
        }
        __syncthreads();
    }
    if (t == 0) {
        if (pass == 0) { sel[0] = res[0]; sel[1] = res[1]; sel[2] = res[2]; sel[3] = res[3]; }
        else if (pass == 1) { sel[0] = (sel[0] << 12) | res[0]; sel[1] = res[1];
                              sel[2] = (sel[2] << 12) | res[2]; sel[3] = res[3]; }
        else {
            unsigned k0 = (sel[0] << 8) | res[0];
            unsigned k1 = (sel[2] << 8) | res[2];
            float med = 0.5f * (__uint_as_float(k0) + __uint_as_float(k1));
            float ssq = 0.5f * med;
            if (ssq < 1e-6f) ssq = 1.0f;
            acc[5] = 1.0f / (ssq + 1e-8f);
            acc[6] = med;
        }
    }
}

// ---- MMD quadrant exp sums ----
__global__ void k_mmd(const float* __restrict__ D2w, float* __restrict__ acc)
{
    const int t = threadIdx.x;
    const float g = acc[5];
    float s[3] = {0.f, 0.f, 0.f};
    const int e0 = blockIdx.x * 1024;
    #pragma unroll
    for (int m = 0; m < 4; m++) {
        int e = e0 + m * 256 + t;
        int i = e >> 9, j = e & 511;
        float v = expf(-g * D2w[e]);
        int qd = (i < 256) ? ((j < 256) ? 0 : 2) : ((j < 256) ? 2 : 1);
        s[qd] += v;
    }
    #pragma unroll
    for (int c = 0; c < 3; c++) {
        float x = s[c];
        #pragma unroll
        for (int off = 32; off > 0; off >>= 1) x += __shfl_down(x, off);
        if ((t & 63) == 0 && x != 0.f) atomicAdd(&acc[2 + c], x);
    }
}

// ---- xnorm[j] = ||X_j||^2 (fallback path only) ----
__global__ void k_xnorm(const float* __restrict__ X, float* __restrict__ xn)
{
    __shared__ float rsum[32];
    const int t = threadIdx.x;
    const long base4 = (long)blockIdx.x * 1024;
    const float4* src = (const float4*)X;
    for (int m = 0; m < 4; m++) {
        float4 v = src[base4 + m * 256 + t];
        float s = v.x * v.x + v.y * v.y + v.z * v.z + v.w * v.w;
        for (int off = 16; off > 0; off >>= 1) s += __shfl_down(s, off, 32);
        if ((t & 31) == 0) rsum[m * 8 + (t >> 5)] = s;
    }
    __syncthreads();
    if (t < 32) xn[blockIdx.x * 32 + t] = rsum[t];
}

// ---- FAST PATH MFMA score pass on pre-swizzled bf16 fragments ----
// Block 256 thr = 4 waves; wave w covers q[w*64 .. w*64+63], block covers 64 rows.
// mode 0: write sample scores (rows = blockIdx.x*64, grid 128 -> rows 0..8191).
// mode 1: filter-append candidate indices (grid 3125 -> rows 0..199999).
__global__ __launch_bounds__(256) void k_mf_sw(const unsigned short* __restrict__ tqsw,
    const unsigned short* __restrict__ xbf, const float* __restrict__ xn,
    const float* __restrict__ thr, float* __restrict__ samp,
    int* __restrict__ cand_i, unsigned* __restrict__ cnt, int mode)
{
    const int t = threadIdx.x;
    const int w = t >> 6, lane = t & 63;
    const int lr = lane & 15, quad = lane >> 4;
    const long rb = (long)blockIdx.x * 8192; // 4 rtiles * 2048 ushorts

    f32x4 acc[4][4];
    #pragma unroll
    for (int i = 0; i < 4; i++)
        #pragma unroll
        for (int j = 0; j < 4; j++) acc[i][j] = (f32x4){0.f, 0.f, 0.f, 0.f};

    #pragma unroll
    for (int ks = 0; ks < 4; ks++) {
        bf16x8 a[4], b[4];
        #pragma unroll
        for (int i = 0; i < 4; i++)
            a[i] = *(const bf16x8*)(tqsw + (w * 4 + i) * 2048 + ks * 512 + lane * 8);
        #pragma unroll
        for (int j = 0; j < 4; j++)
            b[j] = *(const bf16x8*)(xbf + rb + j * 2048 + ks * 512 + lane * 8);
        #pragma unroll
        for (int i = 0; i < 4; i++)
            #pragma unroll
            for (int j = 0; j < 4; j++)
                acc[i][j] = __builtin_amdgcn_mfma_f32_16x16x32_bf16(a[i], b[j], acc[i][j], 0, 0, 0);
    }

    // C/D: col = lane&15 (r), row = quad*4+reg (q)
    if (mode == 0) {
        #pragma unroll
        for (int i = 0; i < 4; i++) {
            #pragma unroll
            for (int reg = 0; reg < 4; reg++) {
                int qq = w * 64 + i * 16 + quad * 4 + reg;
                #pragma unroll
                for (int j = 0; j < 4; j++) {
                    int r = blockIdx.x * 64 + j * 16 + lr;
                    samp[qq * NS_BIG + r] = xn[r] - 2.f * acc[i][j][reg];
                }
            }
        }
    } else {
        #pragma unroll
        for (int i = 0; i < 4; i++) {
            #pragma unroll
            for (int reg = 0; reg < 4; reg++) {
                int qq = w * 64 + i * 16 + quad * 4 + reg;
                float th = thr[qq];
                #pragma unroll
                for (int j = 0; j < 4; j++) {
                    int r = blockIdx.x * 64 + j * 16 + lr;
                    float s = xn[r] - 2.f * acc[i][j][reg];
                    if (s <= th) {
                        unsigned pos = atomicAdd(&cnt[qq * 16], 1u);
                        if (pos < CAP) cand_i[qq * CAP + pos] = r;
                    }
                }
            }
        }
    }
}

// ---- FALLBACK: round-2 direct-load MFMA pass (known good) ----
__global__ __launch_bounds__(256) void k_mf_direct(const unsigned short* __restrict__ tqbf,
    const float* __restrict__ X, const float* __restrict__ xn,
    const float* __restrict__ thr, float* __restrict__ samp,
    int* __restrict__ cand_i, unsigned* __restrict__ cnt, int mode)
{
    const int t = threadIdx.x;
    const int w = t >> 6, lane = t & 63;
    const int qbase = blockIdx.y * 128 + (w >> 1) * 64;
    const int rbase = blockIdx.x * 128 + (w & 1) * 64;
    const int lr = lane & 15, quad = lane >> 4;

    f32x4 acc[4][4];
    #pragma unroll
    for (int i = 0; i < 4; i++)
        #pragma unroll
        for (int j = 0; j < 4; j++) acc[i][j] = (f32x4){0.f, 0.f, 0.f, 0.f};

    #pragma unroll
    for (int ks = 0; ks < 4; ks++) {
        const int koff = ks * 32 + quad * 8;
        bf16x8 a[4], b[4];
        #pragma unroll
        for (int i = 0; i < 4; i++)
            a[i] = *(const bf16x8*)(tqbf + (qbase + i * 16 + lr) * D + koff);
        #pragma unroll
        for (int j = 0; j < 4; j++) {
            int r = rbase + j * 16 + lr; if (r > NPTS - 1) r = NPTS - 1;
            const uint4 u0 = *(const uint4*)(X + (long)r * D + koff);
            const uint4 u1 = *(const uint4*)(X + (long)r * D + koff + 4);
            bf16x8 bv;
            bv[0] = (short)(u0.x >> 16); bv[1] = (short)(u0.y >> 16);
            bv[2] = (short)(u0.z >> 16); bv[3] = (short)(u0.w >> 16);
            bv[4] = (short)(u1.x >> 16); bv[5] = (short)(u1.y >> 16);
            bv[6] = (short)(u1.z >> 16); bv[7] = (short)(u1.w >> 16);
            b[j] = bv;
        }
        #pragma unroll
        for (int i = 0; i < 4; i++)
            #pragma unroll
            for (int j = 0; j < 4; j++)
                acc[i][j] = __builtin_amdgcn_mfma_f32_16x16x32_bf16(a[i], b[j], acc[i][j], 0, 0, 0);
    }

    if (mode == 0) {
        #pragma unroll
        for (int i = 0; i < 4; i++) {
            #pragma unroll
            for (int reg = 0; reg < 4; reg++) {
                int qq = qbase + i * 16 + quad * 4 + reg;
                #pragma unroll
                for (int j = 0; j < 4; j++) {
                    int r = rbase + j * 16 + lr;
                    samp[qq * NS_SMALL + r] = xn[r] - 2.f * acc[i][j][reg];
                }
            }
        }
    } else {
        #pragma unroll
        for (int i = 0; i < 4; i++) {
            #pragma unroll
            for (int reg = 0; reg < 4; reg++) {
                int qq = qbase + i * 16 + quad * 4 + reg;
                float th = thr[qq];
                #pragma unroll
                for (int j = 0; j < 4; j++) {
                    int r = rbase + j * 16 + lr;
                    if (r < NPTS) {
                        float s = xn[r] - 2.f * acc[i][j][reg];
                        if (s <= th) {
                            unsigned pos = atomicAdd(&cnt[qq * 16], 1u);
                            if (pos < CAP) cand_i[qq * CAP + pos] = r;
                        }
                    }
                }
            }
        }
    }
}

// ---- per-query exact 50th-smallest of sample bf16-scores -> thr (+slack) ----
__global__ void k_thr(const float* __restrict__ samp, float* __restrict__ thr, int nsamp)
{
    __shared__ unsigned ks[NS_BIG];
    __shared__ unsigned wred[4];
    const int q = blockIdx.x, t = threadIdx.x;
    for (int m = t; m < nsamp; m += 256) ks[m] = fkey(samp[q * nsamp + m]);
    __syncthreads();
    unsigned v = 0;
    for (int bit = 31; bit >= 0; bit--) {
        unsigned trial = v | (1u << bit);
        unsigned c = 0;
        for (int m = t; m < nsamp; m += 256) c += (ks[m] < trial) ? 1u : 0u;
        #pragma unroll
        for (int off = 32; off > 0; off >>= 1) c += __shfl_down(c, off);
        if ((t & 63) == 0) wred[t >> 6] = c;
        __syncthreads();
        unsigned total = wred[0] + wred[1] + wred[2] + wred[3];
        __syncthreads();
        if (total <= (unsigned)(KNN - 1)) v = trial;
    }
    if (t == 0) {
        unsigned orig = (v & 0x80000000u) ? (v ^ 0x80000000u) : ~v;
        thr[q] = __uint_as_float(orig) + SLACK;
    }
}

// ---- exact f32 rescore of candidates ----
__global__ void k_rescore(const float* __restrict__ comb, const float* __restrict__ X,
                          const float* __restrict__ xn, const int* __restrict__ cand_i,
                          const unsigned* __restrict__ cnt, float* __restrict__ cand_s)
{
    __shared__ float qrow[D];
    const int q = blockIdx.x, t = threadIdx.x;
    if (t < D) qrow[t] = comb[q * D + t];
    __syncthreads();
    unsigned nn = cnt[q * 16];
    const int n = (nn < (unsigned)CAP) ? (int)nn : CAP;
    const int g = t >> 3, j = t & 7; // 32 groups of 8 lanes
    for (int m = g; m < n; m += 32) {
        int r = cand_i[q * CAP + m];
        const float4* xr = (const float4*)(X + (long)r * D);
        float s = 0.f;
        #pragma unroll
        for (int p = 0; p < 4; p++) {
            float4 xv = xr[j * 4 + p];
            float4 qv = *(const float4*)&qrow[(j * 4 + p) * 4];
            s = fmaf(xv.x, qv.x, fmaf(xv.y, qv.y, fmaf(xv.z, qv.z, fmaf(xv.w, qv.w, s))));
        }
        s += __shfl_down(s, 4); s += __shfl_down(s, 2); s += __shfl_down(s, 1);
        if (j == 0) cand_s[q * CAP + m] = xn[r] - 2.f * s;
    }
}

// ---- exact top-50 from rescored candidates (boundary ties -> smallest index) ----
__global__ void k_select(const float* __restrict__ cand_s, const int* __restrict__ cand_i,
                         const unsigned* __restrict__ cnt, int* __restrict__ post_idx)
{
    __shared__ unsigned ks[CAP];
    __shared__ unsigned wred[4];
    __shared__ unsigned wpos, eqn;
    __shared__ int eq[64];
    const int q = blockIdx.x, t = threadIdx.x;
    unsigned nn = cnt[q * 16];
    const int n = (nn < (unsigned)CAP) ? (int)nn : CAP;
    for (int m = t; m < n; m += 256) ks[m] = fkey(cand_s[q * CAP + m]);
    __syncthreads();
    int kk = KNN - 1; if (kk > n - 1) kk = n - 1;
    unsigned v = 0;
    for (int bit = 31; bit >= 0; bit--) {
        unsigned trial = v | (1u << bit);
        unsigned c = 0;
        for (int m = t; m < n; m += 256) c += (ks[m] < trial) ? 1u : 0u;
        #pragma unroll
        for (int off = 32; off > 0; off >>= 1) c += __shfl_down(c, off);
        if ((t & 63) == 0) wred[t >> 6] = c;
        __syncthreads();
        unsigned total = wred[0] + wred[1] + wred[2] + wred[3];
        __syncthreads();
        if (total <= (unsigned)kk) v = trial;
    }
    if (t == 0) { wpos = 0; eqn = 0; }
    __syncthreads();
    for (int m = t; m < n; m += 256) {
        if (ks[m] < v) {
            unsigned p = atomicAdd(&wpos, 1u);
            post_idx[q * KNN + p] = cand_i[q * CAP + m];
        } else if (ks[m] == v) {
            unsigned p = atomicAdd(&eqn, 1u);
            if (p < 64) eq[p] = cand_i[q * CAP + m];
        }
    }
    __syncthreads();
    if (t == 0) {
        int c1 = (int)wpos;
        int need = KNN - c1;
        int ne = (eqn < 64u) ? (int)eqn : 64;
        for (int a = 0; a < ne; a++)
            for (int b2 = a + 1; b2 < ne; b2++)
                if (eq[b2] < eq[a]) { int tmp = eq[a]; eq[a] = eq[b2]; eq[b2] = tmp; }
        for (int a = 0; a < need && a < ne; a++) post_idx[q * KNN + c1 + a] = eq[a];
    }
}

// ---- exact l2 to selected neighbors + softmax(-l2/tau) ----
__global__ void k_l2sm(const float* __restrict__ comb, const float* __restrict__ X,
                       const int* __restrict__ post_idx, float* __restrict__ post_w)
{
    __shared__ float l2s[KNN];
    __shared__ float qrow[D];
    const int q = blockIdx.x, t = threadIdx.x;
    const int w = t >> 6, l = t & 63;
    if (t < D) qrow[t] = comb[q * D + t];
    __syncthreads();
    for (int nb = w; nb < KNN; nb += 4) {
        long j = post_idx[q * KNN + nb];
        float d0 = qrow[l] - X[j * D + l];
        float d1 = qrow[l + 64] - X[j * D + l + 64];
        float s = d0 * d0 + d1 * d1;
        #pragma unroll
        for (int off = 32; off > 0; off >>= 1) s += __shfl_down(s, off);
        if (l == 0) l2s[nb] = s;
    }
    __syncthreads();
    if (t < 64) {
        float logit = (t < KNN) ? (-l2s[t] * 10.0f) : -3.4e38f; // 1/tau = 10
        float m = logit;
        #pragma unroll
        for (int off = 32; off > 0; off >>= 1) m = fmaxf(m, __shfl_down(m, off));
        m = __shfl(m, 0);
        float e = (t < KNN) ? expf(logit - m) : 0.f;
        float ssum = e;
        #pragma unroll
        for (int off = 32; off > 0; off >>= 1) ssum += __shfl_down(ssum, off);
        ssum = __shfl(ssum, 0);
        if (t < KNN) post_w[q * KNN + t] = e / ssum;
    }
}

// ---- union-KL with exact multiplicity semantics ----
__global__ void k_kl(const int* __restrict__ pri, const float* __restrict__ prw,
                     const int* __restrict__ qix, const int* __restrict__ post_idx,
                     const float* __restrict__ post_w, float* __restrict__ acc)
{
    __shared__ int ci[100];
    __shared__ float pwv[50], qwv[50];
    __shared__ float pterm[100], qterm[100], kterm[100];
    __shared__ float Sp, Sq;
    const int b = blockIdx.x, t = threadIdx.x;
    int qi = qix[b];
    if (t < 50) { ci[t] = pri[qi * 50 + t]; pwv[t] = prw[qi * 50 + t]; }
    else if (t < 100) { int k = t - 50; ci[t] = post_idx[b * 50 + k]; qwv[k] = post_w[b * 50 + k]; }
    __syncthreads();
    float pc = 0.f, qc = 0.f, mult = 0.f;
    if (t < 100) {
        int c = ci[t];
        float pr = 0.f, qr = 0.f;
        for (int k = 0; k < 50; k++) {
            bool m1 = (c == ci[k]); bool m2 = (c == ci[50 + k]);
            mult += (m1 ? 1.f : 0.f) + (m2 ? 1.f : 0.f);
            pr += m1 ? pwv[k] : 0.f;
            qr += m2 ? qwv[k] : 0.f;
        }
        pc = fmaxf(pr, 1e-8f); qc = fmaxf(qr, 1e-8f);
        pterm[t] = pc / mult; qterm[t] = qc / mult;
    }
    __syncthreads();
    if (t == 0) { float a = 0.f, b2 = 0.f; for (int m = 0; m < 100; m++) { a += pterm[m]; b2 += qterm[m]; } Sp = a; Sq = b2; }
    __syncthreads();
    if (t < 100) {
        float p = pc / Sp, qq = qc / Sq;
        kterm[t] = (p * (logf(p) - logf(qq))) / mult;
    }
    __syncthreads();
    if (t == 0) { float s = 0.f; for (int m = 0; m < 100; m++) s += kterm[m]; atomicAdd(&acc[1], s); }
}

// ---- reg + final assembly ----
__global__ void k_final(const float* __restrict__ W, const float* __restrict__ bb,
                        const float* __restrict__ acc, float* __restrict__ out)
{
    __shared__ float red[256];
    const int t = threadIdx.x;
    float s = 0.f;
    for (int m = t; m < D * D; m += 256) { float v = W[m]; s += v * v; }
    if (t < D) { float v = bb[t]; s += v * v; }
    red[t] = s;
    __syncthreads();
    for (int off = 128; off > 0; off >>= 1) { if (t < off) red[t] += red[t + off]; __syncthreads(); }
    if (t == 0) {
        float reg = 0.5f * red[0];
        float kxx = acc[2] / 65536.f, kyy = acc[3] / 65536.f, kxy = acc[4] / 131072.f;
        float ld = fmaxf(kxx + kyy - 2.f * kxy, 0.f);
        float lknn = acc[1] / 256.f;
        float lanc = acc[0] / 256.f;
        float total = ld + lknn + 1e-4f * reg + lanc;
        out[0] = total; out[1] = ld; out[2] = lknn; out[3] = lanc;
    }
}

extern "C" void kernel_launch(void* const* d_in, const int* in_sizes, int n_in,
                              void* d_out, int out_size, void* d_ws, size_t ws_size,
                              hipStream_t stream)
{
    (void)in_sizes; (void)n_in; (void)out_size;
    const float* q   = (const float*)d_in[0];
    const float* X   = (const float*)d_in[1];
    const float* W   = (const float*)d_in[2];
    const float* bb  = (const float*)d_in[3];
    const float* prw = (const float*)d_in[4];
    const int*   pri = (const int*)d_in[5];
    const int*   qix = (const int*)d_in[6];
    const int*   idx = (const int*)d_in[7];
    float* out = (float*)d_out;
    char* ws = (char*)d_ws;
    float*    acc  = (float*)(ws + OFF_ACC);
    unsigned* sel  = (unsigned*)(ws + OFF_SEL);
    unsigned* hist = (unsigned*)(ws + OFF_HIST);
    unsigned* cnt  = (unsigned*)(ws + OFF_CNT);
    float*    comb = (float*)(ws + OFF_COMB);
    float*    D2w  = (float*)(ws + OFF_D2);
    float*    xn   = (float*)(ws + OFF_XNORM);
    float*    samp4= (float*)(ws + OFF_SAMP4);
    float*    thr  = (float*)(ws + OFF_THR);
    float*    cs   = (float*)(ws + OFF_CANDS);
    int*      cix  = (int*)(ws + OFF_CANDI);
    int*      pix  = (int*)(ws + OFF_PIDX);
    float*    pw   = (float*)(ws + OFF_PW);
    unsigned short* tqbf = (unsigned short*)(ws + OFF_TQBF);
    unsigned short* tqsw = (unsigned short*)(ws + OFF_TQSW);
    float*    samp8= (float*)(ws + OFF_SAMP8);
    unsigned short* xbf  = (unsigned short*)(ws + OFF_XBF);

    const bool big = (ws_size >= (size_t)WS_NEED_BIG); // constant per session -> graph-safe

    hipMemsetAsync(ws, 0, 131072, stream);
    hipLaunchKernelGGL(k_prep,   dim3(512),    dim3(128), 0, stream, q, X, W, bb, idx, comb, tqbf, tqsw, acc);
    hipLaunchKernelGGL(k_d2,     dim3(512, 8), dim3(64),  0, stream, comb, D2w);
    hipLaunchKernelGGL(k_hist,   dim3(256),    dim3(256), 0, stream, D2w, hist, sel, 0);
    hipLaunchKernelGGL(k_scan,   dim3(1),      dim3(256), 0, stream, hist, sel, acc, 0);
    hipLaunchKernelGGL(k_hist,   dim3(256),    dim3(256), 0, stream, D2w, hist, sel, 1);
    hipLaunchKernelGGL(k_scan,   dim3(1),      dim3(256), 0, stream, hist, sel, acc, 1);
    hipLaunchKernelGGL(k_hist,   dim3(256),    dim3(256), 0, stream, D2w, hist, sel, 2);
    hipLaunchKernelGGL(k_scan,   dim3(1),      dim3(256), 0, stream, hist, sel, acc, 2);
    hipLaunchKernelGGL(k_mmd,    dim3(256),    dim3(256), 0, stream, D2w, acc);

    if (big) {
        hipLaunchKernelGGL(k_cast,  dim3(NRT),  dim3(256), 0, stream, X, xbf, xn);
        hipLaunchKernelGGL(k_mf_sw, dim3(128),  dim3(256), 0, stream, tqsw, xbf, xn, thr, samp8, cix, cnt, 0);
        hipLaunchKernelGGL(k_thr,   dim3(256),  dim3(256), 0, stream, samp8, thr, NS_BIG);
        hipLaunchKernelGGL(k_mf_sw, dim3(3125), dim3(256), 0, stream, tqsw, xbf, xn, thr, samp8, cix, cnt, 1);
    } else {
        hipLaunchKernelGGL(k_xnorm,     dim3(6250),     dim3(256), 0, stream, X, xn);
        hipLaunchKernelGGL(k_mf_direct, dim3(32, 2),    dim3(256), 0, stream, tqbf, X, xn, thr, samp4, cix, cnt, 0);
        hipLaunchKernelGGL(k_thr,       dim3(256),      dim3(256), 0, stream, samp4, thr, NS_SMALL);
        hipLaunchKernelGGL(k_mf_direct, dim3(1563, 2),  dim3(256), 0, stream, tqbf, X, xn, thr, samp4, cix, cnt, 1);
    }

    hipLaunchKernelGGL(k_rescore, dim3(256), dim3(256), 0, stream, comb, X, xn, cix, cnt, cs);
    hipLaunchKernelGGL(k_select,  dim3(256), dim3(256), 0, stream, cs, cix, cnt, pix);
    hipLaunchKernelGGL(k_l2sm,    dim3(256), dim3(256), 0, stream, comb, X, pix, pw);
    hipLaunchKernelGGL(k_kl,      dim3(256), dim3(128), 0, stream, pri, prw, qix, pix, pw, acc);
    hipLaunchKernelGGL(k_final,   dim3(1),   dim3(256), 0, stream, W, bb, acc, out);
}

// Round 4
// 550.436 us; speedup vs baseline: 2.9993x; 1.0458x over previous
//
#include <hip/hip_runtime.h>
#include <cstdint>

#define D 128
#define NPTS 200000
#define KNN 50
#define CAP 8192
#define NS 8192
#define SLACK 2.0f

// ---- workspace byte offsets ----
#define OFF_ACC    0         // 32 f32 (zeroed)
#define OFF_SEL    256       // 16 u32 (zeroed)
#define OFF_CNT    1024      // 256*16 u32 (zeroed, 1 counter / 64B line)
#define OFF_HIST0  17408     // 4096*8 u32 sharded (zeroed)
#define OFF_HIST12 148480    // 2*2*4096 u32 (zeroed)
#define MEMSET_BYTES 214016
#define OFF_COMB   214016    // 512*128 f32
#define OFF_D2     476160    // 262144 f32
#define OFF_XN     1524736   // 200000 f32
#define OFF_SAMP   2324736   // 256*8192 f32
#define OFF_THR    10713344  // 256 f32
#define OFF_CANDI  10714368  // 256*8192 i32
#define OFF_TQSW   19102976  // 256*128 bf16 swizzled
#define OFF_XBF    19168512  // 200000*128 bf16 swizzled (51.2 MB)

typedef __attribute__((ext_vector_type(8))) short bf16x8;
typedef __attribute__((ext_vector_type(4))) float f32x4;

__device__ __forceinline__ unsigned fkey(float f) {
    unsigned u = __float_as_uint(f);
    return u ^ ((unsigned)((int)u >> 31) | 0x80000000u);
}

// ---- phase 1: X->bf16 swizzle + xnorm | Tq=qW^T+b (+swizzle, anchor) | comb X[idx] ----
__global__ void k_phase1(const float* __restrict__ q, const float* __restrict__ X,
                         const float* __restrict__ W, const float* __restrict__ bb,
                         const int* __restrict__ idx, float* __restrict__ comb,
                         unsigned short* __restrict__ tqsw, unsigned short* __restrict__ xbf,
                         float* __restrict__ xn, float* __restrict__ acc)
{
    const int blk = blockIdx.x, t = threadIdx.x;
    if (blk < 12500) {
        __shared__ float xr[16];
        const int lr = t & 15;
        if (t < 16) xr[t] = 0.f;
        __syncthreads();
        const float4* src = (const float4*)(X + ((long)(blk * 16 + lr)) * D + (t >> 4) * 8);
        float4 v0 = src[0], v1 = src[1];
        uint4 pk;
        pk.x = (__float_as_uint(v0.x) >> 16) | (__float_as_uint(v0.y) & 0xFFFF0000u);
        pk.y = (__float_as_uint(v0.z) >> 16) | (__float_as_uint(v0.w) & 0xFFFF0000u);
        pk.z = (__float_as_uint(v1.x) >> 16) | (__float_as_uint(v1.y) & 0xFFFF0000u);
        pk.w = (__float_as_uint(v1.z) >> 16) | (__float_as_uint(v1.w) & 0xFFFF0000u);
        *(uint4*)(xbf + (long)blk * 2048 + t * 8) = pk;
        float ssq = v0.x*v0.x + v0.y*v0.y + v0.z*v0.z + v0.w*v0.w
                  + v1.x*v1.x + v1.y*v1.y + v1.z*v1.z + v1.w*v1.w;
        atomicAdd(&xr[lr], ssq);
        __syncthreads();
        if (t < 16) xn[blk * 16 + t] = xr[t];
    } else if (blk < 12628) {
        __shared__ float rowv[2][D];
        __shared__ float red[2][D];
        const int half = t >> 7, tt = t & 127;
        const int row = (blk - 12500) * 2 + half;
        rowv[half][tt] = q[row * D + tt];
        __syncthreads();
        float s = 0.f;
        const float* wr = W + tt * D;
        #pragma unroll 4
        for (int k = 0; k < D; k++) s = fmaf(rowv[half][k], wr[k], s);
        s += bb[tt];
        comb[row * D + tt] = s;
        unsigned ub = __float_as_uint(s);
        unsigned short hv = (unsigned short)((ub + 0x7fffu + ((ub >> 16) & 1u)) >> 16);
        int ksb = tt >> 5, quad = (tt & 31) >> 3, jj = tt & 7;
        int lane = quad * 16 + (row & 15);
        tqsw[(row >> 4) * 2048 + ksb * 512 + lane * 8 + jj] = hv;
        float dd = s - rowv[half][tt];
        red[half][tt] = dd * dd;
        __syncthreads();
        for (int off = 64; off > 0; off >>= 1) { if (tt < off) red[half][tt] += red[half][tt + off]; __syncthreads(); }
        if (tt == 0) atomicAdd(&acc[0], red[half][0]);
    } else {
        const int half = t >> 7, tt = t & 127;
        const int i = (blk - 12628) * 2 + half;
        comb[(256 + i) * D + tt] = X[(long)idx[i] * D + tt];
    }
}

// ---- D2 (512x512) + fused 12-bit histogram (sharded) ----
__global__ void k_d2h(const float* __restrict__ comb, float* __restrict__ D2w,
                      unsigned* __restrict__ hist0)
{
    __shared__ float ci[D];
    __shared__ float cj[64][D + 4];
    __shared__ unsigned h[4096];
    const int i = blockIdx.x, jb = blockIdx.y, t = threadIdx.x; // 64 threads
    for (int m = t; m < 4096; m += 64) h[m] = 0;
    ci[t] = comb[i * D + t];
    ci[t + 64] = comb[i * D + t + 64];
    const float4* src = (const float4*)(comb + (jb * 64) * D);
    #pragma unroll
    for (int m = 0; m < 32; m++) {
        int u = m * 64 + t;
        int r = u >> 5, c = u & 31;
        float4 v = src[u];
        cj[r][c * 4 + 0] = v.x; cj[r][c * 4 + 1] = v.y; cj[r][c * 4 + 2] = v.z; cj[r][c * 4 + 3] = v.w;
    }
    __syncthreads();
    float s = 0.f;
    #pragma unroll 4
    for (int k = 0; k < D; k++) { float d = ci[k] - cj[t][k]; s = fmaf(d, d, s); }
    D2w[i * 512 + jb * 64 + t] = s;
    atomicAdd(&h[__float_as_uint(s) >> 20], 1u);
    __syncthreads();
    const int sh = (i + jb) & 7;
    for (int m = t; m < 4096; m += 64) { unsigned v = h[m]; if (v) atomicAdd(&hist0[m * 8 + sh], v); }
}

// ---- shared MFMA body: A resident in regs, grid-stride over row-tiles, dbuf B ----
template<int MODE>
__device__ __forceinline__ void mf_body(const unsigned short* __restrict__ tqsw,
    const unsigned short* __restrict__ xbf, const float* __restrict__ xn,
    const float* __restrict__ thr, float* __restrict__ samp,
    int* __restrict__ cand_i, unsigned* __restrict__ cnt, int rtN, int stride)
{
    const int t = threadIdx.x;
    const int w = t >> 6, lane = t & 63;
    const int lr = lane & 15, quad = lane >> 4;
    bf16x8 a[4][4];
    #pragma unroll
    for (int i = 0; i < 4; i++)
        #pragma unroll
        for (int ks = 0; ks < 4; ks++)
            a[i][ks] = *(const bf16x8*)(tqsw + (w * 4 + i) * 2048 + ks * 512 + lane * 8);
    float th_r[4][4];
    if (MODE == 1) {
        #pragma unroll
        for (int i = 0; i < 4; i++)
            #pragma unroll
            for (int reg = 0; reg < 4; reg++)
                th_r[i][reg] = thr[w * 64 + i * 16 + quad * 4 + reg];
    }
    int rt = blockIdx.x;
    bf16x8 bc[4];
    #pragma unroll
    for (int ks = 0; ks < 4; ks++)
        bc[ks] = *(const bf16x8*)(xbf + (long)rt * 2048 + ks * 512 + lane * 8);
    float xnc = xn[rt * 16 + lr];
    while (true) {
        const int rtn = rt + stride;
        const bool has = rtn < rtN;
        bf16x8 bn[4]; float xnn = 0.f;
        if (has) {
            #pragma unroll
            for (int ks = 0; ks < 4; ks++)
                bn[ks] = *(const bf16x8*)(xbf + (long)rtn * 2048 + ks * 512 + lane * 8);
            xnn = xn[rtn * 16 + lr];
        }
        f32x4 acc[4];
        #pragma unroll
        for (int i = 0; i < 4; i++) acc[i] = (f32x4){0.f, 0.f, 0.f, 0.f};
        #pragma unroll
        for (int ks = 0; ks < 4; ks++)
            #pragma unroll
            for (int i = 0; i < 4; i++)
                acc[i] = __builtin_amdgcn_mfma_f32_16x16x32_bf16(a[i][ks], bc[ks], acc[i], 0, 0, 0);
        const int r = rt * 16 + lr;
        if (MODE == 0) {
            #pragma unroll
            for (int i = 0; i < 4; i++)
                #pragma unroll
                for (int reg = 0; reg < 4; reg++) {
                    int qq = w * 64 + i * 16 + quad * 4 + reg;
                    samp[qq * NS + r] = xnc - 2.f * acc[i][reg];
                }
        } else {
            #pragma unroll
            for (int i = 0; i < 4; i++)
                #pragma unroll
                for (int reg = 0; reg < 4; reg++) {
                    float s = xnc - 2.f * acc[i][reg];
                    if (s <= th_r[i][reg]) {
                        int qq = w * 64 + i * 16 + quad * 4 + reg;
                        unsigned pos = atomicAdd(&cnt[qq * 16], 1u);
                        if (pos < CAP) cand_i[qq * CAP + pos] = r;
                    }
                }
        }
        if (!has) break;
        #pragma unroll
        for (int ks = 0; ks < 4; ks++) bc[ks] = bn[ks];
        xnc = xnn; rt = rtn;
    }
}

// ---- mf0 (samples, rtiles 0..511) + scan0 (block 256) ----
__global__ __launch_bounds__(256) void k_mf0(const unsigned short* __restrict__ tqsw,
    const unsigned short* __restrict__ xbf, const float* __restrict__ xn,
    float* __restrict__ samp, const unsigned* __restrict__ hist0, unsigned* __restrict__ sel)
{
    if (blockIdx.x == 256) {
        __shared__ unsigned part[256];
        const int t = threadIdx.x;
        unsigned s = 0;
        for (int m = 0; m < 16; m++) {
            int b = t * 16 + m;
            #pragma unroll
            for (int sh = 0; sh < 8; sh++) s += hist0[b * 8 + sh];
        }
        part[t] = s;
        __syncthreads();
        if (t == 0) {
            for (int tg = 0; tg < 2; tg++) {
                unsigned r = tg ? 131072u : 131071u;
                int c = 0;
                while (part[c] <= r) { r -= part[c]; c++; }
                int b = c * 16;
                while (true) {
                    unsigned bs = 0;
                    #pragma unroll
                    for (int sh = 0; sh < 8; sh++) bs += hist0[b * 8 + sh];
                    if (bs <= r) { r -= bs; b++; } else break;
                }
                sel[2 * tg] = (unsigned)b; sel[2 * tg + 1] = r;
            }
        }
        return;
    }
    mf_body<0>(tqsw, xbf, xn, nullptr, samp, nullptr, nullptr, 512, 256);
}

// ---- hist pass1 (blocks 0..255) + per-query sample threshold (blocks 256..511) ----
__global__ void k_h1thr(const float* __restrict__ D2w, unsigned* __restrict__ hist12,
                        const unsigned* __restrict__ sel, const float* __restrict__ samp,
                        float* __restrict__ thr)
{
    __shared__ unsigned buf[8192];
    __shared__ unsigned wred[4];
    const int t = threadIdx.x;
    if (blockIdx.x < 256) {
        for (int m = t; m < 8192; m += 256) buf[m] = 0;
        __syncthreads();
        unsigned p0 = sel[0], p1 = sel[2];
        const int e0 = blockIdx.x * 1024;
        for (int m = 0; m < 4; m++) {
            unsigned key = __float_as_uint(D2w[e0 + m * 256 + t]);
            if ((key >> 20) == p0) atomicAdd(&buf[(key >> 8) & 0xFFFu], 1u);
            if ((key >> 20) == p1) atomicAdd(&buf[4096 + ((key >> 8) & 0xFFFu)], 1u);
        }
        __syncthreads();
        for (int m = t; m < 8192; m += 256) { unsigned v = buf[m]; if (v) atomicAdd(&hist12[m], v); }
    } else {
        const int q = blockIdx.x - 256;
        for (int m = t; m < NS; m += 256) buf[m] = fkey(samp[q * NS + m]);
        __syncthreads();
        unsigned v = 0;
        for (int bit = 31; bit >= 0; bit--) {
            unsigned trial = v | (1u << bit);
            unsigned c = 0;
            for (int m = t; m < NS; m += 256) c += (buf[m] < trial) ? 1u : 0u;
            #pragma unroll
            for (int off = 32; off > 0; off >>= 1) c += __shfl_down(c, off);
            if ((t & 63) == 0) wred[t >> 6] = c;
            __syncthreads();
            unsigned total = wred[0] + wred[1] + wred[2] + wred[3];
            __syncthreads();
            if (total <= (unsigned)(KNN - 1)) v = trial;
        }
        if (t == 0) {
            unsigned orig = (v & 0x80000000u) ? (v ^ 0x80000000u) : ~v;
            thr[q] = __uint_as_float(orig) + SLACK;
        }
    }
}

// ---- hist pass2 ----
__global__ void k_hist2(const float* __restrict__ D2w, unsigned* __restrict__ hist12,
                        const unsigned* __restrict__ sel)
{
    __shared__ unsigned h[8192];
    const int t = threadIdx.x;
    for (int m = t; m < 8192; m += 256) h[m] = 0;
    __syncthreads();
    unsigned p0 = sel[0], p1 = sel[2];
    const int e0 = blockIdx.x * 1024;
    for (int m = 0; m < 4; m++) {
        unsigned key = __float_as_uint(D2w[e0 + m * 256 + t]);
        if ((key >> 8) == p0) atomicAdd(&h[key & 0xFFu], 1u);
        if ((key >> 8) == p1) atomicAdd(&h[4096 + (key & 0xFFu)], 1u);
    }
    __syncthreads();
    unsigned* g = hist12 + 8192;
    for (int m = t; m < 8192; m += 256) { unsigned v = h[m]; if (v) atomicAdd(&g[m], v); }
}

// ---- scan passes 1,2 ----
__global__ void k_scan(const unsigned* __restrict__ hist12, unsigned* __restrict__ sel,
                       float* __restrict__ acc, int pass)
{
    __shared__ unsigned part[256];
    __shared__ unsigned res[4];
    const int t = threadIdx.x;
    const int per = (pass == 2) ? 1 : 16;
    unsigned rank0 = sel[1], rank1 = sel[3];
    for (int tg = 0; tg < 2; tg++) {
        const unsigned* h = hist12 + (pass - 1) * 8192 + tg * 4096;
        unsigned s = 0;
        for (int m = 0; m < per; m++) s += h[t * per + m];
        part[t] = s;
        __syncthreads();
        if (t == 0) {
            unsigned r = (tg == 0) ? rank0 : rank1;
            int c = 0;
            while (part[c] <= r) { r -= part[c]; c++; }
            int bidx = c * per;
            while (h[bidx] <= r) { r -= h[bidx]; bidx++; }
            res[2 * tg] = (unsigned)bidx; res[2 * tg + 1] = r;
        }
        __syncthreads();
    }
    if (t == 0) {
        if (pass == 1) { sel[0] = (sel[0] << 12) | res[0]; sel[1] = res[1];
                         sel[2] = (sel[2] << 12) | res[2]; sel[3] = res[3]; }
        else {
            unsigned k0 = (sel[0] << 8) | res[0];
            unsigned k1 = (sel[2] << 8) | res[2];
            float med = 0.5f * (__uint_as_float(k0) + __uint_as_float(k1));
            float ssq = 0.5f * med;
            if (ssq < 1e-6f) ssq = 1.0f;
            acc[5] = 1.0f / (ssq + 1e-8f);
        }
    }
}

// ---- mf1 (filter, all rtiles) + mmd (blocks 1024..1279) ----
__global__ __launch_bounds__(256) void k_mf1(const unsigned short* __restrict__ tqsw,
    const unsigned short* __restrict__ xbf, const float* __restrict__ xn,
    const float* __restrict__ thr, int* __restrict__ cand_i, unsigned* __restrict__ cnt,
    const float* __restrict__ D2w, float* __restrict__ acc)
{
    if (blockIdx.x >= 1024) {
        __shared__ float part[12];
        const int t = threadIdx.x, w = t >> 6;
        const float g = acc[5];
        float s[3] = {0.f, 0.f, 0.f};
        const int e0 = (blockIdx.x - 1024) * 1024;
        #pragma unroll
        for (int m = 0; m < 4; m++) {
            int e = e0 + m * 256 + t;
            int i = e >> 9, j = e & 511;
            float v = expf(-g * D2w[e]);
            int qd = (i < 256) ? ((j < 256) ? 0 : 2) : ((j < 256) ? 2 : 1);
            s[qd] += v;
        }
        #pragma unroll
        for (int c = 0; c < 3; c++) {
            float x = s[c];
            #pragma unroll
            for (int off = 32; off > 0; off >>= 1) x += __shfl_down(x, off);
            if ((t & 63) == 0) part[w * 3 + c] = x;
        }
        __syncthreads();
        if (t == 0)
            for (int c = 0; c < 3; c++)
                atomicAdd(&acc[2 + c], part[c] + part[3 + c] + part[6 + c] + part[9 + c]);
        return;
    }
    mf_body<1>(tqsw, xbf, xn, thr, nullptr, cand_i, cnt, 12500, 1024);
}

// ---- per-query: exact rescore -> top-50 -> l2 -> softmax -> union KL ----
__global__ void k_post(const float* __restrict__ comb, const float* __restrict__ X,
                       const float* __restrict__ xn, const int* __restrict__ cand_i,
                       const unsigned* __restrict__ cnt, const int* __restrict__ pri,
                       const float* __restrict__ prw, const int* __restrict__ qix,
                       float* __restrict__ acc)
{
    __shared__ unsigned ks[CAP];
    __shared__ float qrow[D];
    __shared__ unsigned wred[4];
    __shared__ unsigned wpos, eqn;
    __shared__ int eq[64];
    __shared__ int pidx[KNN];
    __shared__ float l2s[KNN];
    __shared__ float pw[KNN];
    __shared__ int ci[100];
    __shared__ float pwv[50], qwv[50];
    __shared__ float pterm[100], qterm[100], kterm[100];
    __shared__ float Sp, Sq;
    const int q = blockIdx.x, t = threadIdx.x;
    if (t < D) qrow[t] = comb[q * D + t];
    if (t == 0) { wpos = 0; eqn = 0; }
    __syncthreads();
    unsigned nn = cnt[q * 16];
    const int n = (nn < (unsigned)CAP) ? (int)nn : CAP;
    const int g = t >> 3, j = t & 7;
    for (int m = g; m < n; m += 32) {
        int r = cand_i[q * CAP + m];
        const float4* xr = (const float4*)(X + (long)r * D);
        float s = 0.f;
        #pragma unroll
        for (int p = 0; p < 4; p++) {
            float4 xv = xr[j * 4 + p];
            float4 qv = *(const float4*)&qrow[(j * 4 + p) * 4];
            s = fmaf(xv.x, qv.x, fmaf(xv.y, qv.y, fmaf(xv.z, qv.z, fmaf(xv.w, qv.w, s))));
        }
        s += __shfl_down(s, 4); s += __shfl_down(s, 2); s += __shfl_down(s, 1);
        if (j == 0) ks[m] = fkey(xn[r] - 2.f * s);
    }
    __syncthreads();
    int kk = KNN - 1; if (kk > n - 1) kk = n - 1;
    unsigned v = 0;
    for (int bit = 31; bit >= 0; bit--) {
        unsigned trial = v | (1u << bit);
        unsigned c = 0;
        for (int m = t; m < n; m += 256) c += (ks[m] < trial) ? 1u : 0u;
        #pragma unroll
        for (int off = 32; off > 0; off >>= 1) c += __shfl_down(c, off);
        if ((t & 63) == 0) wred[t >> 6] = c;
        __syncthreads();
        unsigned total = wred[0] + wred[1] + wred[2] + wred[3];
        __syncthreads();
        if (total <= (unsigned)kk) v = trial;
    }
    for (int m = t; m < n; m += 256) {
        if (ks[m] < v) {
            unsigned p = atomicAdd(&wpos, 1u);
            pidx[p] = cand_i[q * CAP + m];
        } else if (ks[m] == v) {
            unsigned p = atomicAdd(&eqn, 1u);
            if (p < 64) eq[p] = cand_i[q * CAP + m];
        }
    }
    __syncthreads();
    if (t == 0) {
        int c1 = (int)wpos, need = KNN - c1;
        int ne = (eqn < 64u) ? (int)eqn : 64;
        for (int a = 0; a < ne; a++)
            for (int b2 = a + 1; b2 < ne; b2++)
                if (eq[b2] < eq[a]) { int tmp = eq[a]; eq[a] = eq[b2]; eq[b2] = tmp; }
        for (int a = 0; a < need && a < ne; a++) pidx[c1 + a] = eq[a];
    }
    __syncthreads();
    for (int nb = g; nb < KNN; nb += 32) {
        long r = pidx[nb];
        const float4* xr = (const float4*)(X + r * D);
        float s = 0.f;
        #pragma unroll
        for (int p = 0; p < 4; p++) {
            float4 xv = xr[j * 4 + p];
            float4 qv = *(const float4*)&qrow[(j * 4 + p) * 4];
            float d0 = qv.x - xv.x, d1 = qv.y - xv.y, d2 = qv.z - xv.z, d3 = qv.w - xv.w;
            s += d0 * d0 + d1 * d1 + d2 * d2 + d3 * d3;
        }
        s += __shfl_down(s, 4); s += __shfl_down(s, 2); s += __shfl_down(s, 1);
        if (j == 0) l2s[nb] = s;
    }
    int qi = qix[q];
    if (t >= 128 && t < 178) { int k = t - 128; ci[k] = pri[qi * 50 + k]; pwv[k] = prw[qi * 50 + k]; }
    __syncthreads();
    if (t < 64) {
        float logit = (t < KNN) ? (-l2s[t] * 10.0f) : -3.4e38f; // 1/tau = 10
        float m = logit;
        #pragma unroll
        for (int off = 32; off > 0; off >>= 1) m = fmaxf(m, __shfl_down(m, off));
        m = __shfl(m, 0);
        float e = (t < KNN) ? expf(logit - m) : 0.f;
        float ss = e;
        #pragma unroll
        for (int off = 32; off > 0; off >>= 1) ss += __shfl_down(ss, off);
        ss = __shfl(ss, 0);
        if (t < KNN) pw[t] = e / ss;
    }
    __syncthreads();
    if (t < 50) { ci[50 + t] = pidx[t]; qwv[t] = pw[t]; }
    __syncthreads();
    float pc = 0.f, qc = 0.f, mult = 0.f;
    if (t < 100) {
        int c = ci[t];
        float pr = 0.f, qr = 0.f;
        for (int k = 0; k < 50; k++) {
            bool m1 = (c == ci[k]); bool m2 = (c == ci[50 + k]);
            mult += (m1 ? 1.f : 0.f) + (m2 ? 1.f : 0.f);
            pr += m1 ? pwv[k] : 0.f;
            qr += m2 ? qwv[k] : 0.f;
        }
        pc = fmaxf(pr, 1e-8f); qc = fmaxf(qr, 1e-8f);
        pterm[t] = pc / mult; qterm[t] = qc / mult;
    }
    __syncthreads();
    if (t == 0) { float a = 0.f, b2 = 0.f; for (int m = 0; m < 100; m++) { a += pterm[m]; b2 += qterm[m]; } Sp = a; Sq = b2; }
    __syncthreads();
    if (t < 100) {
        float p = pc / Sp, qq2 = qc / Sq;
        kterm[t] = (p * (logf(p) - logf(qq2))) / mult;
    }
    __syncthreads();
    if (t == 0) { float s = 0.f; for (int m = 0; m < 100; m++) s += kterm[m]; atomicAdd(&acc[1], s); }
}

// ---- reg + final assembly ----
__global__ void k_final(const float* __restrict__ W, const float* __restrict__ bb,
                        const float* __restrict__ acc, float* __restrict__ out)
{
    __shared__ float red[256];
    const int t = threadIdx.x;
    float s = 0.f;
    for (int m = t; m < D * D; m += 256) { float v = W[m]; s += v * v; }
    if (t < D) { float v = bb[t]; s += v * v; }
    red[t] = s;
    __syncthreads();
    for (int off = 128; off > 0; off >>= 1) { if (t < off) red[t] += red[t + off]; __syncthreads(); }
    if (t == 0) {
        float reg = 0.5f * red[0];
        float kxx = acc[2] / 65536.f, kyy = acc[3] / 65536.f, kxy = acc[4] / 131072.f;
        float ld = fmaxf(kxx + kyy - 2.f * kxy, 0.f);
        float lknn = acc[1] / 256.f;
        float lanc = acc[0] / 256.f;
        float total = ld + lknn + 1e-4f * reg + lanc;
        out[0] = total; out[1] = ld; out[2] = lknn; out[3] = lanc;
    }
}

extern "C" void kernel_launch(void* const* d_in, const int* in_sizes, int n_in,
                              void* d_out, int out_size, void* d_ws, size_t ws_size,
                              hipStream_t stream)
{
    (void)in_sizes; (void)n_in; (void)out_size; (void)ws_size;
    const float* q   = (const float*)d_in[0];
    const float* X   = (const float*)d_in[1];
    const float* W   = (const float*)d_in[2];
    const float* bb  = (const float*)d_in[3];
    const float* prw = (const float*)d_in[4];
    const int*   pri = (const int*)d_in[5];
    const int*   qix = (const int*)d_in[6];
    const int*   idx = (const int*)d_in[7];
    float* out = (float*)d_out;
    char* ws = (char*)d_ws;
    float*    acc   = (float*)(ws + OFF_ACC);
    unsigned* sel   = (unsigned*)(ws + OFF_SEL);
    unsigned* cnt   = (unsigned*)(ws + OFF_CNT);
    unsigned* hist0 = (unsigned*)(ws + OFF_HIST0);
    unsigned* hist12= (unsigned*)(ws + OFF_HIST12);
    float*    comb  = (float*)(ws + OFF_COMB);
    float*    D2w   = (float*)(ws + OFF_D2);
    float*    xn    = (float*)(ws + OFF_XN);
    float*    samp  = (float*)(ws + OFF_SAMP);
    float*    thr   = (float*)(ws + OFF_THR);
    int*      cix   = (int*)(ws + OFF_CANDI);
    unsigned short* tqsw = (unsigned short*)(ws + OFF_TQSW);
    unsigned short* xbf  = (unsigned short*)(ws + OFF_XBF);

    hipMemsetAsync(ws, 0, MEMSET_BYTES, stream);
    hipLaunchKernelGGL(k_phase1, dim3(12756),   dim3(256), 0, stream, q, X, W, bb, idx, comb, tqsw, xbf, xn, acc);
    hipLaunchKernelGGL(k_d2h,    dim3(512, 8),  dim3(64),  0, stream, comb, D2w, hist0);
    hipLaunchKernelGGL(k_mf0,    dim3(257),     dim3(256), 0, stream, tqsw, xbf, xn, samp, hist0, sel);
    hipLaunchKernelGGL(k_h1thr,  dim3(512),     dim3(256), 0, stream, D2w, hist12, sel, samp, thr);
    hipLaunchKernelGGL(k_scan,   dim3(1),       dim3(256), 0, stream, hist12, sel, acc, 1);
    hipLaunchKernelGGL(k_hist2,  dim3(256),     dim3(256), 0, stream, D2w, hist12, sel);
    hipLaunchKernelGGL(k_scan,   dim3(1),       dim3(256), 0, stream, hist12, sel, acc, 2);
    hipLaunchKernelGGL(k_mf1,    dim3(1280),    dim3(256), 0, stream, tqsw, xbf, xn, thr, cix, cnt, D2w, acc);
    hipLaunchKernelGGL(k_post,   dim3(256),     dim3(256), 0, stream, comb, X, xn, cix, cnt, pri, prw, qix, acc);
    hipLaunchKernelGGL(k_final,  dim3(1),       dim3(256), 0, stream, W, bb, acc, out);
}

// Round 5
// 478.943 us; speedup vs baseline: 3.4470x; 1.1493x over previous
//
#include <hip/hip_runtime.h>
#include <cstdint>

#define D 128
#define NPTS 200000
#define KNN 50
#define CAP 8192
#define NS 8192
#define SLACK 2.0f

// ---- workspace byte offsets ----
#define OFF_ACC    0         // 32 f32 (zeroed)
#define OFF_SEL    256       // 16 u32 (zeroed)
#define OFF_CNT    1024      // 256*16 u32 (zeroed, 1 counter / 64B line)
#define OFF_HIST0  17408     // 4096*8 u32 sharded (zeroed)
#define OFF_HIST12 148480    // 2*2*4096 u32 (zeroed)
#define MEMSET_BYTES 214016
#define OFF_COMB   214016    // 512*128 f32
#define OFF_D2     476160    // 262144 f32
#define OFF_XN     1524736   // 200000 f32
#define OFF_SAMP   2324736   // 256*8192 f32
#define OFF_THR    10713344  // 256 f32
#define OFF_CANDI  10714368  // 256*8192 i32
#define OFF_KSG    19102976  // 256*8192 u32 rescored keys
#define OFF_TQSW   27491584  // 256*128 bf16 swizzled
#define OFF_XBF    27557120  // 200000*128 bf16 swizzled (51.2 MB) -> ends 78,757,120

typedef __attribute__((ext_vector_type(8))) short bf16x8;
typedef __attribute__((ext_vector_type(4))) float f32x4;

__device__ __forceinline__ unsigned fkey(float f) {
    unsigned u = __float_as_uint(f);
    return u ^ ((unsigned)((int)u >> 31) | 0x80000000u);
}

// ---- phase 1: X->bf16 swizzle + xnorm | Tq=qW^T+b (+swizzle, anchor) | comb X[idx] | W reg ----
__global__ void k_phase1(const float* __restrict__ q, const float* __restrict__ X,
                         const float* __restrict__ W, const float* __restrict__ bb,
                         const int* __restrict__ idx, float* __restrict__ comb,
                         unsigned short* __restrict__ tqsw, unsigned short* __restrict__ xbf,
                         float* __restrict__ xn, float* __restrict__ acc)
{
    const int blk = blockIdx.x, t = threadIdx.x;
    if (blk < 12500) {
        __shared__ float xr[16];
        const int lr = t & 15;
        if (t < 16) xr[t] = 0.f;
        __syncthreads();
        const float4* src = (const float4*)(X + ((long)(blk * 16 + lr)) * D + (t >> 4) * 8);
        float4 v0 = src[0], v1 = src[1];
        uint4 pk;
        pk.x = (__float_as_uint(v0.x) >> 16) | (__float_as_uint(v0.y) & 0xFFFF0000u);
        pk.y = (__float_as_uint(v0.z) >> 16) | (__float_as_uint(v0.w) & 0xFFFF0000u);
        pk.z = (__float_as_uint(v1.x) >> 16) | (__float_as_uint(v1.y) & 0xFFFF0000u);
        pk.w = (__float_as_uint(v1.z) >> 16) | (__float_as_uint(v1.w) & 0xFFFF0000u);
        *(uint4*)(xbf + (long)blk * 2048 + t * 8) = pk;
        float ssq = v0.x*v0.x + v0.y*v0.y + v0.z*v0.z + v0.w*v0.w
                  + v1.x*v1.x + v1.y*v1.y + v1.z*v1.z + v1.w*v1.w;
        atomicAdd(&xr[lr], ssq);
        __syncthreads();
        if (t < 16) xn[blk * 16 + t] = xr[t];
    } else if (blk < 12628) {
        __shared__ float rowv[2][D];
        __shared__ float red[2][D];
        const int half = t >> 7, tt = t & 127;
        const int row = (blk - 12500) * 2 + half;
        rowv[half][tt] = q[row * D + tt];
        __syncthreads();
        float s = 0.f;
        const float* wr = W + tt * D;
        #pragma unroll 4
        for (int k = 0; k < D; k++) s = fmaf(rowv[half][k], wr[k], s);
        s += bb[tt];
        comb[row * D + tt] = s;
        unsigned ub = __float_as_uint(s);
        unsigned short hv = (unsigned short)((ub + 0x7fffu + ((ub >> 16) & 1u)) >> 16);
        int ksb = tt >> 5, quad = (tt & 31) >> 3, jj = tt & 7;
        int lane = quad * 16 + (row & 15);
        tqsw[(row >> 4) * 2048 + ksb * 512 + lane * 8 + jj] = hv;
        float dd = s - rowv[half][tt];
        red[half][tt] = dd * dd;
        __syncthreads();
        for (int off = 64; off > 0; off >>= 1) { if (tt < off) red[half][tt] += red[half][tt + off]; __syncthreads(); }
        if (tt == 0) atomicAdd(&acc[0], red[half][0]);
    } else if (blk < 12756) {
        const int half = t >> 7, tt = t & 127;
        const int i = (blk - 12628) * 2 + half;
        comb[(256 + i) * D + tt] = X[(long)idx[i] * D + tt];
    } else {
        // W (+b) sum of squares -> acc[7]
        __shared__ float wred[4];
        const int base = (blk - 12756) * 4096;
        float s = 0.f;
        #pragma unroll 4
        for (int k = 0; k < 16; k++) { float v = W[base + k * 256 + t]; s = fmaf(v, v, s); }
        if (blk == 12756 && t < D) { float v = bb[t]; s = fmaf(v, v, s); }
        #pragma unroll
        for (int off = 32; off > 0; off >>= 1) s += __shfl_down(s, off);
        if ((t & 63) == 0) wred[t >> 6] = s;
        __syncthreads();
        if (t == 0) atomicAdd(&acc[7], wred[0] + wred[1] + wred[2] + wred[3]);
    }
}

// ---- D2 (512x512) + fused 12-bit histogram (sharded) ----
__global__ void k_d2h(const float* __restrict__ comb, float* __restrict__ D2w,
                      unsigned* __restrict__ hist0)
{
    __shared__ float ci[D];
    __shared__ float cj[64][D + 4];
    __shared__ unsigned h[4096];
    const int i = blockIdx.x, jb = blockIdx.y, t = threadIdx.x; // 64 threads
    for (int m = t; m < 4096; m += 64) h[m] = 0;
    ci[t] = comb[i * D + t];
    ci[t + 64] = comb[i * D + t + 64];
    const float4* src = (const float4*)(comb + (jb * 64) * D);
    #pragma unroll
    for (int m = 0; m < 32; m++) {
        int u = m * 64 + t;
        int r = u >> 5, c = u & 31;
        float4 v = src[u];
        cj[r][c * 4 + 0] = v.x; cj[r][c * 4 + 1] = v.y; cj[r][c * 4 + 2] = v.z; cj[r][c * 4 + 3] = v.w;
    }
    __syncthreads();
    float s = 0.f;
    #pragma unroll 4
    for (int k = 0; k < D; k++) { float d = ci[k] - cj[t][k]; s = fmaf(d, d, s); }
    D2w[i * 512 + jb * 64 + t] = s;
    atomicAdd(&h[__float_as_uint(s) >> 20], 1u);
    __syncthreads();
    const int sh = (i + jb) & 7;
    for (int m = t; m < 4096; m += 64) { unsigned v = h[m]; if (v) atomicAdd(&hist0[m * 8 + sh], v); }
}

// ---- shared MFMA body: A resident in regs, grid-stride over row-tiles, dbuf B ----
template<int MODE>
__device__ __forceinline__ void mf_body(const unsigned short* __restrict__ tqsw,
    const unsigned short* __restrict__ xbf, const float* __restrict__ xn,
    const float* __restrict__ thr, float* __restrict__ samp,
    int* __restrict__ cand_i, unsigned* __restrict__ cnt, int rtN, int stride)
{
    const int t = threadIdx.x;
    const int w = t >> 6, lane = t & 63;
    const int lr = lane & 15, quad = lane >> 4;
    bf16x8 a[4][4];
    #pragma unroll
    for (int i = 0; i < 4; i++)
        #pragma unroll
        for (int ks = 0; ks < 4; ks++)
            a[i][ks] = *(const bf16x8*)(tqsw + (w * 4 + i) * 2048 + ks * 512 + lane * 8);
    float th_r[4][4];
    if (MODE == 1) {
        #pragma unroll
        for (int i = 0; i < 4; i++)
            #pragma unroll
            for (int reg = 0; reg < 4; reg++)
                th_r[i][reg] = thr[w * 64 + i * 16 + quad * 4 + reg];
    }
    int rt = blockIdx.x;
    bf16x8 bc[4];
    #pragma unroll
    for (int ks = 0; ks < 4; ks++)
        bc[ks] = *(const bf16x8*)(xbf + (long)rt * 2048 + ks * 512 + lane * 8);
    float xnc = xn[rt * 16 + lr];
    while (true) {
        const int rtn = rt + stride;
        const bool has = rtn < rtN;
        bf16x8 bn[4]; float xnn = 0.f;
        if (has) {
            #pragma unroll
            for (int ks = 0; ks < 4; ks++)
                bn[ks] = *(const bf16x8*)(xbf + (long)rtn * 2048 + ks * 512 + lane * 8);
            xnn = xn[rtn * 16 + lr];
        }
        f32x4 acc[4];
        #pragma unroll
        for (int i = 0; i < 4; i++) acc[i] = (f32x4){0.f, 0.f, 0.f, 0.f};
        #pragma unroll
        for (int ks = 0; ks < 4; ks++)
            #pragma unroll
            for (int i = 0; i < 4; i++)
                acc[i] = __builtin_amdgcn_mfma_f32_16x16x32_bf16(a[i][ks], bc[ks], acc[i], 0, 0, 0);
        const int r = rt * 16 + lr;
        if (MODE == 0) {
            #pragma unroll
            for (int i = 0; i < 4; i++)
                #pragma unroll
                for (int reg = 0; reg < 4; reg++) {
                    int qq = w * 64 + i * 16 + quad * 4 + reg;
                    samp[qq * NS + r] = xnc - 2.f * acc[i][reg];
                }
        } else {
            #pragma unroll
            for (int i = 0; i < 4; i++)
                #pragma unroll
                for (int reg = 0; reg < 4; reg++) {
                    float s = xnc - 2.f * acc[i][reg];
                    if (s <= th_r[i][reg]) {
                        int qq = w * 64 + i * 16 + quad * 4 + reg;
                        unsigned pos = atomicAdd(&cnt[qq * 16], 1u);
                        if (pos < CAP) cand_i[qq * CAP + pos] = r;
                    }
                }
        }
        if (!has) break;
        #pragma unroll
        for (int ks = 0; ks < 4; ks++) bc[ks] = bn[ks];
        xnc = xnn; rt = rtn;
    }
}

// ---- mf0 (samples, rtiles 0..511) + scan0 (block 256) ----
__global__ __launch_bounds__(256) void k_mf0(const unsigned short* __restrict__ tqsw,
    const unsigned short* __restrict__ xbf, const float* __restrict__ xn,
    float* __restrict__ samp, const unsigned* __restrict__ hist0, unsigned* __restrict__ sel)
{
    if (blockIdx.x == 256) {
        __shared__ unsigned part[256];
        const int t = threadIdx.x;
        unsigned s = 0;
        for (int m = 0; m < 16; m++) {
            int b = t * 16 + m;
            #pragma unroll
            for (int sh = 0; sh < 8; sh++) s += hist0[b * 8 + sh];
        }
        part[t] = s;
        __syncthreads();
        if (t == 0) {
            for (int tg = 0; tg < 2; tg++) {
                unsigned r = tg ? 131072u : 131071u;
                int c = 0;
                while (part[c] <= r) { r -= part[c]; c++; }
                int b = c * 16;
                while (true) {
                    unsigned bs = 0;
                    #pragma unroll
                    for (int sh = 0; sh < 8; sh++) bs += hist0[b * 8 + sh];
                    if (bs <= r) { r -= bs; b++; } else break;
                }
                sel[2 * tg] = (unsigned)b; sel[2 * tg + 1] = r;
            }
        }
        return;
    }
    mf_body<0>(tqsw, xbf, xn, nullptr, samp, nullptr, nullptr, 512, 256);
}

// ---- hist pass1 (blocks 0..255) + per-query sample threshold (blocks 256..511) ----
__global__ void k_h1thr(const float* __restrict__ D2w, unsigned* __restrict__ hist12,
                        const unsigned* __restrict__ sel, const float* __restrict__ samp,
                        float* __restrict__ thr)
{
    __shared__ unsigned buf[8192];
    __shared__ unsigned wred[4];
    const int t = threadIdx.x;
    if (blockIdx.x < 256) {
        for (int m = t; m < 8192; m += 256) buf[m] = 0;
        __syncthreads();
        unsigned p0 = sel[0], p1 = sel[2];
        const int e0 = blockIdx.x * 1024;
        for (int m = 0; m < 4; m++) {
            unsigned key = __float_as_uint(D2w[e0 + m * 256 + t]);
            if ((key >> 20) == p0) atomicAdd(&buf[(key >> 8) & 0xFFFu], 1u);
            if ((key >> 20) == p1) atomicAdd(&buf[4096 + ((key >> 8) & 0xFFFu)], 1u);
        }
        __syncthreads();
        for (int m = t; m < 8192; m += 256) { unsigned v = buf[m]; if (v) atomicAdd(&hist12[m], v); }
    } else {
        const int q = blockIdx.x - 256;
        for (int m = t; m < NS; m += 256) buf[m] = fkey(samp[q * NS + m]);
        __syncthreads();
        unsigned v = 0;
        for (int bit = 31; bit >= 0; bit--) {
            unsigned trial = v | (1u << bit);
            unsigned c = 0;
            for (int m = t; m < NS; m += 256) c += (buf[m] < trial) ? 1u : 0u;
            #pragma unroll
            for (int off = 32; off > 0; off >>= 1) c += __shfl_down(c, off);
            if ((t & 63) == 0) wred[t >> 6] = c;
            __syncthreads();
            unsigned total = wred[0] + wred[1] + wred[2] + wred[3];
            __syncthreads();
            if (total <= (unsigned)(KNN - 1)) v = trial;
        }
        if (t == 0) {
            unsigned orig = (v & 0x80000000u) ? (v ^ 0x80000000u) : ~v;
            thr[q] = __uint_as_float(orig) + SLACK;
        }
    }
}

// ---- hist pass2 with fused local scan1 (block 0 persists sel[4..7]) ----
__global__ void k_hist2s(const float* __restrict__ D2w, unsigned* __restrict__ hist12,
                         unsigned* __restrict__ sel)
{
    __shared__ unsigned h[8192];
    __shared__ unsigned part[256];
    __shared__ unsigned pfx[2];
    __shared__ unsigned rr[2];
    const int t = threadIdx.x;
    for (int tg = 0; tg < 2; tg++) {
        const unsigned* hh = hist12 + tg * 4096;
        unsigned s = 0;
        for (int m = 0; m < 16; m++) s += hh[t * 16 + m];
        part[t] = s;
        __syncthreads();
        if (t == 0) {
            unsigned r = sel[1 + 2 * tg];
            int c = 0;
            while (part[c] <= r) { r -= part[c]; c++; }
            int b = c * 16;
            while (hh[b] <= r) { r -= hh[b]; b++; }
            pfx[tg] = (sel[2 * tg] << 12) | (unsigned)b;
            rr[tg] = r;
        }
        __syncthreads();
    }
    if (blockIdx.x == 0 && t == 0) {
        sel[4] = pfx[0]; sel[5] = rr[0]; sel[6] = pfx[1]; sel[7] = rr[1];
    }
    for (int m = t; m < 8192; m += 256) h[m] = 0;
    __syncthreads();
    unsigned p0 = pfx[0], p1 = pfx[1];
    const int e0 = blockIdx.x * 1024;
    for (int m = 0; m < 4; m++) {
        unsigned key = __float_as_uint(D2w[e0 + m * 256 + t]);
        if ((key >> 8) == p0) atomicAdd(&h[key & 0xFFu], 1u);
        if ((key >> 8) == p1) atomicAdd(&h[4096 + (key & 0xFFu)], 1u);
    }
    __syncthreads();
    unsigned* gp = hist12 + 8192;
    for (int m = t; m < 8192; m += 256) { unsigned v = h[m]; if (v) atomicAdd(&gp[m], v); }
}

// ---- mf1 (filter, all rtiles) + mmd with fused local scan2 (blocks 1024..1279) ----
__global__ __launch_bounds__(256) void k_mf1(const unsigned short* __restrict__ tqsw,
    const unsigned short* __restrict__ xbf, const float* __restrict__ xn,
    const float* __restrict__ thr, int* __restrict__ cand_i, unsigned* __restrict__ cnt,
    const float* __restrict__ D2w, const unsigned* __restrict__ hist12,
    const unsigned* __restrict__ sel, float* __restrict__ acc)
{
    if (blockIdx.x >= 1024) {
        __shared__ unsigned h2[512];
        __shared__ float gsh;
        __shared__ float part[12];
        const int t = threadIdx.x, w = t >> 6;
        h2[t] = hist12[8192 + t];
        h2[256 + t] = hist12[8192 + 4096 + t];
        __syncthreads();
        if (t == 0) {
            unsigned key[2];
            for (int tg = 0; tg < 2; tg++) {
                unsigned r = sel[5 + 2 * tg];
                const unsigned* hh = h2 + tg * 256;
                int b = 0;
                while (hh[b] <= r) { r -= hh[b]; b++; }
                key[tg] = (sel[4 + 2 * tg] << 8) | (unsigned)b;
            }
            float med = 0.5f * (__uint_as_float(key[0]) + __uint_as_float(key[1]));
            float ssq = 0.5f * med;
            if (ssq < 1e-6f) ssq = 1.0f;
            gsh = 1.0f / (ssq + 1e-8f);
        }
        __syncthreads();
        const float g = gsh;
        float s[3] = {0.f, 0.f, 0.f};
        const int e0 = (blockIdx.x - 1024) * 1024;
        #pragma unroll
        for (int m = 0; m < 4; m++) {
            int e = e0 + m * 256 + t;
            int i = e >> 9, j = e & 511;
            float v = expf(-g * D2w[e]);
            int qd = (i < 256) ? ((j < 256) ? 0 : 2) : ((j < 256) ? 2 : 1);
            s[qd] += v;
        }
        #pragma unroll
        for (int c = 0; c < 3; c++) {
            float x = s[c];
            #pragma unroll
            for (int off = 32; off > 0; off >>= 1) x += __shfl_down(x, off);
            if ((t & 63) == 0) part[w * 3 + c] = x;
        }
        __syncthreads();
        if (t == 0)
            for (int c = 0; c < 3; c++)
                atomicAdd(&acc[2 + c], part[c] + part[3 + c] + part[6 + c] + part[9 + c]);
        return;
    }
    mf_body<1>(tqsw, xbf, xn, thr, nullptr, cand_i, cnt, 12500, 1024);
}

// ---- exact f32 rescore of candidates (high-occupancy, 8 splits per query) ----
__global__ void k_rescore(const float* __restrict__ comb, const float* __restrict__ X,
                          const float* __restrict__ xn, const int* __restrict__ cand_i,
                          const unsigned* __restrict__ cnt, unsigned* __restrict__ ksg)
{
    __shared__ float qrow[D];
    const int q = blockIdx.x, sp = blockIdx.y, t = threadIdx.x;
    if (t < D) qrow[t] = comb[q * D + t];
    __syncthreads();
    unsigned nn = cnt[q * 16];
    const int n = (nn < (unsigned)CAP) ? (int)nn : CAP;
    const int g = t >> 3, j = t & 7;
    for (int m = sp * 32 + g; m < n; m += 256) {
        int r = cand_i[q * CAP + m];
        const float4* xr = (const float4*)(X + (long)r * D);
        float s = 0.f;
        #pragma unroll
        for (int p = 0; p < 4; p++) {
            float4 xv = xr[j * 4 + p];
            float4 qv = *(const float4*)&qrow[(j * 4 + p) * 4];
            s = fmaf(xv.x, qv.x, fmaf(xv.y, qv.y, fmaf(xv.z, qv.z, fmaf(xv.w, qv.w, s))));
        }
        s += __shfl_down(s, 4); s += __shfl_down(s, 2); s += __shfl_down(s, 1);
        if (j == 0) ksg[q * CAP + m] = fkey(xn[r] - 2.f * s);
    }
}

// ---- per-query: top-50 from precomputed keys -> l2 -> softmax -> union KL ----
__global__ void k_post2(const float* __restrict__ comb, const float* __restrict__ X,
                        const int* __restrict__ cand_i, const unsigned* __restrict__ cnt,
                        const unsigned* __restrict__ ksg, const int* __restrict__ pri,
                        const float* __restrict__ prw, const int* __restrict__ qix,
                        float* __restrict__ acc)
{
    __shared__ unsigned ks[CAP];
    __shared__ float qrow[D];
    __shared__ unsigned wred[4];
    __shared__ unsigned wpos, eqn;
    __shared__ int eq[64];
    __shared__ int pidx[KNN];
    __shared__ float l2s[KNN];
    __shared__ float pw[KNN];
    __shared__ int ci[100];
    __shared__ float pwv[50], qwv[50];
    __shared__ float pterm[100], qterm[100], kterm[100];
    __shared__ float Sp, Sq;
    const int q = blockIdx.x, t = threadIdx.x;
    if (t < D) qrow[t] = comb[q * D + t];
    if (t == 0) { wpos = 0; eqn = 0; }
    unsigned nn = cnt[q * 16];
    const int n = (nn < (unsigned)CAP) ? (int)nn : CAP;
    for (int m = t; m < n; m += 256) ks[m] = ksg[q * CAP + m];
    __syncthreads();
    int kk = KNN - 1; if (kk > n - 1) kk = n - 1;
    unsigned v = 0;
    for (int bit = 31; bit >= 0; bit--) {
        unsigned trial = v | (1u << bit);
        unsigned c = 0;
        for (int m = t; m < n; m += 256) c += (ks[m] < trial) ? 1u : 0u;
        #pragma unroll
        for (int off = 32; off > 0; off >>= 1) c += __shfl_down(c, off);
        if ((t & 63) == 0) wred[t >> 6] = c;
        __syncthreads();
        unsigned total = wred[0] + wred[1] + wred[2] + wred[3];
        __syncthreads();
        if (total <= (unsigned)kk) v = trial;
    }
    for (int m = t; m < n; m += 256) {
        if (ks[m] < v) {
            unsigned p = atomicAdd(&wpos, 1u);
            pidx[p] = cand_i[q * CAP + m];
        } else if (ks[m] == v) {
            unsigned p = atomicAdd(&eqn, 1u);
            if (p < 64) eq[p] = cand_i[q * CAP + m];
        }
    }
    __syncthreads();
    if (t == 0) {
        int c1 = (int)wpos, need = KNN - c1;
        int ne = (eqn < 64u) ? (int)eqn : 64;
        for (int a = 0; a < ne; a++)
            for (int b2 = a + 1; b2 < ne; b2++)
                if (eq[b2] < eq[a]) { int tmp = eq[a]; eq[a] = eq[b2]; eq[b2] = tmp; }
        for (int a = 0; a < need && a < ne; a++) pidx[c1 + a] = eq[a];
    }
    __syncthreads();
    const int g = t >> 3, j = t & 7;
    for (int nb = g; nb < KNN; nb += 32) {
        long r = pidx[nb];
        const float4* xr = (const float4*)(X + r * D);
        float s = 0.f;
        #pragma unroll
        for (int p = 0; p < 4; p++) {
            float4 xv = xr[j * 4 + p];
            float4 qv = *(const float4*)&qrow[(j * 4 + p) * 4];
            float d0 = qv.x - xv.x, d1 = qv.y - xv.y, d2 = qv.z - xv.z, d3 = qv.w - xv.w;
            s += d0 * d0 + d1 * d1 + d2 * d2 + d3 * d3;
        }
        s += __shfl_down(s, 4); s += __shfl_down(s, 2); s += __shfl_down(s, 1);
        if (j == 0) l2s[nb] = s;
    }
    int qi = qix[q];
    if (t >= 128 && t < 178) { int k = t - 128; ci[k] = pri[qi * 50 + k]; pwv[k] = prw[qi * 50 + k]; }
    __syncthreads();
    if (t < 64) {
        float logit = (t < KNN) ? (-l2s[t] * 10.0f) : -3.4e38f; // 1/tau = 10
        float m = logit;
        #pragma unroll
        for (int off = 32; off > 0; off >>= 1) m = fmaxf(m, __shfl_down(m, off));
        m = __shfl(m, 0);
        float e = (t < KNN) ? expf(logit - m) : 0.f;
        float ss = e;
        #pragma unroll
        for (int off = 32; off > 0; off >>= 1) ss += __shfl_down(ss, off);
        ss = __shfl(ss, 0);
        if (t < KNN) pw[t] = e / ss;
    }
    __syncthreads();
    if (t < 50) { ci[50 + t] = pidx[t]; qwv[t] = pw[t]; }
    __syncthreads();
    float pc = 0.f, qc = 0.f, mult = 0.f;
    if (t < 100) {
        int c = ci[t];
        float pr = 0.f, qr = 0.f;
        for (int k = 0; k < 50; k++) {
            bool m1 = (c == ci[k]); bool m2 = (c == ci[50 + k]);
            mult += (m1 ? 1.f : 0.f) + (m2 ? 1.f : 0.f);
            pr += m1 ? pwv[k] : 0.f;
            qr += m2 ? qwv[k] : 0.f;
        }
        pc = fmaxf(pr, 1e-8f); qc = fmaxf(qr, 1e-8f);
        pterm[t] = pc / mult; qterm[t] = qc / mult;
    }
    __syncthreads();
    if (t == 0) { float a = 0.f, b2 = 0.f; for (int m = 0; m < 100; m++) { a += pterm[m]; b2 += qterm[m]; } Sp = a; Sq = b2; }
    __syncthreads();
    if (t < 100) {
        float p = pc / Sp, qq2 = qc / Sq;
        kterm[t] = (p * (logf(p) - logf(qq2))) / mult;
    }
    __syncthreads();
    if (t == 0) { float s = 0.f; for (int m = 0; m < 100; m++) s += kterm[m]; atomicAdd(&acc[1], s); }
}

// ---- final assembly (reg precomputed in phase1) ----
__global__ void k_final(const float* __restrict__ acc, float* __restrict__ out)
{
    if (threadIdx.x == 0) {
        float reg = 0.5f * acc[7];
        float kxx = acc[2] / 65536.f, kyy = acc[3] / 65536.f, kxy = acc[4] / 131072.f;
        float ld = fmaxf(kxx + kyy - 2.f * kxy, 0.f);
        float lknn = acc[1] / 256.f;
        float lanc = acc[0] / 256.f;
        out[0] = ld + lknn + 1e-4f * reg + lanc;
        out[1] = ld; out[2] = lknn; out[3] = lanc;
    }
}

extern "C" void kernel_launch(void* const* d_in, const int* in_sizes, int n_in,
                              void* d_out, int out_size, void* d_ws, size_t ws_size,
                              hipStream_t stream)
{
    (void)in_sizes; (void)n_in; (void)out_size; (void)ws_size;
    const float* q   = (const float*)d_in[0];
    const float* X   = (const float*)d_in[1];
    const float* W   = (const float*)d_in[2];
    const float* bb  = (const float*)d_in[3];
    const float* prw = (const float*)d_in[4];
    const int*   pri = (const int*)d_in[5];
    const int*   qix = (const int*)d_in[6];
    const int*   idx = (const int*)d_in[7];
    float* out = (float*)d_out;
    char* ws = (char*)d_ws;
    float*    acc   = (float*)(ws + OFF_ACC);
    unsigned* sel   = (unsigned*)(ws + OFF_SEL);
    unsigned* cnt   = (unsigned*)(ws + OFF_CNT);
    unsigned* hist0 = (unsigned*)(ws + OFF_HIST0);
    unsigned* hist12= (unsigned*)(ws + OFF_HIST12);
    float*    comb  = (float*)(ws + OFF_COMB);
    float*    D2w   = (float*)(ws + OFF_D2);
    float*    xn    = (float*)(ws + OFF_XN);
    float*    samp  = (float*)(ws + OFF_SAMP);
    float*    thr   = (float*)(ws + OFF_THR);
    int*      cix   = (int*)(ws + OFF_CANDI);
    unsigned* ksg   = (unsigned*)(ws + OFF_KSG);
    unsigned short* tqsw = (unsigned short*)(ws + OFF_TQSW);
    unsigned short* xbf  = (unsigned short*)(ws + OFF_XBF);

    hipMemsetAsync(ws, 0, MEMSET_BYTES, stream);
    hipLaunchKernelGGL(k_phase1,  dim3(12760),   dim3(256), 0, stream, q, X, W, bb, idx, comb, tqsw, xbf, xn, acc);
    hipLaunchKernelGGL(k_d2h,     dim3(512, 8),  dim3(64),  0, stream, comb, D2w, hist0);
    hipLaunchKernelGGL(k_mf0,     dim3(257),     dim3(256), 0, stream, tqsw, xbf, xn, samp, hist0, sel);
    hipLaunchKernelGGL(k_h1thr,   dim3(512),     dim3(256), 0, stream, D2w, hist12, sel, samp, thr);
    hipLaunchKernelGGL(k_hist2s,  dim3(256),     dim3(256), 0, stream, D2w, hist12, sel);
    hipLaunchKernelGGL(k_mf1,     dim3(1280),    dim3(256), 0, stream, tqsw, xbf, xn, thr, cix, cnt, D2w, hist12, sel, acc);
    hipLaunchKernelGGL(k_rescore, dim3(256, 8),  dim3(256), 0, stream, comb, X, xn, cix, cnt, ksg);
    hipLaunchKernelGGL(k_post2,   dim3(256),     dim3(256), 0, stream, comb, X, cix, cnt, ksg, pri, prw, qix, acc);
    hipLaunchKernelGGL(k_final,   dim3(1),       dim3(64),  0, stream, acc, out);
}

// Round 6
// 475.558 us; speedup vs baseline: 3.4716x; 1.0071x over previous
//
#include <hip/hip_runtime.h>
#include <cstdint>

#define D 128
#define NPTS 200000
#define KNN 50
#define CAP 8192
#define NS 8192
#define SLACK 2.0f

// ---- workspace byte offsets ----
#define OFF_ACC    0         // 32 f32 (zeroed)
#define OFF_SEL    256       // 16 u32 (zeroed)
#define OFF_CNT    1024      // 256*16 u32 (zeroed, 1 counter / 64B line)
#define OFF_HIST0  17408     // 4096*8 u32 sharded (zeroed)
#define OFF_HIST12 148480    // 2*2*4096 u32 (zeroed)
#define MEMSET_BYTES 214016
#define OFF_COMB   214016    // 512*128 f32
#define OFF_D2     476160    // 262144 f32
#define OFF_XN     1524736   // 200000 f32
#define OFF_SAMP   2324736   // 256*8192 f32
#define OFF_THR    10713344  // 256 f32
#define OFF_CANDI  10714368  // 256*8192 i32
#define OFF_KSG    19102976  // 256*8192 u32 rescored keys
#define OFF_TQSW   27491584  // 256*128 bf16 swizzled
#define OFF_XBF    27557120  // 200000*128 bf16 swizzled (51.2 MB) -> ends 78,757,120

typedef __attribute__((ext_vector_type(8))) short bf16x8;
typedef __attribute__((ext_vector_type(4))) float f32x4;

__device__ __forceinline__ unsigned fkey(float f) {
    unsigned u = __float_as_uint(f);
    return u ^ ((unsigned)((int)u >> 31) | 0x80000000u);
}

// ---- phase 1: X->bf16 swizzle + xnorm | Tq=qW^T+b (+swizzle, anchor) | comb X[idx] | W reg ----
__global__ void k_phase1(const float* __restrict__ q, const float* __restrict__ X,
                         const float* __restrict__ W, const float* __restrict__ bb,
                         const int* __restrict__ idx, float* __restrict__ comb,
                         unsigned short* __restrict__ tqsw, unsigned short* __restrict__ xbf,
                         float* __restrict__ xn, float* __restrict__ acc)
{
    const int blk = blockIdx.x, t = threadIdx.x;
    if (blk < 12500) {
        __shared__ float xr[16];
        const int lr = t & 15;
        if (t < 16) xr[t] = 0.f;
        __syncthreads();
        const float4* src = (const float4*)(X + ((long)(blk * 16 + lr)) * D + (t >> 4) * 8);
        float4 v0 = src[0], v1 = src[1];
        uint4 pk;
        pk.x = (__float_as_uint(v0.x) >> 16) | (__float_as_uint(v0.y) & 0xFFFF0000u);
        pk.y = (__float_as_uint(v0.z) >> 16) | (__float_as_uint(v0.w) & 0xFFFF0000u);
        pk.z = (__float_as_uint(v1.x) >> 16) | (__float_as_uint(v1.y) & 0xFFFF0000u);
        pk.w = (__float_as_uint(v1.z) >> 16) | (__float_as_uint(v1.w) & 0xFFFF0000u);
        *(uint4*)(xbf + (long)blk * 2048 + t * 8) = pk;
        float ssq = v0.x*v0.x + v0.y*v0.y + v0.z*v0.z + v0.w*v0.w
                  + v1.x*v1.x + v1.y*v1.y + v1.z*v1.z + v1.w*v1.w;
        atomicAdd(&xr[lr], ssq);
        __syncthreads();
        if (t < 16) xn[blk * 16 + t] = xr[t];
    } else if (blk < 12628) {
        __shared__ float rowv[2][D];
        __shared__ float red[2][D];
        const int half = t >> 7, tt = t & 127;
        const int row = (blk - 12500) * 2 + half;
        rowv[half][tt] = q[row * D + tt];
        __syncthreads();
        float s = 0.f;
        const float* wr = W + tt * D;
        #pragma unroll 4
        for (int k = 0; k < D; k++) s = fmaf(rowv[half][k], wr[k], s);
        s += bb[tt];
        comb[row * D + tt] = s;
        unsigned ub = __float_as_uint(s);
        unsigned short hv = (unsigned short)((ub + 0x7fffu + ((ub >> 16) & 1u)) >> 16);
        int ksb = tt >> 5, quad = (tt & 31) >> 3, jj = tt & 7;
        int lane = quad * 16 + (row & 15);
        tqsw[(row >> 4) * 2048 + ksb * 512 + lane * 8 + jj] = hv;
        float dd = s - rowv[half][tt];
        red[half][tt] = dd * dd;
        __syncthreads();
        for (int off = 64; off > 0; off >>= 1) { if (tt < off) red[half][tt] += red[half][tt + off]; __syncthreads(); }
        if (tt == 0) atomicAdd(&acc[0], red[half][0]);
    } else if (blk < 12756) {
        const int half = t >> 7, tt = t & 127;
        const int i = (blk - 12628) * 2 + half;
        comb[(256 + i) * D + tt] = X[(long)idx[i] * D + tt];
    } else {
        // W (+b) sum of squares -> acc[7]
        __shared__ float wred[4];
        const int base = (blk - 12756) * 4096;
        float s = 0.f;
        #pragma unroll 4
        for (int k = 0; k < 16; k++) { float v = W[base + k * 256 + t]; s = fmaf(v, v, s); }
        if (blk == 12756 && t < D) { float v = bb[t]; s = fmaf(v, v, s); }
        #pragma unroll
        for (int off = 32; off > 0; off >>= 1) s += __shfl_down(s, off);
        if ((t & 63) == 0) wred[t >> 6] = s;
        __syncthreads();
        if (t == 0) atomicAdd(&acc[7], wred[0] + wred[1] + wred[2] + wred[3]);
    }
}

// ---- D2 (512x512) + fused 12-bit histogram (sharded) ----
__global__ void k_d2h(const float* __restrict__ comb, float* __restrict__ D2w,
                      unsigned* __restrict__ hist0)
{
    __shared__ float ci[D];
    __shared__ float cj[64][D + 4];
    __shared__ unsigned h[4096];
    const int i = blockIdx.x, jb = blockIdx.y, t = threadIdx.x; // 64 threads
    for (int m = t; m < 4096; m += 64) h[m] = 0;
    ci[t] = comb[i * D + t];
    ci[t + 64] = comb[i * D + t + 64];
    const float4* src = (const float4*)(comb + (jb * 64) * D);
    #pragma unroll
    for (int m = 0; m < 32; m++) {
        int u = m * 64 + t;
        int r = u >> 5, c = u & 31;
        float4 v = src[u];
        cj[r][c * 4 + 0] = v.x; cj[r][c * 4 + 1] = v.y; cj[r][c * 4 + 2] = v.z; cj[r][c * 4 + 3] = v.w;
    }
    __syncthreads();
    float s = 0.f;
    #pragma unroll 4
    for (int k = 0; k < D; k++) { float d = ci[k] - cj[t][k]; s = fmaf(d, d, s); }
    D2w[i * 512 + jb * 64 + t] = s;
    atomicAdd(&h[__float_as_uint(s) >> 20], 1u);
    __syncthreads();
    const int sh = (i + jb) & 7;
    for (int m = t; m < 4096; m += 64) { unsigned v = h[m]; if (v) atomicAdd(&hist0[m * 8 + sh], v); }
}

// ---- MFMA body: A resident, chunks of 2 row-tiles, register double-buffered pipeline ----
template<int MODE>
__device__ __forceinline__ void mf_body(const unsigned short* __restrict__ tqsw,
    const unsigned short* __restrict__ xbf, const float* __restrict__ xn,
    const float* __restrict__ thr, float* __restrict__ samp,
    int* __restrict__ cand_i, unsigned* __restrict__ cnt, int chunkN, int stride)
{
    const int t = threadIdx.x;
    const int w = t >> 6, lane = t & 63;
    const int lr = lane & 15, quad = lane >> 4;
    bf16x8 a[4][4];
    #pragma unroll
    for (int i = 0; i < 4; i++)
        #pragma unroll
        for (int ks = 0; ks < 4; ks++)
            a[i][ks] = *(const bf16x8*)(tqsw + (w * 4 + i) * 2048 + ks * 512 + lane * 8);
    float th_r[4][4];
    if (MODE == 1) {
        #pragma unroll
        for (int i = 0; i < 4; i++)
            #pragma unroll
            for (int reg = 0; reg < 4; reg++)
                th_r[i][reg] = thr[w * 64 + i * 16 + quad * 4 + reg];
    }
    int ck = blockIdx.x;
    bf16x8 bc[2][4]; float xnc[2];
    #pragma unroll
    for (int tt = 0; tt < 2; tt++) {
        const long tile = (long)ck * 2 + tt;
        #pragma unroll
        for (int ks = 0; ks < 4; ks++)
            bc[tt][ks] = *(const bf16x8*)(xbf + tile * 2048 + ks * 512 + lane * 8);
        xnc[tt] = xn[tile * 16 + lr];
    }
    while (true) {
        const int ckn = ck + stride;
        const bool has = ckn < chunkN;
        bf16x8 bn[2][4]; float xnn[2];
        if (has) {
            #pragma unroll
            for (int tt = 0; tt < 2; tt++) {
                const long tile = (long)ckn * 2 + tt;
                #pragma unroll
                for (int ks = 0; ks < 4; ks++)
                    bn[tt][ks] = *(const bf16x8*)(xbf + tile * 2048 + ks * 512 + lane * 8);
                xnn[tt] = xn[tile * 16 + lr];
            }
        }
        #pragma unroll
        for (int tt = 0; tt < 2; tt++) {
            f32x4 acc[4];
            #pragma unroll
            for (int i = 0; i < 4; i++) acc[i] = (f32x4){0.f, 0.f, 0.f, 0.f};
            #pragma unroll
            for (int ks = 0; ks < 4; ks++)
                #pragma unroll
                for (int i = 0; i < 4; i++)
                    acc[i] = __builtin_amdgcn_mfma_f32_16x16x32_bf16(a[i][ks], bc[tt][ks], acc[i], 0, 0, 0);
            const int r = (ck * 2 + tt) * 16 + lr;
            if (MODE == 0) {
                #pragma unroll
                for (int i = 0; i < 4; i++)
                    #pragma unroll
                    for (int reg = 0; reg < 4; reg++) {
                        int qq = w * 64 + i * 16 + quad * 4 + reg;
                        samp[qq * NS + r] = xnc[tt] - 2.f * acc[i][reg];
                    }
            } else {
                #pragma unroll
                for (int i = 0; i < 4; i++)
                    #pragma unroll
                    for (int reg = 0; reg < 4; reg++) {
                        float s = xnc[tt] - 2.f * acc[i][reg];
                        if (s <= th_r[i][reg]) {
                            int qq = w * 64 + i * 16 + quad * 4 + reg;
                            unsigned pos = atomicAdd(&cnt[qq * 16], 1u);
                            if (pos < CAP) cand_i[qq * CAP + pos] = r;
                        }
                    }
            }
        }
        if (!has) break;
        #pragma unroll
        for (int tt = 0; tt < 2; tt++) {
            #pragma unroll
            for (int ks = 0; ks < 4; ks++) bc[tt][ks] = bn[tt][ks];
            xnc[tt] = xnn[tt];
        }
        ck = ckn;
    }
}

// ---- mf0 (samples, chunks 0..127 -> rows 0..8191) + scan0 (block 128) ----
__global__ __launch_bounds__(256, 2) void k_mf0(const unsigned short* __restrict__ tqsw,
    const unsigned short* __restrict__ xbf, const float* __restrict__ xn,
    float* __restrict__ samp, const unsigned* __restrict__ hist0, unsigned* __restrict__ sel)
{
    if (blockIdx.x == 128) {
        __shared__ unsigned part[256];
        const int t = threadIdx.x;
        unsigned s = 0;
        for (int m = 0; m < 16; m++) {
            int b = t * 16 + m;
            #pragma unroll
            for (int sh = 0; sh < 8; sh++) s += hist0[b * 8 + sh];
        }
        part[t] = s;
        __syncthreads();
        if (t == 0) {
            for (int tg = 0; tg < 2; tg++) {
                unsigned r = tg ? 131072u : 131071u;
                int c = 0;
                while (part[c] <= r) { r -= part[c]; c++; }
                int b = c * 16;
                while (true) {
                    unsigned bs = 0;
                    #pragma unroll
                    for (int sh = 0; sh < 8; sh++) bs += hist0[b * 8 + sh];
                    if (bs <= r) { r -= bs; b++; } else break;
                }
                sel[2 * tg] = (unsigned)b; sel[2 * tg + 1] = r;
            }
        }
        return;
    }
    mf_body<0>(tqsw, xbf, xn, nullptr, samp, nullptr, nullptr, 256, 128);
}

// ---- hist pass1 (blocks 0..255) + per-query sample threshold (blocks 256..511) ----
__global__ void k_h1thr(const float* __restrict__ D2w, unsigned* __restrict__ hist12,
                        const unsigned* __restrict__ sel, const float* __restrict__ samp,
                        float* __restrict__ thr)
{
    __shared__ unsigned buf[8192];
    __shared__ unsigned wred[4];
    const int t = threadIdx.x;
    if (blockIdx.x < 256) {
        for (int m = t; m < 8192; m += 256) buf[m] = 0;
        __syncthreads();
        unsigned p0 = sel[0], p1 = sel[2];
        const int e0 = blockIdx.x * 1024;
        for (int m = 0; m < 4; m++) {
            unsigned key = __float_as_uint(D2w[e0 + m * 256 + t]);
            if ((key >> 20) == p0) atomicAdd(&buf[(key >> 8) & 0xFFFu], 1u);
            if ((key >> 20) == p1) atomicAdd(&buf[4096 + ((key >> 8) & 0xFFFu)], 1u);
        }
        __syncthreads();
        for (int m = t; m < 8192; m += 256) { unsigned v = buf[m]; if (v) atomicAdd(&hist12[m], v); }
    } else {
        const int q = blockIdx.x - 256;
        for (int m = t; m < NS; m += 256) buf[m] = fkey(samp[q * NS + m]);
        __syncthreads();
        unsigned v = 0;
        for (int bit = 31; bit >= 0; bit--) {
            unsigned trial = v | (1u << bit);
            unsigned c = 0;
            for (int m = t; m < NS; m += 256) c += (buf[m] < trial) ? 1u : 0u;
            #pragma unroll
            for (int off = 32; off > 0; off >>= 1) c += __shfl_down(c, off);
            if ((t & 63) == 0) wred[t >> 6] = c;
            __syncthreads();
            unsigned total = wred[0] + wred[1] + wred[2] + wred[3];
            __syncthreads();
            if (total <= (unsigned)(KNN - 1)) v = trial;
        }
        if (t == 0) {
            unsigned orig = (v & 0x80000000u) ? (v ^ 0x80000000u) : ~v;
            thr[q] = __uint_as_float(orig) + SLACK;
        }
    }
}

// ---- hist pass2 with fused local scan1 (block 0 persists sel[4..7]) ----
__global__ void k_hist2s(const float* __restrict__ D2w, unsigned* __restrict__ hist12,
                         unsigned* __restrict__ sel)
{
    __shared__ unsigned h[8192];
    __shared__ unsigned part[256];
    __shared__ unsigned pfx[2];
    __shared__ unsigned rr[2];
    const int t = threadIdx.x;
    for (int tg = 0; tg < 2; tg++) {
        const unsigned* hh = hist12 + tg * 4096;
        unsigned s = 0;
        for (int m = 0; m < 16; m++) s += hh[t * 16 + m];
        part[t] = s;
        __syncthreads();
        if (t == 0) {
            unsigned r = sel[1 + 2 * tg];
            int c = 0;
            while (part[c] <= r) { r -= part[c]; c++; }
            int b = c * 16;
            while (hh[b] <= r) { r -= hh[b]; b++; }
            pfx[tg] = (sel[2 * tg] << 12) | (unsigned)b;
            rr[tg] = r;
        }
        __syncthreads();
    }
    if (blockIdx.x == 0 && t == 0) {
        sel[4] = pfx[0]; sel[5] = rr[0]; sel[6] = pfx[1]; sel[7] = rr[1];
    }
    for (int m = t; m < 8192; m += 256) h[m] = 0;
    __syncthreads();
    unsigned p0 = pfx[0], p1 = pfx[1];
    const int e0 = blockIdx.x * 1024;
    for (int m = 0; m < 4; m++) {
        unsigned key = __float_as_uint(D2w[e0 + m * 256 + t]);
        if ((key >> 8) == p0) atomicAdd(&h[key & 0xFFu], 1u);
        if ((key >> 8) == p1) atomicAdd(&h[4096 + (key & 0xFFu)], 1u);
    }
    __syncthreads();
    unsigned* gp = hist12 + 8192;
    for (int m = t; m < 8192; m += 256) { unsigned v = h[m]; if (v) atomicAdd(&gp[m], v); }
}

// ---- mf1 (filter, chunks 0..6249) + mmd with fused local scan2 (blocks 1024..1279) ----
__global__ __launch_bounds__(256, 2) void k_mf1(const unsigned short* __restrict__ tqsw,
    const unsigned short* __restrict__ xbf, const float* __restrict__ xn,
    const float* __restrict__ thr, int* __restrict__ cand_i, unsigned* __restrict__ cnt,
    const float* __restrict__ D2w, const unsigned* __restrict__ hist12,
    const unsigned* __restrict__ sel, float* __restrict__ acc)
{
    if (blockIdx.x >= 1024) {
        __shared__ unsigned h2[512];
        __shared__ float gsh;
        __shared__ float part[12];
        const int t = threadIdx.x, w = t >> 6;
        h2[t] = hist12[8192 + t];
        h2[256 + t] = hist12[8192 + 4096 + t];
        __syncthreads();
        if (t == 0) {
            unsigned key[2];
            for (int tg = 0; tg < 2; tg++) {
                unsigned r = sel[5 + 2 * tg];
                const unsigned* hh = h2 + tg * 256;
                int b = 0;
                while (hh[b] <= r) { r -= hh[b]; b++; }
                key[tg] = (sel[4 + 2 * tg] << 8) | (unsigned)b;
            }
            float med = 0.5f * (__uint_as_float(key[0]) + __uint_as_float(key[1]));
            float ssq = 0.5f * med;
            if (ssq < 1e-6f) ssq = 1.0f;
            gsh = 1.0f / (ssq + 1e-8f);
        }
        __syncthreads();
        const float g = gsh;
        float s[3] = {0.f, 0.f, 0.f};
        const int e0 = (blockIdx.x - 1024) * 1024;
        #pragma unroll
        for (int m = 0; m < 4; m++) {
            int e = e0 + m * 256 + t;
            int i = e >> 9, j = e & 511;
            float v = expf(-g * D2w[e]);
            int qd = (i < 256) ? ((j < 256) ? 0 : 2) : ((j < 256) ? 2 : 1);
            s[qd] += v;
        }
        #pragma unroll
        for (int c = 0; c < 3; c++) {
            float x = s[c];
            #pragma unroll
            for (int off = 32; off > 0; off >>= 1) x += __shfl_down(x, off);
            if ((t & 63) == 0) part[w * 3 + c] = x;
        }
        __syncthreads();
        if (t == 0)
            for (int c = 0; c < 3; c++)
                atomicAdd(&acc[2 + c], part[c] + part[3 + c] + part[6 + c] + part[9 + c]);
        return;
    }
    mf_body<1>(tqsw, xbf, xn, thr, nullptr, cand_i, cnt, 6250, 1024);
}

// ---- exact f32 rescore of candidates (high-occupancy, 8 splits per query) ----
__global__ void k_rescore(const float* __restrict__ comb, const float* __restrict__ X,
                          const float* __restrict__ xn, const int* __restrict__ cand_i,
                          const unsigned* __restrict__ cnt, unsigned* __restrict__ ksg)
{
    __shared__ float qrow[D];
    const int q = blockIdx.x, sp = blockIdx.y, t = threadIdx.x;
    if (t < D) qrow[t] = comb[q * D + t];
    __syncthreads();
    unsigned nn = cnt[q * 16];
    const int n = (nn < (unsigned)CAP) ? (int)nn : CAP;
    const int g = t >> 3, j = t & 7;
    for (int m = sp * 32 + g; m < n; m += 256) {
        int r = cand_i[q * CAP + m];
        const float4* xr = (const float4*)(X + (long)r * D);
        float s = 0.f;
        #pragma unroll
        for (int p = 0; p < 4; p++) {
            float4 xv = xr[j * 4 + p];
            float4 qv = *(const float4*)&qrow[(j * 4 + p) * 4];
            s = fmaf(xv.x, qv.x, fmaf(xv.y, qv.y, fmaf(xv.z, qv.z, fmaf(xv.w, qv.w, s))));
        }
        s += __shfl_down(s, 4); s += __shfl_down(s, 2); s += __shfl_down(s, 1);
        if (j == 0) ksg[q * CAP + m] = fkey(xn[r] - 2.f * s);
    }
}

// ---- per-query: top-50 from precomputed keys -> l2 -> softmax -> union KL ----
__global__ void k_post2(const float* __restrict__ comb, const float* __restrict__ X,
                        const int* __restrict__ cand_i, const unsigned* __restrict__ cnt,
                        const unsigned* __restrict__ ksg, const int* __restrict__ pri,
                        const float* __restrict__ prw, const int* __restrict__ qix,
                        float* __restrict__ acc)
{
    __shared__ unsigned ks[CAP];
    __shared__ float qrow[D];
    __shared__ unsigned wred[4];
    __shared__ unsigned wpos, eqn;
    __shared__ int eq[64];
    __shared__ int pidx[KNN];
    __shared__ float l2s[KNN];
    __shared__ float pw[KNN];
    __shared__ int ci[100];
    __shared__ float pwv[50], qwv[50];
    __shared__ float pterm[100], qterm[100], kterm[100];
    __shared__ float Sp, Sq;
    const int q = blockIdx.x, t = threadIdx.x;
    if (t < D) qrow[t] = comb[q * D + t];
    if (t == 0) { wpos = 0; eqn = 0; }
    unsigned nn = cnt[q * 16];
    const int n = (nn < (unsigned)CAP) ? (int)nn : CAP;
    for (int m = t; m < n; m += 256) ks[m] = ksg[q * CAP + m];
    __syncthreads();
    int kk = KNN - 1; if (kk > n - 1) kk = n - 1;
    unsigned v = 0;
    for (int bit = 31; bit >= 0; bit--) {
        unsigned trial = v | (1u << bit);
        unsigned c = 0;
        for (int m = t; m < n; m += 256) c += (ks[m] < trial) ? 1u : 0u;
        #pragma unroll
        for (int off = 32; off > 0; off >>= 1) c += __shfl_down(c, off);
        if ((t & 63) == 0) wred[t >> 6] = c;
        __syncthreads();
        unsigned total = wred[0] + wred[1] + wred[2] + wred[3];
        __syncthreads();
        if (total <= (unsigned)kk) v = trial;
    }
    for (int m = t; m < n; m += 256) {
        if (ks[m] < v) {
            unsigned p = atomicAdd(&wpos, 1u);
            pidx[p] = cand_i[q * CAP + m];
        } else if (ks[m] == v) {
            unsigned p = atomicAdd(&eqn, 1u);
            if (p < 64) eq[p] = cand_i[q * CAP + m];
        }
    }
    __syncthreads();
    if (t == 0) {
        int c1 = (int)wpos, need = KNN - c1;
        int ne = (eqn < 64u) ? (int)eqn : 64;
        for (int a = 0; a < ne; a++)
            for (int b2 = a + 1; b2 < ne; b2++)
                if (eq[b2] < eq[a]) { int tmp = eq[a]; eq[a] = eq[b2]; eq[b2] = tmp; }
        for (int a = 0; a < need && a < ne; a++) pidx[c1 + a] = eq[a];
    }
    __syncthreads();
    const int g = t >> 3, j = t & 7;
    for (int nb = g; nb < KNN; nb += 32) {
        long r = pidx[nb];
        const float4* xr = (const float4*)(X + r * D);
        float s = 0.f;
        #pragma unroll
        for (int p = 0; p < 4; p++) {
            float4 xv = xr[j * 4 + p];
            float4 qv = *(const float4*)&qrow[(j * 4 + p) * 4];
            float d0 = qv.x - xv.x, d1 = qv.y - xv.y, d2 = qv.z - xv.z, d3 = qv.w - xv.w;
            s += d0 * d0 + d1 * d1 + d2 * d2 + d3 * d3;
        }
        s += __shfl_down(s, 4); s += __shfl_down(s, 2); s += __shfl_down(s, 1);
        if (j == 0) l2s[nb] = s;
    }
    int qi = qix[q];
    if (t >= 128 && t < 178) { int k = t - 128; ci[k] = pri[qi * 50 + k]; pwv[k] = prw[qi * 50 + k]; }
    __syncthreads();
    if (t < 64) {
        float logit = (t < KNN) ? (-l2s[t] * 10.0f) : -3.4e38f; // 1/tau = 10
        float m = logit;
        #pragma unroll
        for (int off = 32; off > 0; off >>= 1) m = fmaxf(m, __shfl_down(m, off));
        m = __shfl(m, 0);
        float e = (t < KNN) ? expf(logit - m) : 0.f;
        float ss = e;
        #pragma unroll
        for (int off = 32; off > 0; off >>= 1) ss += __shfl_down(ss, off);
        ss = __shfl(ss, 0);
        if (t < KNN) pw[t] = e / ss;
    }
    __syncthreads();
    if (t < 50) { ci[50 + t] = pidx[t]; qwv[t] = pw[t]; }
    __syncthreads();
    float pc = 0.f, qc = 0.f, mult = 0.f;
    if (t < 100) {
        int c = ci[t];
        float pr = 0.f, qr = 0.f;
        for (int k = 0; k < 50; k++) {
            bool m1 = (c == ci[k]); bool m2 = (c == ci[50 + k]);
            mult += (m1 ? 1.f : 0.f) + (m2 ? 1.f : 0.f);
            pr += m1 ? pwv[k] : 0.f;
            qr += m2 ? qwv[k] : 0.f;
        }
        pc = fmaxf(pr, 1e-8f); qc = fmaxf(qr, 1e-8f);
        pterm[t] = pc / mult; qterm[t] = qc / mult;
    }
    __syncthreads();
    if (t == 0) { float a = 0.f, b2 = 0.f; for (int m = 0; m < 100; m++) { a += pterm[m]; b2 += qterm[m]; } Sp = a; Sq = b2; }
    __syncthreads();
    if (t < 100) {
        float p = pc / Sp, qq2 = qc / Sq;
        kterm[t] = (p * (logf(p) - logf(qq2))) / mult;
    }
    __syncthreads();
    if (t == 0) { float s = 0.f; for (int m = 0; m < 100; m++) s += kterm[m]; atomicAdd(&acc[1], s); }
}

// ---- final assembly (reg precomputed in phase1) ----
__global__ void k_final(const float* __restrict__ acc, float* __restrict__ out)
{
    if (threadIdx.x == 0) {
        float reg = 0.5f * acc[7];
        float kxx = acc[2] / 65536.f, kyy = acc[3] / 65536.f, kxy = acc[4] / 131072.f;
        float ld = fmaxf(kxx + kyy - 2.f * kxy, 0.f);
        float lknn = acc[1] / 256.f;
        float lanc = acc[0] / 256.f;
        out[0] = ld + lknn + 1e-4f * reg + lanc;
        out[1] = ld; out[2] = lknn; out[3] = lanc;
    }
}

extern "C" void kernel_launch(void* const* d_in, const int* in_sizes, int n_in,
                              void* d_out, int out_size, void* d_ws, size_t ws_size,
                              hipStream_t stream)
{
    (void)in_sizes; (void)n_in; (void)out_size; (void)ws_size;
    const float* q   = (const float*)d_in[0];
    const float* X   = (const float*)d_in[1];
    const float* W   = (const float*)d_in[2];
    const float* bb  = (const float*)d_in[3];
    const float* prw = (const float*)d_in[4];
    const int*   pri = (const int*)d_in[5];
    const int*   qix = (const int*)d_in[6];
    const int*   idx = (const int*)d_in[7];
    float* out = (float*)d_out;
    char* ws = (char*)d_ws;
    float*    acc   = (float*)(ws + OFF_ACC);
    unsigned* sel   = (unsigned*)(ws + OFF_SEL);
    unsigned* cnt   = (unsigned*)(ws + OFF_CNT);
    unsigned* hist0 = (unsigned*)(ws + OFF_HIST0);
    unsigned* hist12= (unsigned*)(ws + OFF_HIST12);
    float*    comb  = (float*)(ws + OFF_COMB);
    float*    D2w   = (float*)(ws + OFF_D2);
    float*    xn    = (float*)(ws + OFF_XN);
    float*    samp  = (float*)(ws + OFF_SAMP);
    float*    thr   = (float*)(ws + OFF_THR);
    int*      cix   = (int*)(ws + OFF_CANDI);
    unsigned* ksg   = (unsigned*)(ws + OFF_KSG);
    unsigned short* tqsw = (unsigned short*)(ws + OFF_TQSW);
    unsigned short* xbf  = (unsigned short*)(ws + OFF_XBF);

    hipMemsetAsync(ws, 0, MEMSET_BYTES, stream);
    hipLaunchKernelGGL(k_phase1,  dim3(12760),   dim3(256), 0, stream, q, X, W, bb, idx, comb, tqsw, xbf, xn, acc);
    hipLaunchKernelGGL(k_d2h,     dim3(512, 8),  dim3(64),  0, stream, comb, D2w, hist0);
    hipLaunchKernelGGL(k_mf0,     dim3(129),     dim3(256), 0, stream, tqsw, xbf, xn, samp, hist0, sel);
    hipLaunchKernelGGL(k_h1thr,   dim3(512),     dim3(256), 0, stream, D2w, hist12, sel, samp, thr);
    hipLaunchKernelGGL(k_hist2s,  dim3(256),     dim3(256), 0, stream, D2w, hist12, sel);
    hipLaunchKernelGGL(k_mf1,     dim3(1280),    dim3(256), 0, stream, tqsw, xbf, xn, thr, cix, cnt, D2w, hist12, sel, acc);
    hipLaunchKernelGGL(k_rescore, dim3(256, 8),  dim3(256), 0, stream, comb, X, xn, cix, cnt, ksg);
    hipLaunchKernelGGL(k_post2,   dim3(256),     dim3(256), 0, stream, comb, X, cix, cnt, ksg, pri, prw, qix, acc);
    hipLaunchKernelGGL(k_final,   dim3(1),       dim3(64),  0, stream, acc, out);
}

// Round 7
// 436.660 us; speedup vs baseline: 3.7808x; 1.0891x over previous
//
#include <hip/hip_runtime.h>
#include <cstdint>

#define D 128
#define NPTS 200000
#define KNN 50
#define CAP 8192
#define NS 8192
#define SLACK 2.0f

// ---- workspace byte offsets ----
#define OFF_ACC    0         // 32 f32 (zeroed)
#define OFF_SEL    256       // 16 u32 (zeroed)
#define OFF_CNT    1024      // 256*16 u32 (zeroed, 1 counter / 64B line)
#define OFF_HIST0  17408     // 4096*8 u32 sharded (zeroed)
#define OFF_HIST12 148480    // 2*2*4096 u32 (zeroed)
#define MEMSET_BYTES 214016
#define OFF_COMB   214016    // 512*128 f32
#define OFF_D2     476160    // 262144 f32
#define OFF_XN     1524736   // 200000 f32
#define OFF_SAMP   2324736   // 256*8192 f32
#define OFF_THR    10713344  // 256 f32
#define OFF_CANDI  10714368  // 256*8192 i32
#define OFF_KSG    19102976  // 256*8192 u32 rescored keys
#define OFF_TQSW   27491584  // 256*128 bf16 swizzled
#define OFF_XBF    27557120  // 200000*128 bf16 swizzled (51.2 MB)

typedef __attribute__((ext_vector_type(8))) short bf16x8;
typedef __attribute__((ext_vector_type(4))) float f32x4;
typedef const __attribute__((address_space(1))) void* gas_p;
typedef __attribute__((address_space(3))) void* las_p;

__device__ __forceinline__ unsigned fkey(float f) {
    unsigned u = __float_as_uint(f);
    return u ^ ((unsigned)((int)u >> 31) | 0x80000000u);
}

// async-stage 8KB chunk (4096 ushorts) into LDS: wave-uniform lds base, lane*16B implicit
__device__ __forceinline__ void stage8k(const unsigned short* __restrict__ g,
                                        unsigned short* l, int w, int lane)
{
    #pragma unroll
    for (int j = 0; j < 2; j++) {
        const unsigned short* gp = g + j * 2048 + w * 512 + lane * 8;
        unsigned short* lp = l + j * 2048 + w * 512;
        __builtin_amdgcn_global_load_lds((gas_p)gp, (las_p)lp, 16, 0, 0);
    }
}

// ---- phase 1: X->bf16 swizzle + xnorm | Tq=qW^T+b (+swizzle, anchor) | comb X[idx] | W reg ----
__global__ void k_phase1(const float* __restrict__ q, const float* __restrict__ X,
                         const float* __restrict__ W, const float* __restrict__ bb,
                         const int* __restrict__ idx, float* __restrict__ comb,
                         unsigned short* __restrict__ tqsw, unsigned short* __restrict__ xbf,
                         float* __restrict__ xn, float* __restrict__ acc)
{
    const int blk = blockIdx.x, t = threadIdx.x;
    if (blk < 12500) {
        __shared__ float xr[16];
        const int lr = t & 15;
        if (t < 16) xr[t] = 0.f;
        __syncthreads();
        const float4* src = (const float4*)(X + ((long)(blk * 16 + lr)) * D + (t >> 4) * 8);
        float4 v0 = src[0], v1 = src[1];
        uint4 pk;
        pk.x = (__float_as_uint(v0.x) >> 16) | (__float_as_uint(v0.y) & 0xFFFF0000u);
        pk.y = (__float_as_uint(v0.z) >> 16) | (__float_as_uint(v0.w) & 0xFFFF0000u);
        pk.z = (__float_as_uint(v1.x) >> 16) | (__float_as_uint(v1.y) & 0xFFFF0000u);
        pk.w = (__float_as_uint(v1.z) >> 16) | (__float_as_uint(v1.w) & 0xFFFF0000u);
        *(uint4*)(xbf + (long)blk * 2048 + t * 8) = pk;
        float ssq = v0.x*v0.x + v0.y*v0.y + v0.z*v0.z + v0.w*v0.w
                  + v1.x*v1.x + v1.y*v1.y + v1.z*v1.z + v1.w*v1.w;
        atomicAdd(&xr[lr], ssq);
        __syncthreads();
        if (t < 16) xn[blk * 16 + t] = xr[t];
    } else if (blk < 12628) {
        __shared__ float rowv[2][D];
        __shared__ float red[2][D];
        const int half = t >> 7, tt = t & 127;
        const int row = (blk - 12500) * 2 + half;
        rowv[half][tt] = q[row * D + tt];
        __syncthreads();
        float s = 0.f;
        const float* wr = W + tt * D;
        #pragma unroll 4
        for (int k = 0; k < D; k++) s = fmaf(rowv[half][k], wr[k], s);
        s += bb[tt];
        comb[row * D + tt] = s;
        unsigned ub = __float_as_uint(s);
        unsigned short hv = (unsigned short)((ub + 0x7fffu + ((ub >> 16) & 1u)) >> 16);
        int ksb = tt >> 5, quad = (tt & 31) >> 3, jj = tt & 7;
        int lane = quad * 16 + (row & 15);
        tqsw[(row >> 4) * 2048 + ksb * 512 + lane * 8 + jj] = hv;
        float dd = s - rowv[half][tt];
        red[half][tt] = dd * dd;
        __syncthreads();
        for (int off = 64; off > 0; off >>= 1) { if (tt < off) red[half][tt] += red[half][tt + off]; __syncthreads(); }
        if (tt == 0) atomicAdd(&acc[0], red[half][0]);
    } else if (blk < 12756) {
        const int half = t >> 7, tt = t & 127;
        const int i = (blk - 12628) * 2 + half;
        comb[(256 + i) * D + tt] = X[(long)idx[i] * D + tt];
    } else {
        __shared__ float wred[4];
        const int base = (blk - 12756) * 4096;
        float s = 0.f;
        #pragma unroll 4
        for (int k = 0; k < 16; k++) { float v = W[base + k * 256 + t]; s = fmaf(v, v, s); }
        if (blk == 12756 && t < D) { float v = bb[t]; s = fmaf(v, v, s); }
        #pragma unroll
        for (int off = 32; off > 0; off >>= 1) s += __shfl_down(s, off);
        if ((t & 63) == 0) wred[t >> 6] = s;
        __syncthreads();
        if (t == 0) atomicAdd(&acc[7], wred[0] + wred[1] + wred[2] + wred[3]);
    }
}

// ---- D2 (512x512) + fused 12-bit histogram; 4 waves share one cj stage ----
__global__ void k_d2h(const float* __restrict__ comb, float* __restrict__ D2w,
                      unsigned* __restrict__ hist0)
{
    __shared__ float cj[64][D + 1];
    __shared__ float ci[4][D];
    __shared__ unsigned h[4096];
    const int ib = blockIdx.x, jb = blockIdx.y, t = threadIdx.x;
    const int w = t >> 6, l = t & 63;
    for (int m = t; m < 4096; m += 256) h[m] = 0;
    const int irow = ib * 4 + w;
    ci[w][l] = comb[irow * D + l];
    ci[w][l + 64] = comb[irow * D + l + 64];
    const float4* src = (const float4*)(comb + (jb * 64) * D);
    #pragma unroll
    for (int m = 0; m < 8; m++) {
        int u = m * 256 + t;
        int r = u >> 5, c = u & 31;
        float4 v = src[u];
        cj[r][c * 4 + 0] = v.x; cj[r][c * 4 + 1] = v.y; cj[r][c * 4 + 2] = v.z; cj[r][c * 4 + 3] = v.w;
    }
    __syncthreads();
    float s = 0.f;
    #pragma unroll 4
    for (int k = 0; k < D; k++) { float d = ci[w][k] - cj[l][k]; s = fmaf(d, d, s); }
    D2w[irow * 512 + jb * 64 + l] = s;
    atomicAdd(&h[__float_as_uint(s) >> 20], 1u);
    __syncthreads();
    const int sh = (ib + jb) & 7;
    for (int m = t; m < 4096; m += 256) { unsigned v = h[m]; if (v) atomicAdd(&hist0[m * 8 + sh], v); }
}

// ---- mf0: samples via LDS-staged chunks (blocks 0..255 = one 32-row chunk) + scan0 (block 256) ----
__global__ __launch_bounds__(256) void k_mf0(const unsigned short* __restrict__ tqsw,
    const unsigned short* __restrict__ xbf, const float* __restrict__ xn,
    float* __restrict__ samp, const unsigned* __restrict__ hist0, unsigned* __restrict__ sel)
{
    if (blockIdx.x == 256) {
        __shared__ unsigned part[256];
        const int t = threadIdx.x;
        unsigned s = 0;
        for (int m = 0; m < 16; m++) {
            int b = t * 16 + m;
            #pragma unroll
            for (int sh = 0; sh < 8; sh++) s += hist0[b * 8 + sh];
        }
        part[t] = s;
        __syncthreads();
        if (t == 0) {
            for (int tg = 0; tg < 2; tg++) {
                unsigned r = tg ? 131072u : 131071u;
                int c = 0;
                while (part[c] <= r) { r -= part[c]; c++; }
                int b = c * 16;
                while (true) {
                    unsigned bs = 0;
                    #pragma unroll
                    for (int sh = 0; sh < 8; sh++) bs += hist0[b * 8 + sh];
                    if (bs <= r) { r -= bs; b++; } else break;
                }
                sel[2 * tg] = (unsigned)b; sel[2 * tg + 1] = r;
            }
        }
        return;
    }
    __shared__ unsigned short sb[4096]; // 8 KB chunk
    const int t = threadIdx.x;
    const int w = t >> 6, lane = t & 63;
    const int lr = lane & 15, quad = lane >> 4;
    const int ck = blockIdx.x;
    stage8k(xbf + (long)ck * 4096, sb, w, lane);
    bf16x8 a[4][4];
    #pragma unroll
    for (int i = 0; i < 4; i++)
        #pragma unroll
        for (int ks = 0; ks < 4; ks++)
            a[i][ks] = *(const bf16x8*)(tqsw + (w * 4 + i) * 2048 + ks * 512 + lane * 8);
    __syncthreads();
    #pragma unroll
    for (int tt = 0; tt < 2; tt++) {
        const int r = (ck * 2 + tt) * 16 + lr;
        float xnv = xn[r];
        bf16x8 b[4];
        #pragma unroll
        for (int ks = 0; ks < 4; ks++)
            b[ks] = *(const bf16x8*)(sb + tt * 2048 + ks * 512 + lane * 8);
        f32x4 acc[4];
        #pragma unroll
        for (int i = 0; i < 4; i++) acc[i] = (f32x4){0.f, 0.f, 0.f, 0.f};
        #pragma unroll
        for (int ks = 0; ks < 4; ks++)
            #pragma unroll
            for (int i = 0; i < 4; i++)
                acc[i] = __builtin_amdgcn_mfma_f32_16x16x32_bf16(a[i][ks], b[ks], acc[i], 0, 0, 0);
        #pragma unroll
        for (int i = 0; i < 4; i++)
            #pragma unroll
            for (int reg = 0; reg < 4; reg++) {
                int qq = w * 64 + i * 16 + quad * 4 + reg;
                samp[qq * NS + r] = xnv - 2.f * acc[i][reg];
            }
    }
}

// ---- hist pass1 (blocks 0..255) + per-query sample threshold (blocks 256..511) ----
__global__ void k_h1thr(const float* __restrict__ D2w, unsigned* __restrict__ hist12,
                        const unsigned* __restrict__ sel, const float* __restrict__ samp,
                        float* __restrict__ thr)
{
    __shared__ unsigned buf[8192];
    __shared__ unsigned wred[4];
    const int t = threadIdx.x;
    if (blockIdx.x < 256) {
        for (int m = t; m < 8192; m += 256) buf[m] = 0;
        __syncthreads();
        unsigned p0 = sel[0], p1 = sel[2];
        const int e0 = blockIdx.x * 1024;
        for (int m = 0; m < 4; m++) {
            unsigned key = __float_as_uint(D2w[e0 + m * 256 + t]);
            if ((key >> 20) == p0) atomicAdd(&buf[(key >> 8) & 0xFFFu], 1u);
            if ((key >> 20) == p1) atomicAdd(&buf[4096 + ((key >> 8) & 0xFFFu)], 1u);
        }
        __syncthreads();
        for (int m = t; m < 8192; m += 256) { unsigned v = buf[m]; if (v) atomicAdd(&hist12[m], v); }
    } else {
        const int q = blockIdx.x - 256;
        for (int m = t; m < NS; m += 256) buf[m] = fkey(samp[q * NS + m]);
        __syncthreads();
        unsigned v = 0;
        for (int bit = 31; bit >= 0; bit--) {
            unsigned trial = v | (1u << bit);
            unsigned c = 0;
            for (int m = t; m < NS; m += 256) c += (buf[m] < trial) ? 1u : 0u;
            #pragma unroll
            for (int off = 32; off > 0; off >>= 1) c += __shfl_down(c, off);
            if ((t & 63) == 0) wred[t >> 6] = c;
            __syncthreads();
            unsigned total = wred[0] + wred[1] + wred[2] + wred[3];
            __syncthreads();
            if (total <= (unsigned)(KNN - 1)) v = trial;
        }
        if (t == 0) {
            unsigned orig = (v & 0x80000000u) ? (v ^ 0x80000000u) : ~v;
            thr[q] = __uint_as_float(orig) + SLACK;
        }
    }
}

// ---- hist pass2 with fused local scan1 (block 0 persists sel[4..7]) ----
__global__ void k_hist2s(const float* __restrict__ D2w, unsigned* __restrict__ hist12,
                         unsigned* __restrict__ sel)
{
    __shared__ unsigned h[8192];
    __shared__ unsigned part[256];
    __shared__ unsigned pfx[2];
    __shared__ unsigned rr[2];
    const int t = threadIdx.x;
    for (int tg = 0; tg < 2; tg++) {
        const unsigned* hh = hist12 + tg * 4096;
        unsigned s = 0;
        for (int m = 0; m < 16; m++) s += hh[t * 16 + m];
        part[t] = s;
        __syncthreads();
        if (t == 0) {
            unsigned r = sel[1 + 2 * tg];
            int c = 0;
            while (part[c] <= r) { r -= part[c]; c++; }
            int b = c * 16;
            while (hh[b] <= r) { r -= hh[b]; b++; }
            pfx[tg] = (sel[2 * tg] << 12) | (unsigned)b;
            rr[tg] = r;
        }
        __syncthreads();
    }
    if (blockIdx.x == 0 && t == 0) {
        sel[4] = pfx[0]; sel[5] = rr[0]; sel[6] = pfx[1]; sel[7] = rr[1];
    }
    for (int m = t; m < 8192; m += 256) h[m] = 0;
    __syncthreads();
    unsigned p0 = pfx[0], p1 = pfx[1];
    const int e0 = blockIdx.x * 1024;
    for (int m = 0; m < 4; m++) {
        unsigned key = __float_as_uint(D2w[e0 + m * 256 + t]);
        if ((key >> 8) == p0) atomicAdd(&h[key & 0xFFu], 1u);
        if ((key >> 8) == p1) atomicAdd(&h[4096 + (key & 0xFFu)], 1u);
    }
    __syncthreads();
    unsigned* gp = hist12 + 8192;
    for (int m = t; m < 8192; m += 256) { unsigned v = h[m]; if (v) atomicAdd(&gp[m], v); }
}

// ---- mf1: filter via LDS double-buffered chunks (blocks 0..1023) + mmd/scan2 (1024..1279) ----
__global__ __launch_bounds__(256) void k_mf1(const unsigned short* __restrict__ tqsw,
    const unsigned short* __restrict__ xbf, const float* __restrict__ xn,
    const float* __restrict__ thr, int* __restrict__ cand_i, unsigned* __restrict__ cnt,
    const float* __restrict__ D2w, const unsigned* __restrict__ hist12,
    const unsigned* __restrict__ sel, float* __restrict__ acc)
{
    if (blockIdx.x >= 1024) {
        __shared__ unsigned h2[512];
        __shared__ float gsh;
        __shared__ float part[12];
        const int t = threadIdx.x, w = t >> 6;
        h2[t] = hist12[8192 + t];
        h2[256 + t] = hist12[8192 + 4096 + t];
        __syncthreads();
        if (t == 0) {
            unsigned key[2];
            for (int tg = 0; tg < 2; tg++) {
                unsigned r = sel[5 + 2 * tg];
                const unsigned* hh = h2 + tg * 256;
                int b = 0;
                while (hh[b] <= r) { r -= hh[b]; b++; }
                key[tg] = (sel[4 + 2 * tg] << 8) | (unsigned)b;
            }
            float med = 0.5f * (__uint_as_float(key[0]) + __uint_as_float(key[1]));
            float ssq = 0.5f * med;
            if (ssq < 1e-6f) ssq = 1.0f;
            gsh = 1.0f / (ssq + 1e-8f);
        }
        __syncthreads();
        const float g = gsh;
        float s[3] = {0.f, 0.f, 0.f};
        const int e0 = (blockIdx.x - 1024) * 1024;
        #pragma unroll
        for (int m = 0; m < 4; m++) {
            int e = e0 + m * 256 + t;
            int i = e >> 9, j = e & 511;
            float v = expf(-g * D2w[e]);
            int qd = (i < 256) ? ((j < 256) ? 0 : 2) : ((j < 256) ? 2 : 1);
            s[qd] += v;
        }
        #pragma unroll
        for (int c = 0; c < 3; c++) {
            float x = s[c];
            #pragma unroll
            for (int off = 32; off > 0; off >>= 1) x += __shfl_down(x, off);
            if ((t & 63) == 0) part[w * 3 + c] = x;
        }
        __syncthreads();
        if (t == 0)
            for (int c = 0; c < 3; c++)
                atomicAdd(&acc[2 + c], part[c] + part[3 + c] + part[6 + c] + part[9 + c]);
        return;
    }
    __shared__ unsigned short sb[2][4096]; // double-buffered 8 KB chunks
    const int t = threadIdx.x;
    const int w = t >> 6, lane = t & 63;
    const int lr = lane & 15, quad = lane >> 4;
    bf16x8 a[4][4];
    #pragma unroll
    for (int i = 0; i < 4; i++)
        #pragma unroll
        for (int ks = 0; ks < 4; ks++)
            a[i][ks] = *(const bf16x8*)(tqsw + (w * 4 + i) * 2048 + ks * 512 + lane * 8);
    float th_r[4][4];
    #pragma unroll
    for (int i = 0; i < 4; i++)
        #pragma unroll
        for (int reg = 0; reg < 4; reg++)
            th_r[i][reg] = thr[w * 64 + i * 16 + quad * 4 + reg];
    int ck = blockIdx.x;
    int cur = 0;
    stage8k(xbf + (long)ck * 4096, sb[0], w, lane);
    __syncthreads();
    while (true) {
        const int ckn = ck + 1024;
        const bool has = ckn < 6250;
        if (has) stage8k(xbf + (long)ckn * 4096, sb[cur ^ 1], w, lane);
        #pragma unroll
        for (int tt = 0; tt < 2; tt++) {
            const int r = (ck * 2 + tt) * 16 + lr;
            float xnv = xn[r];
            bf16x8 b[4];
            #pragma unroll
            for (int ks = 0; ks < 4; ks++)
                b[ks] = *(const bf16x8*)(sb[cur] + tt * 2048 + ks * 512 + lane * 8);
            f32x4 acc4[4];
            #pragma unroll
            for (int i = 0; i < 4; i++) acc4[i] = (f32x4){0.f, 0.f, 0.f, 0.f};
            #pragma unroll
            for (int ks = 0; ks < 4; ks++)
                #pragma unroll
                for (int i = 0; i < 4; i++)
                    acc4[i] = __builtin_amdgcn_mfma_f32_16x16x32_bf16(a[i][ks], b[ks], acc4[i], 0, 0, 0);
            #pragma unroll
            for (int i = 0; i < 4; i++)
                #pragma unroll
                for (int reg = 0; reg < 4; reg++) {
                    float s = xnv - 2.f * acc4[i][reg];
                    if (s <= th_r[i][reg]) {
                        int qq = w * 64 + i * 16 + quad * 4 + reg;
                        unsigned pos = atomicAdd(&cnt[qq * 16], 1u);
                        if (pos < CAP) cand_i[qq * CAP + pos] = r;
                    }
                }
        }
        if (!has) break;
        __syncthreads(); // drains prefetch (vmcnt) + protects buffer swap
        ck = ckn; cur ^= 1;
    }
}

// ---- exact f32 rescore of candidates (16 splits per query for co-residency) ----
__global__ void k_rescore(const float* __restrict__ comb, const float* __restrict__ X,
                          const float* __restrict__ xn, const int* __restrict__ cand_i,
                          const unsigned* __restrict__ cnt, unsigned* __restrict__ ksg)
{
    __shared__ float qrow[D];
    const int q = blockIdx.x, sp = blockIdx.y, t = threadIdx.x;
    if (t < D) qrow[t] = comb[q * D + t];
    __syncthreads();
    unsigned nn = cnt[q * 16];
    const int n = (nn < (unsigned)CAP) ? (int)nn : CAP;
    const int g = t >> 3, j = t & 7;
    for (int m = sp * 32 + g; m < n; m += 512) {
        int r = cand_i[q * CAP + m];
        const float4* xr = (const float4*)(X + (long)r * D);
        float s = 0.f;
        #pragma unroll
        for (int p = 0; p < 4; p++) {
            float4 xv = xr[j * 4 + p];
            float4 qv = *(const float4*)&qrow[(j * 4 + p) * 4];
            s = fmaf(xv.x, qv.x, fmaf(xv.y, qv.y, fmaf(xv.z, qv.z, fmaf(xv.w, qv.w, s))));
        }
        s += __shfl_down(s, 4); s += __shfl_down(s, 2); s += __shfl_down(s, 1);
        if (j == 0) ksg[q * CAP + m] = fkey(xn[r] - 2.f * s);
    }
}

// ---- per-query: top-50 from precomputed keys -> l2 -> softmax -> union KL ----
__global__ void k_post2(const float* __restrict__ comb, const float* __restrict__ X,
                        const int* __restrict__ cand_i, const unsigned* __restrict__ cnt,
                        const unsigned* __restrict__ ksg, const int* __restrict__ pri,
                        const float* __restrict__ prw, const int* __restrict__ qix,
                        float* __restrict__ acc)
{
    __shared__ unsigned ks[CAP];
    __shared__ float qrow[D];
    __shared__ unsigned wred[4];
    __shared__ unsigned wpos, eqn;
    __shared__ int eq[64];
    __shared__ int pidx[KNN];
    __shared__ float l2s[KNN];
    __shared__ float pw[KNN];
    __shared__ int ci[100];
    __shared__ float pwv[50], qwv[50];
    __shared__ float pterm[100], qterm[100], kterm[100];
    __shared__ float Sp, Sq;
    const int q = blockIdx.x, t = threadIdx.x;
    if (t < D) qrow[t] = comb[q * D + t];
    if (t == 0) { wpos = 0; eqn = 0; }
    unsigned nn = cnt[q * 16];
    const int n = (nn < (unsigned)CAP) ? (int)nn : CAP;
    for (int m = t; m < n; m += 256) ks[m] = ksg[q * CAP + m];
    __syncthreads();
    int kk = KNN - 1; if (kk > n - 1) kk = n - 1;
    unsigned v = 0;
    for (int bit = 31; bit >= 0; bit--) {
        unsigned trial = v | (1u << bit);
        unsigned c = 0;
        for (int m = t; m < n; m += 256) c += (ks[m] < trial) ? 1u : 0u;
        #pragma unroll
        for (int off = 32; off > 0; off >>= 1) c += __shfl_down(c, off);
        if ((t & 63) == 0) wred[t >> 6] = c;
        __syncthreads();
        unsigned total = wred[0] + wred[1] + wred[2] + wred[3];
        __syncthreads();
        if (total <= (unsigned)kk) v = trial;
    }
    for (int m = t; m < n; m += 256) {
        if (ks[m] < v) {
            unsigned p = atomicAdd(&wpos, 1u);
            pidx[p] = cand_i[q * CAP + m];
        } else if (ks[m] == v) {
            unsigned p = atomicAdd(&eqn, 1u);
            if (p < 64) eq[p] = cand_i[q * CAP + m];
        }
    }
    __syncthreads();
    if (t == 0) {
        int c1 = (int)wpos, need = KNN - c1;
        int ne = (eqn < 64u) ? (int)eqn : 64;
        for (int a = 0; a < ne; a++)
            for (int b2 = a + 1; b2 < ne; b2++)
                if (eq[b2] < eq[a]) { int tmp = eq[a]; eq[a] = eq[b2]; eq[b2] = tmp; }
        for (int a = 0; a < need && a < ne; a++) pidx[c1 + a] = eq[a];
    }
    __syncthreads();
    const int g = t >> 3, j = t & 7;
    for (int nb = g; nb < KNN; nb += 32) {
        long r = pidx[nb];
        const float4* xr = (const float4*)(X + r * D);
        float s = 0.f;
        #pragma unroll
        for (int p = 0; p < 4; p++) {
            float4 xv = xr[j * 4 + p];
            float4 qv = *(const float4*)&qrow[(j * 4 + p) * 4];
            float d0 = qv.x - xv.x, d1 = qv.y - xv.y, d2 = qv.z - xv.z, d3 = qv.w - xv.w;
            s += d0 * d0 + d1 * d1 + d2 * d2 + d3 * d3;
        }
        s += __shfl_down(s, 4); s += __shfl_down(s, 2); s += __shfl_down(s, 1);
        if (j == 0) l2s[nb] = s;
    }
    int qi = qix[q];
    if (t >= 128 && t < 178) { int k = t - 128; ci[k] = pri[qi * 50 + k]; pwv[k] = prw[qi * 50 + k]; }
    __syncthreads();
    if (t < 64) {
        float logit = (t < KNN) ? (-l2s[t] * 10.0f) : -3.4e38f; // 1/tau = 10
        float m = logit;
        #pragma unroll
        for (int off = 32; off > 0; off >>= 1) m = fmaxf(m, __shfl_down(m, off));
        m = __shfl(m, 0);
        float e = (t < KNN) ? expf(logit - m) : 0.f;
        float ss = e;
        #pragma unroll
        for (int off = 32; off > 0; off >>= 1) ss += __shfl_down(ss, off);
        ss = __shfl(ss, 0);
        if (t < KNN) pw[t] = e / ss;
    }
    __syncthreads();
    if (t < 50) { ci[50 + t] = pidx[t]; qwv[t] = pw[t]; }
    __syncthreads();
    float pc = 0.f, qc = 0.f, mult = 0.f;
    if (t < 100) {
        int c = ci[t];
        float pr = 0.f, qr = 0.f;
        for (int k = 0; k < 50; k++) {
            bool m1 = (c == ci[k]); bool m2 = (c == ci[50 + k]);
            mult += (m1 ? 1.f : 0.f) + (m2 ? 1.f : 0.f);
            pr += m1 ? pwv[k] : 0.f;
            qr += m2 ? qwv[k] : 0.f;
        }
        pc = fmaxf(pr, 1e-8f); qc = fmaxf(qr, 1e-8f);
        pterm[t] = pc / mult; qterm[t] = qc / mult;
    }
    __syncthreads();
    if (t == 0) { float a = 0.f, b2 = 0.f; for (int m = 0; m < 100; m++) { a += pterm[m]; b2 += qterm[m]; } Sp = a; Sq = b2; }
    __syncthreads();
    if (t < 100) {
        float p = pc / Sp, qq2 = qc / Sq;
        kterm[t] = (p * (logf(p) - logf(qq2))) / mult;
    }
    __syncthreads();
    if (t == 0) { float s = 0.f; for (int m = 0; m < 100; m++) s += kterm[m]; atomicAdd(&acc[1], s); }
}

// ---- final assembly (reg precomputed in phase1) ----
__global__ void k_final(const float* __restrict__ acc, float* __restrict__ out)
{
    if (threadIdx.x == 0) {
        float reg = 0.5f * acc[7];
        float kxx = acc[2] / 65536.f, kyy = acc[3] / 65536.f, kxy = acc[4] / 131072.f;
        float ld = fmaxf(kxx + kyy - 2.f * kxy, 0.f);
        float lknn = acc[1] / 256.f;
        float lanc = acc[0] / 256.f;
        out[0] = ld + lknn + 1e-4f * reg + lanc;
        out[1] = ld; out[2] = lknn; out[3] = lanc;
    }
}

extern "C" void kernel_launch(void* const* d_in, const int* in_sizes, int n_in,
                              void* d_out, int out_size, void* d_ws, size_t ws_size,
                              hipStream_t stream)
{
    (void)in_sizes; (void)n_in; (void)out_size; (void)ws_size;
    const float* q   = (const float*)d_in[0];
    const float* X   = (const float*)d_in[1];
    const float* W   = (const float*)d_in[2];
    const float* bb  = (const float*)d_in[3];
    const float* prw = (const float*)d_in[4];
    const int*   pri = (const int*)d_in[5];
    const int*   qix = (const int*)d_in[6];
    const int*   idx = (const int*)d_in[7];
    float* out = (float*)d_out;
    char* ws = (char*)d_ws;
    float*    acc   = (float*)(ws + OFF_ACC);
    unsigned* sel   = (unsigned*)(ws + OFF_SEL);
    unsigned* cnt   = (unsigned*)(ws + OFF_CNT);
    unsigned* hist0 = (unsigned*)(ws + OFF_HIST0);
    unsigned* hist12= (unsigned*)(ws + OFF_HIST12);
    float*    comb  = (float*)(ws + OFF_COMB);
    float*    D2w   = (float*)(ws + OFF_D2);
    float*    xn    = (float*)(ws + OFF_XN);
    float*    samp  = (float*)(ws + OFF_SAMP);
    float*    thr   = (float*)(ws + OFF_THR);
    int*      cix   = (int*)(ws + OFF_CANDI);
    unsigned* ksg   = (unsigned*)(ws + OFF_KSG);
    unsigned short* tqsw = (unsigned short*)(ws + OFF_TQSW);
    unsigned short* xbf  = (unsigned short*)(ws + OFF_XBF);

    hipMemsetAsync(ws, 0, MEMSET_BYTES, stream);
    hipLaunchKernelGGL(k_phase1,  dim3(12760),   dim3(256), 0, stream, q, X, W, bb, idx, comb, tqsw, xbf, xn, acc);
    hipLaunchKernelGGL(k_d2h,     dim3(128, 8),  dim3(256), 0, stream, comb, D2w, hist0);
    hipLaunchKernelGGL(k_mf0,     dim3(257),     dim3(256), 0, stream, tqsw, xbf, xn, samp, hist0, sel);
    hipLaunchKernelGGL(k_h1thr,   dim3(512),     dim3(256), 0, stream, D2w, hist12, sel, samp, thr);
    hipLaunchKernelGGL(k_hist2s,  dim3(256),     dim3(256), 0, stream, D2w, hist12, sel);
    hipLaunchKernelGGL(k_mf1,     dim3(1280),    dim3(256), 0, stream, tqsw, xbf, xn, thr, cix, cnt, D2w, hist12, sel, acc);
    hipLaunchKernelGGL(k_rescore, dim3(256, 16), dim3(256), 0, stream, comb, X, xn, cix, cnt, ksg);
    hipLaunchKernelGGL(k_post2,   dim3(256),     dim3(256), 0, stream, comb, X, cix, cnt, ksg, pri, prw, qix, acc);
    hipLaunchKernelGGL(k_final,   dim3(1),       dim3(64),  0, stream, acc, out);
}

// Round 8
// 417.080 us; speedup vs baseline: 3.9583x; 1.0469x over previous
//
#include <hip/hip_runtime.h>
#include <cstdint>

#define D 128
#define NPTS 200000
#define KNN 50
#define CAP 8192
#define NS 8192
#define SLACK 2.0f

// ---- workspace byte offsets ----
#define OFF_ACC    0         // 32 f32 (zeroed)
#define OFF_SEL    256       // 16 u32 (zeroed)
#define OFF_CNT    1024      // 256*16 u32 (zeroed, 1 counter / 64B line)
#define OFF_HIST0  17408     // 4096*8 u32 sharded (zeroed)
#define OFF_HIST12 148480    // 2*2*4096 u32 (zeroed)
#define MEMSET_BYTES 214016
#define OFF_COMB   214016    // 512*128 f32
#define OFF_D2     476160    // 262144 f32
#define OFF_XN     1524736   // 200000 f32
#define OFF_SAMP   2324736   // 256*8192 f32
#define OFF_THR    10713344  // 256 f32
#define OFF_CANDI  10714368  // 256*8192 i32
#define OFF_KSG    19102976  // 256*8192 u32 rescored keys
#define OFF_TQSW   27491584  // 256*128 bf16 swizzled
#define OFF_XBF    27557120  // 200000*128 bf16 swizzled (51.2 MB)

typedef __attribute__((ext_vector_type(8))) short bf16x8;
typedef __attribute__((ext_vector_type(4))) float f32x4;
typedef const __attribute__((address_space(1))) void* gas_p;
typedef __attribute__((address_space(3))) void* las_p;

__device__ __forceinline__ unsigned fkey(float f) {
    unsigned u = __float_as_uint(f);
    return u ^ ((unsigned)((int)u >> 31) | 0x80000000u);
}

// async-stage 8KB chunk (4096 ushorts) into LDS: wave-uniform lds base, lane*16B implicit
__device__ __forceinline__ void stage8k(const unsigned short* __restrict__ g,
                                        unsigned short* l, int w, int lane)
{
    #pragma unroll
    for (int j = 0; j < 2; j++) {
        const unsigned short* gp = g + j * 2048 + w * 512 + lane * 8;
        unsigned short* lp = l + j * 2048 + w * 512;
        __builtin_amdgcn_global_load_lds((gas_p)gp, (las_p)lp, 16, 0, 0);
    }
}

// ---- phase 1: X->bf16 swizzle + xnorm | Tq=qW^T+b (+swizzle, anchor) | comb X[idx] | W reg ----
__global__ void k_phase1(const float* __restrict__ q, const float* __restrict__ X,
                         const float* __restrict__ W, const float* __restrict__ bb,
                         const int* __restrict__ idx, float* __restrict__ comb,
                         unsigned short* __restrict__ tqsw, unsigned short* __restrict__ xbf,
                         float* __restrict__ xn, float* __restrict__ acc)
{
    const int blk = blockIdx.x, t = threadIdx.x;
    if (blk < 12500) {
        __shared__ float xr[16];
        const int lr = t & 15;
        if (t < 16) xr[t] = 0.f;
        __syncthreads();
        const float4* src = (const float4*)(X + ((long)(blk * 16 + lr)) * D + (t >> 4) * 8);
        float4 v0 = src[0], v1 = src[1];
        uint4 pk;
        pk.x = (__float_as_uint(v0.x) >> 16) | (__float_as_uint(v0.y) & 0xFFFF0000u);
        pk.y = (__float_as_uint(v0.z) >> 16) | (__float_as_uint(v0.w) & 0xFFFF0000u);
        pk.z = (__float_as_uint(v1.x) >> 16) | (__float_as_uint(v1.y) & 0xFFFF0000u);
        pk.w = (__float_as_uint(v1.z) >> 16) | (__float_as_uint(v1.w) & 0xFFFF0000u);
        *(uint4*)(xbf + (long)blk * 2048 + t * 8) = pk;
        float ssq = v0.x*v0.x + v0.y*v0.y + v0.z*v0.z + v0.w*v0.w
                  + v1.x*v1.x + v1.y*v1.y + v1.z*v1.z + v1.w*v1.w;
        atomicAdd(&xr[lr], ssq);
        __syncthreads();
        if (t < 16) xn[blk * 16 + t] = xr[t];
    } else if (blk < 12628) {
        __shared__ float rowv[2][D];
        __shared__ float red[2][D];
        const int half = t >> 7, tt = t & 127;
        const int row = (blk - 12500) * 2 + half;
        rowv[half][tt] = q[row * D + tt];
        __syncthreads();
        float s = 0.f;
        const float* wr = W + tt * D;
        #pragma unroll 4
        for (int k = 0; k < D; k++) s = fmaf(rowv[half][k], wr[k], s);
        s += bb[tt];
        comb[row * D + tt] = s;
        unsigned ub = __float_as_uint(s);
        unsigned short hv = (unsigned short)((ub + 0x7fffu + ((ub >> 16) & 1u)) >> 16);
        int ksb = tt >> 5, quad = (tt & 31) >> 3, jj = tt & 7;
        int lane = quad * 16 + (row & 15);
        tqsw[(row >> 4) * 2048 + ksb * 512 + lane * 8 + jj] = hv;
        float dd = s - rowv[half][tt];
        red[half][tt] = dd * dd;
        __syncthreads();
        for (int off = 64; off > 0; off >>= 1) { if (tt < off) red[half][tt] += red[half][tt + off]; __syncthreads(); }
        if (tt == 0) atomicAdd(&acc[0], red[half][0]);
    } else if (blk < 12756) {
        const int half = t >> 7, tt = t & 127;
        const int i = (blk - 12628) * 2 + half;
        comb[(256 + i) * D + tt] = X[(long)idx[i] * D + tt];
    } else {
        __shared__ float wred[4];
        const int base = (blk - 12756) * 4096;
        float s = 0.f;
        #pragma unroll 4
        for (int k = 0; k < 16; k++) { float v = W[base + k * 256 + t]; s = fmaf(v, v, s); }
        if (blk == 12756 && t < D) { float v = bb[t]; s = fmaf(v, v, s); }
        #pragma unroll
        for (int off = 32; off > 0; off >>= 1) s += __shfl_down(s, off);
        if ((t & 63) == 0) wred[t >> 6] = s;
        __syncthreads();
        if (t == 0) atomicAdd(&acc[7], wred[0] + wred[1] + wred[2] + wred[3]);
    }
}

// ---- D2 (512x512) + fused 12-bit histogram; 4 waves share one cj stage ----
__global__ void k_d2h(const float* __restrict__ comb, float* __restrict__ D2w,
                      unsigned* __restrict__ hist0)
{
    __shared__ float cj[64][D + 1];
    __shared__ float ci[4][D];
    __shared__ unsigned h[4096];
    const int ib = blockIdx.x, jb = blockIdx.y, t = threadIdx.x;
    const int w = t >> 6, l = t & 63;
    for (int m = t; m < 4096; m += 256) h[m] = 0;
    const int irow = ib * 4 + w;
    ci[w][l] = comb[irow * D + l];
    ci[w][l + 64] = comb[irow * D + l + 64];
    const float4* src = (const float4*)(comb + (jb * 64) * D);
    #pragma unroll
    for (int m = 0; m < 8; m++) {
        int u = m * 256 + t;
        int r = u >> 5, c = u & 31;
        float4 v = src[u];
        cj[r][c * 4 + 0] = v.x; cj[r][c * 4 + 1] = v.y; cj[r][c * 4 + 2] = v.z; cj[r][c * 4 + 3] = v.w;
    }
    __syncthreads();
    float s = 0.f;
    #pragma unroll 4
    for (int k = 0; k < D; k++) { float d = ci[w][k] - cj[l][k]; s = fmaf(d, d, s); }
    D2w[irow * 512 + jb * 64 + l] = s;
    atomicAdd(&h[__float_as_uint(s) >> 20], 1u);
    __syncthreads();
    const int sh = (ib + jb) & 7;
    for (int m = t; m < 4096; m += 256) { unsigned v = h[m]; if (v) atomicAdd(&hist0[m * 8 + sh], v); }
}

// ---- mf0: samples via LDS-staged chunks (blocks 0..255 = one 32-row chunk) + scan0 (block 256) ----
__global__ __launch_bounds__(256) void k_mf0(const unsigned short* __restrict__ tqsw,
    const unsigned short* __restrict__ xbf, const float* __restrict__ xn,
    float* __restrict__ samp, const unsigned* __restrict__ hist0, unsigned* __restrict__ sel)
{
    if (blockIdx.x == 256) {
        __shared__ unsigned part[256];
        const int t = threadIdx.x;
        unsigned s = 0;
        for (int m = 0; m < 16; m++) {
            int b = t * 16 + m;
            #pragma unroll
            for (int sh = 0; sh < 8; sh++) s += hist0[b * 8 + sh];
        }
        part[t] = s;
        __syncthreads();
        if (t == 0) {
            for (int tg = 0; tg < 2; tg++) {
                unsigned r = tg ? 131072u : 131071u;
                int c = 0;
                while (part[c] <= r) { r -= part[c]; c++; }
                int b = c * 16;
                while (true) {
                    unsigned bs = 0;
                    #pragma unroll
                    for (int sh = 0; sh < 8; sh++) bs += hist0[b * 8 + sh];
                    if (bs <= r) { r -= bs; b++; } else break;
                }
                sel[2 * tg] = (unsigned)b; sel[2 * tg + 1] = r;
            }
        }
        return;
    }
    __shared__ unsigned short sb[4096]; // 8 KB chunk
    const int t = threadIdx.x;
    const int w = t >> 6, lane = t & 63;
    const int lr = lane & 15, quad = lane >> 4;
    const int ck = blockIdx.x;
    stage8k(xbf + (long)ck * 4096, sb, w, lane);
    bf16x8 a[4][4];
    #pragma unroll
    for (int i = 0; i < 4; i++)
        #pragma unroll
        for (int ks = 0; ks < 4; ks++)
            a[i][ks] = *(const bf16x8*)(tqsw + (w * 4 + i) * 2048 + ks * 512 + lane * 8);
    __syncthreads();
    #pragma unroll
    for (int tt = 0; tt < 2; tt++) {
        const int r = (ck * 2 + tt) * 16 + lr;
        float xnv = xn[r];
        bf16x8 b[4];
        #pragma unroll
        for (int ks = 0; ks < 4; ks++)
            b[ks] = *(const bf16x8*)(sb + tt * 2048 + ks * 512 + lane * 8);
        f32x4 acc[4];
        #pragma unroll
        for (int i = 0; i < 4; i++) acc[i] = (f32x4){0.f, 0.f, 0.f, 0.f};
        #pragma unroll
        for (int ks = 0; ks < 4; ks++)
            #pragma unroll
            for (int i = 0; i < 4; i++)
                acc[i] = __builtin_amdgcn_mfma_f32_16x16x32_bf16(a[i][ks], b[ks], acc[i], 0, 0, 0);
        #pragma unroll
        for (int i = 0; i < 4; i++)
            #pragma unroll
            for (int reg = 0; reg < 4; reg++) {
                int qq = w * 64 + i * 16 + quad * 4 + reg;
                samp[qq * NS + r] = xnv - 2.f * acc[i][reg];
            }
    }
}

// ---- hist pass1 (blocks 0..255) + per-query sample threshold (blocks 256..511) ----
__global__ void k_h1thr(const float* __restrict__ D2w, unsigned* __restrict__ hist12,
                        const unsigned* __restrict__ sel, const float* __restrict__ samp,
                        float* __restrict__ thr)
{
    __shared__ unsigned buf[8192];
    __shared__ unsigned wred[4];
    const int t = threadIdx.x;
    if (blockIdx.x < 256) {
        for (int m = t; m < 8192; m += 256) buf[m] = 0;
        __syncthreads();
        unsigned p0 = sel[0], p1 = sel[2];
        const int e0 = blockIdx.x * 1024;
        for (int m = 0; m < 4; m++) {
            unsigned key = __float_as_uint(D2w[e0 + m * 256 + t]);
            if ((key >> 20) == p0) atomicAdd(&buf[(key >> 8) & 0xFFFu], 1u);
            if ((key >> 20) == p1) atomicAdd(&buf[4096 + ((key >> 8) & 0xFFFu)], 1u);
        }
        __syncthreads();
        for (int m = t; m < 8192; m += 256) { unsigned v = buf[m]; if (v) atomicAdd(&hist12[m], v); }
    } else {
        const int q = blockIdx.x - 256;
        for (int m = t; m < NS; m += 256) buf[m] = fkey(samp[q * NS + m]);
        __syncthreads();
        unsigned v = 0;
        for (int bit = 31; bit >= 0; bit--) {
            unsigned trial = v | (1u << bit);
            unsigned c = 0;
            for (int m = t; m < NS; m += 256) c += (buf[m] < trial) ? 1u : 0u;
            #pragma unroll
            for (int off = 32; off > 0; off >>= 1) c += __shfl_down(c, off);
            if ((t & 63) == 0) wred[t >> 6] = c;
            __syncthreads();
            unsigned total = wred[0] + wred[1] + wred[2] + wred[3];
            __syncthreads();
            if (total <= (unsigned)(KNN - 1)) v = trial;
        }
        if (t == 0) {
            unsigned orig = (v & 0x80000000u) ? (v ^ 0x80000000u) : ~v;
            thr[q] = __uint_as_float(orig) + SLACK;
        }
    }
}

// ---- hist pass2 with fused local scan1 (block 0 persists sel[4..7]) ----
__global__ void k_hist2s(const float* __restrict__ D2w, unsigned* __restrict__ hist12,
                         unsigned* __restrict__ sel)
{
    __shared__ unsigned h[8192];
    __shared__ unsigned part[256];
    __shared__ unsigned pfx[2];
    __shared__ unsigned rr[2];
    const int t = threadIdx.x;
    for (int tg = 0; tg < 2; tg++) {
        const unsigned* hh = hist12 + tg * 4096;
        unsigned s = 0;
        for (int m = 0; m < 16; m++) s += hh[t * 16 + m];
        part[t] = s;
        __syncthreads();
        if (t == 0) {
            unsigned r = sel[1 + 2 * tg];
            int c = 0;
            while (part[c] <= r) { r -= part[c]; c++; }
            int b = c * 16;
            while (hh[b] <= r) { r -= hh[b]; b++; }
            pfx[tg] = (sel[2 * tg] << 12) | (unsigned)b;
            rr[tg] = r;
        }
        __syncthreads();
    }
    if (blockIdx.x == 0 && t == 0) {
        sel[4] = pfx[0]; sel[5] = rr[0]; sel[6] = pfx[1]; sel[7] = rr[1];
    }
    for (int m = t; m < 8192; m += 256) h[m] = 0;
    __syncthreads();
    unsigned p0 = pfx[0], p1 = pfx[1];
    const int e0 = blockIdx.x * 1024;
    for (int m = 0; m < 4; m++) {
        unsigned key = __float_as_uint(D2w[e0 + m * 256 + t]);
        if ((key >> 8) == p0) atomicAdd(&h[key & 0xFFu], 1u);
        if ((key >> 8) == p1) atomicAdd(&h[4096 + (key & 0xFFu)], 1u);
    }
    __syncthreads();
    unsigned* gp = hist12 + 8192;
    for (int m = t; m < 8192; m += 256) { unsigned v = h[m]; if (v) atomicAdd(&gp[m], v); }
}

// ---- mf1: filter, LDS dbuf staging + LDS candidate aggregation (blocks 0..1023) + mmd (1024..1279) ----
__global__ __launch_bounds__(256) void k_mf1(const unsigned short* __restrict__ tqsw,
    const unsigned short* __restrict__ xbf, const float* __restrict__ xn,
    const float* __restrict__ thr, int* __restrict__ cand_i, unsigned* __restrict__ cnt,
    const float* __restrict__ D2w, const unsigned* __restrict__ hist12,
    const unsigned* __restrict__ sel, float* __restrict__ acc)
{
    if (blockIdx.x >= 1024) {
        __shared__ unsigned h2[512];
        __shared__ float gsh;
        __shared__ float part[12];
        const int t = threadIdx.x, w = t >> 6;
        h2[t] = hist12[8192 + t];
        h2[256 + t] = hist12[8192 + 4096 + t];
        __syncthreads();
        if (t == 0) {
            unsigned key[2];
            for (int tg = 0; tg < 2; tg++) {
                unsigned r = sel[5 + 2 * tg];
                const unsigned* hh = h2 + tg * 256;
                int b = 0;
                while (hh[b] <= r) { r -= hh[b]; b++; }
                key[tg] = (sel[4 + 2 * tg] << 8) | (unsigned)b;
            }
            float med = 0.5f * (__uint_as_float(key[0]) + __uint_as_float(key[1]));
            float ssq = 0.5f * med;
            if (ssq < 1e-6f) ssq = 1.0f;
            gsh = 1.0f / (ssq + 1e-8f);
        }
        __syncthreads();
        const float g = gsh;
        float s[3] = {0.f, 0.f, 0.f};
        const int e0 = (blockIdx.x - 1024) * 1024;
        #pragma unroll
        for (int m = 0; m < 4; m++) {
            int e = e0 + m * 256 + t;
            int i = e >> 9, j = e & 511;
            float v = expf(-g * D2w[e]);
            int qd = (i < 256) ? ((j < 256) ? 0 : 2) : ((j < 256) ? 2 : 1);
            s[qd] += v;
        }
        #pragma unroll
        for (int c = 0; c < 3; c++) {
            float x = s[c];
            #pragma unroll
            for (int off = 32; off > 0; off >>= 1) x += __shfl_down(x, off);
            if ((t & 63) == 0) part[w * 3 + c] = x;
        }
        __syncthreads();
        if (t == 0)
            for (int c = 0; c < 3; c++)
                atomicAdd(&acc[2 + c], part[c] + part[3 + c] + part[6 + c] + part[9 + c]);
        return;
    }
    __shared__ unsigned short sb[2][4096]; // double-buffered 8 KB chunks
    __shared__ unsigned lbuf[1024];        // packed (qq<<18)|r candidates
    __shared__ unsigned lcnt;
    const int t = threadIdx.x;
    const int w = t >> 6, lane = t & 63;
    const int lr = lane & 15, quad = lane >> 4;
    bf16x8 a[4][4];
    #pragma unroll
    for (int i = 0; i < 4; i++)
        #pragma unroll
        for (int ks = 0; ks < 4; ks++)
            a[i][ks] = *(const bf16x8*)(tqsw + (w * 4 + i) * 2048 + ks * 512 + lane * 8);
    float th_r[4][4];
    #pragma unroll
    for (int i = 0; i < 4; i++)
        #pragma unroll
        for (int reg = 0; reg < 4; reg++)
            th_r[i][reg] = thr[w * 64 + i * 16 + quad * 4 + reg];
    int ck = blockIdx.x;
    int cur = 0;
    if (t == 0) lcnt = 0;
    stage8k(xbf + (long)ck * 4096, sb[0], w, lane);
    __syncthreads();
    while (true) {
        const int ckn = ck + 1024;
        const bool has = ckn < 6250;
        if (has) stage8k(xbf + (long)ckn * 4096, sb[cur ^ 1], w, lane);
        #pragma unroll
        for (int tt = 0; tt < 2; tt++) {
            const int r = (ck * 2 + tt) * 16 + lr;
            float xnv = xn[r];
            bf16x8 b[4];
            #pragma unroll
            for (int ks = 0; ks < 4; ks++)
                b[ks] = *(const bf16x8*)(sb[cur] + tt * 2048 + ks * 512 + lane * 8);
            f32x4 acc4[4];
            #pragma unroll
            for (int i = 0; i < 4; i++) acc4[i] = (f32x4){0.f, 0.f, 0.f, 0.f};
            #pragma unroll
            for (int ks = 0; ks < 4; ks++)
                #pragma unroll
                for (int i = 0; i < 4; i++)
                    acc4[i] = __builtin_amdgcn_mfma_f32_16x16x32_bf16(a[i][ks], b[ks], acc4[i], 0, 0, 0);
            #pragma unroll
            for (int i = 0; i < 4; i++)
                #pragma unroll
                for (int reg = 0; reg < 4; reg++) {
                    float s = xnv - 2.f * acc4[i][reg];
                    if (s <= th_r[i][reg]) {
                        unsigned qq = (unsigned)(w * 64 + i * 16 + quad * 4 + reg);
                        unsigned p = atomicAdd(&lcnt, 1u);
                        if (p < 1024u) lbuf[p] = (qq << 18) | (unsigned)r;
                        else { // overflow fallback: direct (rare)
                            unsigned pos = atomicAdd(&cnt[qq * 16], 1u);
                            if (pos < CAP) cand_i[qq * CAP + pos] = r;
                        }
                    }
                }
        }
        __syncthreads(); // publishes lcnt/lbuf; drains prefetch into sb[cur^1]
        unsigned n = lcnt;
        if (!has || n >= 512u) {
            unsigned nf = (n < 1024u) ? n : 1024u;
            for (unsigned m = t; m < nf; m += 256) {
                unsigned e = lbuf[m];
                unsigned qq = e >> 18, r2 = e & 0x3FFFFu;
                unsigned pos = atomicAdd(&cnt[qq * 16], 1u);
                if (pos < CAP) cand_i[qq * CAP + pos] = (int)r2;
            }
            __syncthreads();
            if (t == 0) lcnt = 0;
            __syncthreads();
        }
        if (!has) break;
        ck = ckn; cur ^= 1;
    }
}

// ---- exact f32 rescore of candidates (16 splits per query for co-residency) ----
__global__ void k_rescore(const float* __restrict__ comb, const float* __restrict__ X,
                          const float* __restrict__ xn, const int* __restrict__ cand_i,
                          const unsigned* __restrict__ cnt, unsigned* __restrict__ ksg)
{
    __shared__ float qrow[D];
    const int q = blockIdx.x, sp = blockIdx.y, t = threadIdx.x;
    if (t < D) qrow[t] = comb[q * D + t];
    __syncthreads();
    unsigned nn = cnt[q * 16];
    const int n = (nn < (unsigned)CAP) ? (int)nn : CAP;
    const int g = t >> 3, j = t & 7;
    for (int m = sp * 32 + g; m < n; m += 512) {
        int r = cand_i[q * CAP + m];
        const float4* xr = (const float4*)(X + (long)r * D);
        float s = 0.f;
        #pragma unroll
        for (int p = 0; p < 4; p++) {
            float4 xv = xr[j * 4 + p];
            float4 qv = *(const float4*)&qrow[(j * 4 + p) * 4];
            s = fmaf(xv.x, qv.x, fmaf(xv.y, qv.y, fmaf(xv.z, qv.z, fmaf(xv.w, qv.w, s))));
        }
        s += __shfl_down(s, 4); s += __shfl_down(s, 2); s += __shfl_down(s, 1);
        if (j == 0) ksg[q * CAP + m] = fkey(xn[r] - 2.f * s);
    }
}

// ---- per-query: top-50 from precomputed keys -> l2 -> softmax -> union KL ----
__global__ void k_post2(const float* __restrict__ comb, const float* __restrict__ X,
                        const int* __restrict__ cand_i, const unsigned* __restrict__ cnt,
                        const unsigned* __restrict__ ksg, const int* __restrict__ pri,
                        const float* __restrict__ prw, const int* __restrict__ qix,
                        float* __restrict__ acc)
{
    __shared__ unsigned ks[CAP];
    __shared__ float qrow[D];
    __shared__ unsigned wred[4];
    __shared__ unsigned wpos, eqn;
    __shared__ int eq[64];
    __shared__ int pidx[KNN];
    __shared__ float l2s[KNN];
    __shared__ float pw[KNN];
    __shared__ int ci[100];
    __shared__ float pwv[50], qwv[50];
    __shared__ float pterm[100], qterm[100], kterm[100];
    __shared__ float Sp, Sq;
    const int q = blockIdx.x, t = threadIdx.x;
    if (t < D) qrow[t] = comb[q * D + t];
    if (t == 0) { wpos = 0; eqn = 0; }
    unsigned nn = cnt[q * 16];
    const int n = (nn < (unsigned)CAP) ? (int)nn : CAP;
    for (int m = t; m < n; m += 256) ks[m] = ksg[q * CAP + m];
    __syncthreads();
    int kk = KNN - 1; if (kk > n - 1) kk = n - 1;
    unsigned v = 0;
    for (int bit = 31; bit >= 0; bit--) {
        unsigned trial = v | (1u << bit);
        unsigned c = 0;
        for (int m = t; m < n; m += 256) c += (ks[m] < trial) ? 1u : 0u;
        #pragma unroll
        for (int off = 32; off > 0; off >>= 1) c += __shfl_down(c, off);
        if ((t & 63) == 0) wred[t >> 6] = c;
        __syncthreads();
        unsigned total = wred[0] + wred[1] + wred[2] + wred[3];
        __syncthreads();
        if (total <= (unsigned)kk) v = trial;
    }
    for (int m = t; m < n; m += 256) {
        if (ks[m] < v) {
            unsigned p = atomicAdd(&wpos, 1u);
            pidx[p] = cand_i[q * CAP + m];
        } else if (ks[m] == v) {
            unsigned p = atomicAdd(&eqn, 1u);
            if (p < 64) eq[p] = cand_i[q * CAP + m];
        }
    }
    __syncthreads();
    if (t == 0) {
        int c1 = (int)wpos, need = KNN - c1;
        int ne = (eqn < 64u) ? (int)eqn : 64;
        for (int a = 0; a < ne; a++)
            for (int b2 = a + 1; b2 < ne; b2++)
                if (eq[b2] < eq[a]) { int tmp = eq[a]; eq[a] = eq[b2]; eq[b2] = tmp; }
        for (int a = 0; a < need && a < ne; a++) pidx[c1 + a] = eq[a];
    }
    __syncthreads();
    const int g = t >> 3, j = t & 7;
    for (int nb = g; nb < KNN; nb += 32) {
        long r = pidx[nb];
        const float4* xr = (const float4*)(X + r * D);
        float s = 0.f;
        #pragma unroll
        for (int p = 0; p < 4; p++) {
            float4 xv = xr[j * 4 + p];
            float4 qv = *(const float4*)&qrow[(j * 4 + p) * 4];
            float d0 = qv.x - xv.x, d1 = qv.y - xv.y, d2 = qv.z - xv.z, d3 = qv.w - xv.w;
            s += d0 * d0 + d1 * d1 + d2 * d2 + d3 * d3;
        }
        s += __shfl_down(s, 4); s += __shfl_down(s, 2); s += __shfl_down(s, 1);
        if (j == 0) l2s[nb] = s;
    }
    int qi = qix[q];
    if (t >= 128 && t < 178) { int k = t - 128; ci[k] = pri[qi * 50 + k]; pwv[k] = prw[qi * 50 + k]; }
    __syncthreads();
    if (t < 64) {
        float logit = (t < KNN) ? (-l2s[t] * 10.0f) : -3.4e38f; // 1/tau = 10
        float m = logit;
        #pragma unroll
        for (int off = 32; off > 0; off >>= 1) m = fmaxf(m, __shfl_down(m, off));
        m = __shfl(m, 0);
        float e = (t < KNN) ? expf(logit - m) : 0.f;
        float ss = e;
        #pragma unroll
        for (int off = 32; off > 0; off >>= 1) ss += __shfl_down(ss, off);
        ss = __shfl(ss, 0);
        if (t < KNN) pw[t] = e / ss;
    }
    __syncthreads();
    if (t < 50) { ci[50 + t] = pidx[t]; qwv[t] = pw[t]; }
    __syncthreads();
    float pc = 0.f, qc = 0.f, mult = 0.f;
    if (t < 100) {
        int c = ci[t];
        float pr = 0.f, qr = 0.f;
        for (int k = 0; k < 50; k++) {
            bool m1 = (c == ci[k]); bool m2 = (c == ci[50 + k]);
            mult += (m1 ? 1.f : 0.f) + (m2 ? 1.f : 0.f);
            pr += m1 ? pwv[k] : 0.f;
            qr += m2 ? qwv[k] : 0.f;
        }
        pc = fmaxf(pr, 1e-8f); qc = fmaxf(qr, 1e-8f);
        pterm[t] = pc / mult; qterm[t] = qc / mult;
    }
    __syncthreads();
    if (t == 0) { float a = 0.f, b2 = 0.f; for (int m = 0; m < 100; m++) { a += pterm[m]; b2 += qterm[m]; } Sp = a; Sq = b2; }
    __syncthreads();
    if (t < 100) {
        float p = pc / Sp, qq2 = qc / Sq;
        kterm[t] = (p * (logf(p) - logf(qq2))) / mult;
    }
    __syncthreads();
    if (t == 0) { float s = 0.f; for (int m = 0; m < 100; m++) s += kterm[m]; atomicAdd(&acc[1], s); }
}

// ---- final assembly (reg precomputed in phase1) ----
__global__ void k_final(const float* __restrict__ acc, float* __restrict__ out)
{
    if (threadIdx.x == 0) {
        float reg = 0.5f * acc[7];
        float kxx = acc[2] / 65536.f, kyy = acc[3] / 65536.f, kxy = acc[4] / 131072.f;
        float ld = fmaxf(kxx + kyy - 2.f * kxy, 0.f);
        float lknn = acc[1] / 256.f;
        float lanc = acc[0] / 256.f;
        out[0] = ld + lknn + 1e-4f * reg + lanc;
        out[1] = ld; out[2] = lknn; out[3] = lanc;
    }
}

extern "C" void kernel_launch(void* const* d_in, const int* in_sizes, int n_in,
                              void* d_out, int out_size, void* d_ws, size_t ws_size,
                              hipStream_t stream)
{
    (void)in_sizes; (void)n_in; (void)out_size; (void)ws_size;
    const float* q   = (const float*)d_in[0];
    const float* X   = (const float*)d_in[1];
    const float* W   = (const float*)d_in[2];
    const float* bb  = (const float*)d_in[3];
    const float* prw = (const float*)d_in[4];
    const int*   pri = (const int*)d_in[5];
    const int*   qix = (const int*)d_in[6];
    const int*   idx = (const int*)d_in[7];
    float* out = (float*)d_out;
    char* ws = (char*)d_ws;
    float*    acc   = (float*)(ws + OFF_ACC);
    unsigned* sel   = (unsigned*)(ws + OFF_SEL);
    unsigned* cnt   = (unsigned*)(ws + OFF_CNT);
    unsigned* hist0 = (unsigned*)(ws + OFF_HIST0);
    unsigned* hist12= (unsigned*)(ws + OFF_HIST12);
    float*    comb  = (float*)(ws + OFF_COMB);
    float*    D2w   = (float*)(ws + OFF_D2);
    float*    xn    = (float*)(ws + OFF_XN);
    float*    samp  = (float*)(ws + OFF_SAMP);
    float*    thr   = (float*)(ws + OFF_THR);
    int*      cix   = (int*)(ws + OFF_CANDI);
    unsigned* ksg   = (unsigned*)(ws + OFF_KSG);
    unsigned short* tqsw = (unsigned short*)(ws + OFF_TQSW);
    unsigned short* xbf  = (unsigned short*)(ws + OFF_XBF);

    hipMemsetAsync(ws, 0, MEMSET_BYTES, stream);
    hipLaunchKernelGGL(k_phase1,  dim3(12760),   dim3(256), 0, stream, q, X, W, bb, idx, comb, tqsw, xbf, xn, acc);
    hipLaunchKernelGGL(k_d2h,     dim3(128, 8),  dim3(256), 0, stream, comb, D2w, hist0);
    hipLaunchKernelGGL(k_mf0,     dim3(257),     dim3(256), 0, stream, tqsw, xbf, xn, samp, hist0, sel);
    hipLaunchKernelGGL(k_h1thr,   dim3(512),     dim3(256), 0, stream, D2w, hist12, sel, samp, thr);
    hipLaunchKernelGGL(k_hist2s,  dim3(256),     dim3(256), 0, stream, D2w, hist12, sel);
    hipLaunchKernelGGL(k_mf1,     dim3(1280),    dim3(256), 0, stream, tqsw, xbf, xn, thr, cix, cnt, D2w, hist12, sel, acc);
    hipLaunchKernelGGL(k_rescore, dim3(256, 16), dim3(256), 0, stream, comb, X, xn, cix, cnt, ksg);
    hipLaunchKernelGGL(k_post2,   dim3(256),     dim3(256), 0, stream, comb, X, cix, cnt, ksg, pri, prw, qix, acc);
    hipLaunchKernelGGL(k_final,   dim3(1),       dim3(64),  0, stream, acc, out);
}